// Round 1
// baseline (1991.065 us; speedup 1.0000x reference)
//
#include <hip/hip_runtime.h>
#include <math.h>

#define NNODES 51200
#define NEDGES 409600
#define NB 1024
#define NODES_PER 50
#define NVOCAB 100000

__device__ __forceinline__ float sigf(float x) { return 1.0f / (1.0f + __expf(-x)); }

// ---------------------------------------------------------------------------
// Generic tiled f32 GEMM:  C[M,N] = A[M,K=128] @ B[N,K=128]^T (+bias[N])
// A row stride = strideA (floats), B row stride = 128 (all our B's), C stride = N.
// Requires M % 128 == 0 (true for all call sites). Tile 128x128, 256 threads,
// 8x8 acc per thread. K=128 fully staged in LDS (k-major, pad 132 keeps
// ds_read_b128 16B-aligned).
// ---------------------------------------------------------------------------
__global__ __launch_bounds__(256)
void gemm_bt128(float* __restrict__ C, const float* __restrict__ A,
                const float* __restrict__ B, const float* __restrict__ bias,
                int M, int N, int strideA) {
    __shared__ float At[128][132];
    __shared__ float Bt[128][132];
    const int m0 = blockIdx.y * 128;
    const int n0 = blockIdx.x * 128;
    const int t  = threadIdx.x;

    // stage A tile (coalesced global float4, transposed store to k-major)
    for (int f = t; f < 4096; f += 256) {
        const int r = f >> 5, kc = f & 31;
        const float4 v = *(const float4*)(A + (size_t)(m0 + r) * strideA + kc * 4);
        At[kc*4+0][r] = v.x; At[kc*4+1][r] = v.y;
        At[kc*4+2][r] = v.z; At[kc*4+3][r] = v.w;
    }
    // stage B tile (guard n < N for the ragged last vocab tile)
    for (int f = t; f < 4096; f += 256) {
        const int c = f >> 5, kc = f & 31;
        const int n = n0 + c;
        float4 v = make_float4(0.f, 0.f, 0.f, 0.f);
        if (n < N) v = *(const float4*)(B + (size_t)n * 128 + kc * 4);
        Bt[kc*4+0][c] = v.x; Bt[kc*4+1][c] = v.y;
        Bt[kc*4+2][c] = v.z; Bt[kc*4+3][c] = v.w;
    }
    __syncthreads();

    const int tx = t & 15, ty = t >> 4;
    const int r0 = ty * 8, c0 = tx * 8;
    float acc[8][8] = {};
    #pragma unroll 4
    for (int k = 0; k < 128; ++k) {
        float a[8], b[8];
        *(float4*)&a[0] = *(const float4*)&At[k][r0];
        *(float4*)&a[4] = *(const float4*)&At[k][r0 + 4];
        *(float4*)&b[0] = *(const float4*)&Bt[k][c0];
        *(float4*)&b[4] = *(const float4*)&Bt[k][c0 + 4];
        #pragma unroll
        for (int i = 0; i < 8; ++i)
            #pragma unroll
            for (int j = 0; j < 8; ++j)
                acc[i][j] = fmaf(a[i], b[j], acc[i][j]);
    }

    if (n0 + 128 <= N) {   // full tile: float4 stores
        #pragma unroll
        for (int i = 0; i < 8; ++i) {
            float* crow = C + (size_t)(m0 + r0 + i) * N + n0 + c0;
            float4 v0, v1;
            float bv[8];
            #pragma unroll
            for (int j = 0; j < 8; ++j) bv[j] = acc[i][j] + (bias ? bias[n0 + c0 + j] : 0.f);
            v0 = make_float4(bv[0], bv[1], bv[2], bv[3]);
            v1 = make_float4(bv[4], bv[5], bv[6], bv[7]);
            *(float4*)(crow)     = v0;
            *(float4*)(crow + 4) = v1;
        }
    } else {               // ragged tile: guarded scalar stores
        #pragma unroll
        for (int i = 0; i < 8; ++i) {
            float* crow = C + (size_t)(m0 + r0 + i) * N + n0 + c0;
            #pragma unroll
            for (int j = 0; j < 8; ++j) {
                const int n = n0 + c0 + j;
                if (n < N) crow[j] = acc[i][j] + (bias ? bias[n] : 0.f);
            }
        }
    }
}

// h[i][:] = emb[x[i]-1][:]
__global__ __launch_bounds__(256)
void gather_kernel(const int* __restrict__ x, const float* __restrict__ emb,
                   float* __restrict__ h) {
    const int tid = blockIdx.x * 256 + threadIdx.x;
    const int i = tid >> 5, c = (tid & 31) * 4;
    const int idx = x[i] - 1;
    *(float4*)(h + (size_t)i * 128 + c) = *(const float4*)(emb + (size_t)idx * 128 + c);
}

// Wt[n][k] = W[k][n]  (128x128)
__global__ __launch_bounds__(256)
void transpose128(const float* __restrict__ W, float* __restrict__ Wt) {
    const int tid = blockIdx.x * 256 + threadIdx.x;
    const int k = tid >> 7, n = tid & 127;
    Wt[(size_t)n * 128 + k] = W[tid];
}

__global__ void b12_kernel(const float* __restrict__ b1, const float* __restrict__ b2,
                           float* __restrict__ b12) {
    const int t = threadIdx.x;
    b12[t] = b1[t] + b2[t];
}

// agg[dst] += m[src] over all edges (atomic f32)
__global__ __launch_bounds__(256)
void scatter_kernel(const int* __restrict__ ei, const float* __restrict__ m,
                    float* __restrict__ agg) {
    const int tid = blockIdx.x * 256 + threadIdx.x;
    const int e = tid >> 5, c = (tid & 31) * 4;
    const int src = ei[e];
    const int dst = ei[NEDGES + e];
    const float4 v = *(const float4*)(m + (size_t)src * 128 + c);
    float* a = agg + (size_t)dst * 128 + c;
    atomicAdd(a + 0, v.x); atomicAdd(a + 1, v.y);
    atomicAdd(a + 2, v.z); atomicAdd(a + 3, v.w);
}

// GRU elementwise over one 12800-node chunk; h updated in place, then ReLU
__global__ __launch_bounds__(256)
void gru_kernel(const float* __restrict__ gi, const float* __restrict__ gh,
                float* __restrict__ h) {
    const int tid = blockIdx.x * 256 + threadIdx.x;
    const int i = tid >> 7, j = tid & 127;
    const size_t gb = (size_t)i * 384;
    const float ir = gi[gb + j], iz = gi[gb + 128 + j], in_ = gi[gb + 256 + j];
    const float hr = gh[gb + j], hz = gh[gb + 128 + j], hn  = gh[gb + 256 + j];
    const float hv = h[(size_t)i * 128 + j];
    const float r  = sigf(ir + hr);
    const float z  = sigf(iz + hz);
    const float ng = tanhf(in_ + r * hn);
    const float o  = (1.f - z) * ng + z * hv;
    h[(size_t)i * 128 + j] = fmaxf(o, 0.f);
}

// Per-session attention readout: one wave per session.
// a = sigmoid(t1[b] + t2[i]); alpha_i = a . q + qb; sg[b] = sum alpha_i * h[i]
__global__ __launch_bounds__(64)
void attn_kernel(const float* __restrict__ h, const float* __restrict__ t1,
                 const float* __restrict__ t2, const float* __restrict__ qw,
                 const float* __restrict__ qbp, float* __restrict__ sg) {
    const int b = blockIdx.x, l = threadIdx.x;
    const float t1a = t1[b * 128 + l], t1b = t1[b * 128 + 64 + l];
    const float qa = qw[l], qb2 = qw[64 + l];
    const float qbias = qbp[0];
    const float* hb  = h  + (size_t)b * NODES_PER * 128;
    const float* t2b = t2 + (size_t)b * NODES_PER * 128;
    float sga = 0.f, sgb = 0.f;
    for (int i = 0; i < NODES_PER; ++i) {
        const float ha  = hb[i * 128 + l],      hb2v = hb[i * 128 + 64 + l];
        const float aa  = sigf(t1a + t2b[i * 128 + l]);
        const float ab  = sigf(t1b + t2b[i * 128 + 64 + l]);
        float p = aa * qa + ab * qb2;
        #pragma unroll
        for (int off = 32; off > 0; off >>= 1) p += __shfl_down(p, off);
        const float alpha = __shfl(p, 0) + qbias;
        sga += alpha * ha; sgb += alpha * hb2v;
    }
    sg[b * 128 + l] = sga;
    sg[b * 128 + 64 + l] = sgb;
}

// s_h[b] = W3 @ [v_n[b]; s_g[b]] + b3 ; 8 sessions per block, W3 staged in LDS
__global__ __launch_bounds__(128)
void sh_kernel(const float* __restrict__ h, const float* __restrict__ sgbuf,
               const float* __restrict__ W3, const float* __restrict__ b3,
               float* __restrict__ sh) {
    __shared__ float W3s[128 * 257];
    __shared__ float vns[128], sgs[128];
    const int t = threadIdx.x;
    for (int f = t; f < 8192; f += 128) {
        const int r = f >> 6, c4 = (f & 63) * 4;
        const float4 v = *(const float4*)(W3 + (size_t)r * 256 + c4);
        float* d = &W3s[r * 257 + c4];
        d[0] = v.x; d[1] = v.y; d[2] = v.z; d[3] = v.w;
    }
    for (int bb = 0; bb < 8; ++bb) {
        const int b = blockIdx.x * 8 + bb;
        __syncthreads();
        vns[t] = h[((size_t)b * NODES_PER + 49) * 128 + t];
        sgs[t] = sgbuf[b * 128 + t];
        __syncthreads();
        float acc = b3[t];
        const float* wr = &W3s[t * 257];
        #pragma unroll 8
        for (int k = 0; k < 128; ++k) acc = fmaf(wr[k], vns[k], acc);
        #pragma unroll 8
        for (int k = 0; k < 128; ++k) acc = fmaf(wr[128 + k], sgs[k], acc);
        sh[b * 128 + t] = acc;
    }
}

extern "C" void kernel_launch(void* const* d_in, const int* in_sizes, int n_in,
                              void* d_out, int out_size, void* d_ws, size_t ws_size,
                              hipStream_t stream) {
    const int*   x   = (const int*)d_in[0];
    const int*   ei  = (const int*)d_in[1];
    // d_in[2] = batch (structure known: repeat(arange(1024), 50)) — unused
    const float* emb = (const float*)d_in[3];
    const float* Wg  = (const float*)d_in[4];
    const float* Wih = (const float*)d_in[5];
    const float* Whh = (const float*)d_in[6];
    const float* bih = (const float*)d_in[7];
    const float* bhh = (const float*)d_in[8];
    const float* W1  = (const float*)d_in[9];
    const float* b1  = (const float*)d_in[10];
    const float* W2  = (const float*)d_in[11];
    const float* b2  = (const float*)d_in[12];
    const float* qw  = (const float*)d_in[13];
    const float* qb  = (const float*)d_in[14];
    const float* W3  = (const float*)d_in[15];
    const float* b3  = (const float*)d_in[16];
    float* out = (float*)d_out;

    // workspace layout (floats); total ~119.6 MB
    float* ws   = (float*)d_ws;
    float* h    = ws;                  // 51200*128 = 6,553,600
    float* m    = h   + 6553600;       // 6,553,600  (reused as t2 later)
    float* agg  = m   + 6553600;       // 6,553,600
    float* gi   = agg + 6553600;       // 12800*384 = 4,915,200
    float* gh   = gi  + 4915200;       // 4,915,200
    float* Wgt  = gh  + 4915200;       // 16,384
    float* t1   = Wgt + 16384;         // 131,072
    float* b12  = t1  + 131072;        // 128
    float* sg   = b12 + 128;           // 131,072
    float* sh   = sg  + 131072;        // 131,072

    hipMemsetAsync(agg, 0, (size_t)6553600 * sizeof(float), stream);
    transpose128<<<64, 256, 0, stream>>>(Wg, Wgt);
    b12_kernel<<<1, 128, 0, stream>>>(b1, b2, b12);

    // h = emb[x-1]
    gather_kernel<<<6400, 256, 0, stream>>>(x, emb, h);
    // m = h @ W_gconv
    gemm_bt128<<<dim3(1, 400), 256, 0, stream>>>(m, h, Wgt, nullptr, NNODES, 128, 128);
    // agg[dst] += m[src]
    scatter_kernel<<<51200, 256, 0, stream>>>(ei, m, agg);

    // GRU over 4 node chunks of 12800
    for (int c = 0; c < 4; ++c) {
        const size_t off = (size_t)c * 12800 * 128;
        gemm_bt128<<<dim3(3, 100), 256, 0, stream>>>(gi, agg + off, Wih, bih, 12800, 384, 128);
        gemm_bt128<<<dim3(3, 100), 256, 0, stream>>>(gh, h + off,  Whh, bhh, 12800, 384, 128);
        gru_kernel<<<6400, 256, 0, stream>>>(gi, gh, h + off);
    }

    // t1[b] = v_n[b] @ W1^T + (b1+b2)   (v_n = strided rows of h)
    gemm_bt128<<<dim3(1, 8), 256, 0, stream>>>(t1, h + 49 * 128, W1, b12, NB, 128, NODES_PER * 128);
    // t2 = h @ W2^T  (into m buffer, m is dead)
    gemm_bt128<<<dim3(1, 400), 256, 0, stream>>>(m, h, W2, nullptr, NNODES, 128, 128);
    // attention readout -> sg
    attn_kernel<<<NB, 64, 0, stream>>>(h, t1, m, qw, qb, sg);
    // s_h = W3 @ [v_n; s_g] + b3
    sh_kernel<<<128, 128, 0, stream>>>(h, sg, W3, b3, sh);
    // out = s_h @ emb^T
    gemm_bt128<<<dim3(782, 8), 256, 0, stream>>>(out, sh, emb, nullptr, NB, NVOCAB, 128);
}

// Round 2
// 1216.618 us; speedup vs baseline: 1.6366x; 1.6366x over previous
//
#include <hip/hip_runtime.h>
#include <math.h>

#define NNODES 51200
#define NEDGES 409600
#define NB 1024
#define NODES_PER 50
#define NVOCAB 100000

__device__ __forceinline__ float sigf(float x) { return 1.0f / (1.0f + __expf(-x)); }

// ---------------------------------------------------------------------------
// Tiled f32 GEMM:  C[M,N] = A[M,K=128] @ B[N,K=128]^T (+bias[N])
// 512 threads (8 waves -> 2 waves/SIMD at 1 block/CU), tile 128x128,
// 4x8 acc per thread. K=128 fully staged in LDS k-major (pad 132).
// ---------------------------------------------------------------------------
__global__ __launch_bounds__(512)
void gemm_bt128(float* __restrict__ C, const float* __restrict__ A,
                const float* __restrict__ B, const float* __restrict__ bias,
                int M, int N, int strideA) {
    __shared__ float At[128][132];
    __shared__ float Bt[128][132];
    const int m0 = blockIdx.y * 128;
    const int n0 = blockIdx.x * 128;
    const int t  = threadIdx.x;

    #pragma unroll
    for (int f = t; f < 4096; f += 512) {
        const int r = f >> 5, kc = f & 31;
        const float4 v = *(const float4*)(A + (size_t)(m0 + r) * strideA + kc * 4);
        At[kc*4+0][r] = v.x; At[kc*4+1][r] = v.y;
        At[kc*4+2][r] = v.z; At[kc*4+3][r] = v.w;
    }
    #pragma unroll
    for (int f = t; f < 4096; f += 512) {
        const int c = f >> 5, kc = f & 31;
        const int n = n0 + c;
        float4 v = make_float4(0.f, 0.f, 0.f, 0.f);
        if (n < N) v = *(const float4*)(B + (size_t)n * 128 + kc * 4);
        Bt[kc*4+0][c] = v.x; Bt[kc*4+1][c] = v.y;
        Bt[kc*4+2][c] = v.z; Bt[kc*4+3][c] = v.w;
    }
    __syncthreads();

    const int tx = t & 15, ty = t >> 4;     // tx: 16 col-groups, ty: 32 row-groups
    const int r0 = ty * 4, c0 = tx * 8;
    float acc[4][8] = {};
    #pragma unroll 4
    for (int k = 0; k < 128; ++k) {
        float a[4], b[8];
        *(float4*)&a[0] = *(const float4*)&At[k][r0];
        *(float4*)&b[0] = *(const float4*)&Bt[k][c0];
        *(float4*)&b[4] = *(const float4*)&Bt[k][c0 + 4];
        #pragma unroll
        for (int i = 0; i < 4; ++i)
            #pragma unroll
            for (int j = 0; j < 8; ++j)
                acc[i][j] = fmaf(a[i], b[j], acc[i][j]);
    }

    if (n0 + 128 <= N) {
        #pragma unroll
        for (int i = 0; i < 4; ++i) {
            float* crow = C + (size_t)(m0 + r0 + i) * N + n0 + c0;
            float bv[8];
            #pragma unroll
            for (int j = 0; j < 8; ++j) bv[j] = acc[i][j] + (bias ? bias[n0 + c0 + j] : 0.f);
            *(float4*)(crow)     = make_float4(bv[0], bv[1], bv[2], bv[3]);
            *(float4*)(crow + 4) = make_float4(bv[4], bv[5], bv[6], bv[7]);
        }
    } else {
        #pragma unroll
        for (int i = 0; i < 4; ++i) {
            float* crow = C + (size_t)(m0 + r0 + i) * N + n0 + c0;
            #pragma unroll
            for (int j = 0; j < 8; ++j) {
                const int n = n0 + c0 + j;
                if (n < N) crow[j] = acc[i][j] + (bias ? bias[n] : 0.f);
            }
        }
    }
}

// h[i][:] = emb[x[i]-1][:]
__global__ __launch_bounds__(256)
void gather_kernel(const int* __restrict__ x, const float* __restrict__ emb,
                   float* __restrict__ h) {
    const int tid = blockIdx.x * 256 + threadIdx.x;
    const int i = tid >> 5, c = (tid & 31) * 4;
    const int idx = x[i] - 1;
    *(float4*)(h + (size_t)i * 128 + c) = *(const float4*)(emb + (size_t)idx * 128 + c);
}

__global__ __launch_bounds__(256)
void transpose128(const float* __restrict__ W, float* __restrict__ Wt) {
    const int tid = blockIdx.x * 256 + threadIdx.x;
    const int k = tid >> 7, n = tid & 127;
    Wt[(size_t)n * 128 + k] = W[tid];
}

__global__ void b12_kernel(const float* __restrict__ b1, const float* __restrict__ b2,
                           float* __restrict__ b12) {
    const int t = threadIdx.x;
    b12[t] = b1[t] + b2[t];
}

// ---------------- CSR build: histogram -> scan -> fill ----------------
__global__ __launch_bounds__(256)
void hist_kernel(const int* __restrict__ ei, int* __restrict__ deg) {
    const int e = blockIdx.x * 256 + threadIdx.x;
    atomicAdd(&deg[ei[NEDGES + e]], 1);
}

__global__ __launch_bounds__(256)
void blocksum_kernel(const int* __restrict__ deg, int* __restrict__ bsum) {
    __shared__ int s[256];
    const int t = threadIdx.x;
    s[t] = deg[blockIdx.x * 256 + t];
    __syncthreads();
    for (int off = 128; off > 0; off >>= 1) {
        if (t < off) s[t] += s[t + off];
        __syncthreads();
    }
    if (t == 0) bsum[blockIdx.x] = s[0];
}

__global__ void scan_bsum_kernel(int* __restrict__ bsum) {   // exclusive, 200 elems
    if (threadIdx.x == 0) {
        int acc = 0;
        for (int i = 0; i < 200; ++i) { const int v = bsum[i]; bsum[i] = acc; acc += v; }
    }
}

__global__ __launch_bounds__(256)
void scan_kernel(const int* __restrict__ deg, const int* __restrict__ bsum,
                 int* __restrict__ offs, int* __restrict__ cursor) {
    __shared__ int s[256];
    const int t = threadIdx.x;
    const int i = blockIdx.x * 256 + t;
    const int v = deg[i];
    s[t] = v;
    __syncthreads();
    for (int off = 1; off < 256; off <<= 1) {     // inclusive Hillis-Steele
        const int add = (t >= off) ? s[t - off] : 0;
        __syncthreads();
        s[t] += add;
        __syncthreads();
    }
    const int excl = s[t] - v + bsum[blockIdx.x];
    offs[i] = excl;
    cursor[i] = excl;
    if (blockIdx.x == 199 && t == 255) offs[NNODES] = excl + v;
}

__global__ __launch_bounds__(256)
void fill_kernel(const int* __restrict__ ei, int* __restrict__ cursor,
                 int* __restrict__ esrc) {
    const int e = blockIdx.x * 256 + threadIdx.x;
    const int dst = ei[NEDGES + e];
    const int pos = atomicAdd(&cursor[dst], 1);
    esrc[pos] = ei[e];
}

// agg[i] = sum over in-edges of m[src]; one wave per node, float2 per lane
__global__ __launch_bounds__(256)
void agg_kernel(const int* __restrict__ offs, const int* __restrict__ esrc,
                const float* __restrict__ m, float* __restrict__ agg) {
    const int node = blockIdx.x * 4 + (threadIdx.x >> 6);
    const int l = threadIdx.x & 63;
    const int s = offs[node], e = offs[node + 1];
    float2 acc = make_float2(0.f, 0.f);
    for (int j = s; j < e; ++j) {
        const int src = esrc[j];
        const float2 v = *(const float2*)(m + (size_t)src * 128 + l * 2);
        acc.x += v.x; acc.y += v.y;
    }
    *(float2*)(agg + (size_t)node * 128 + l * 2) = acc;
}

// GRU elementwise over one 12800-node chunk; h updated in place, then ReLU
__global__ __launch_bounds__(256)
void gru_kernel(const float* __restrict__ gi, const float* __restrict__ gh,
                float* __restrict__ h) {
    const int tid = blockIdx.x * 256 + threadIdx.x;
    const int i = tid >> 7, j = tid & 127;
    const size_t gb = (size_t)i * 384;
    const float ir = gi[gb + j], iz = gi[gb + 128 + j], in_ = gi[gb + 256 + j];
    const float hr = gh[gb + j], hz = gh[gb + 128 + j], hn  = gh[gb + 256 + j];
    const float hv = h[(size_t)i * 128 + j];
    const float r  = sigf(ir + hr);
    const float z  = sigf(iz + hz);
    const float ng = tanhf(in_ + r * hn);
    const float o  = (1.f - z) * ng + z * hv;
    h[(size_t)i * 128 + j] = fmaxf(o, 0.f);
}

// Per-session attention readout: one wave per session.
__global__ __launch_bounds__(64)
void attn_kernel(const float* __restrict__ h, const float* __restrict__ t1,
                 const float* __restrict__ t2, const float* __restrict__ qw,
                 const float* __restrict__ qbp, float* __restrict__ sg) {
    const int b = blockIdx.x, l = threadIdx.x;
    const float t1a = t1[b * 128 + l], t1b = t1[b * 128 + 64 + l];
    const float qa = qw[l], qb2 = qw[64 + l];
    const float qbias = qbp[0];
    const float* hb  = h  + (size_t)b * NODES_PER * 128;
    const float* t2b = t2 + (size_t)b * NODES_PER * 128;
    float sga = 0.f, sgb = 0.f;
    for (int i = 0; i < NODES_PER; ++i) {
        const float ha  = hb[i * 128 + l], hb2v = hb[i * 128 + 64 + l];
        const float aa  = sigf(t1a + t2b[i * 128 + l]);
        const float ab  = sigf(t1b + t2b[i * 128 + 64 + l]);
        float p = aa * qa + ab * qb2;
        #pragma unroll
        for (int off = 32; off > 0; off >>= 1) p += __shfl_down(p, off);
        const float alpha = __shfl(p, 0) + qbias;
        sga += alpha * ha; sgb += alpha * hb2v;
    }
    sg[b * 128 + l] = sga;
    sg[b * 128 + 64 + l] = sgb;
}

// s_h[b] = W3 @ [v_n[b]; s_g[b]] + b3
__global__ __launch_bounds__(128)
void sh_kernel(const float* __restrict__ h, const float* __restrict__ sgbuf,
               const float* __restrict__ W3, const float* __restrict__ b3,
               float* __restrict__ sh) {
    __shared__ float W3s[128 * 257];
    __shared__ float vns[128], sgs[128];
    const int t = threadIdx.x;
    for (int f = t; f < 8192; f += 128) {
        const int r = f >> 6, c4 = (f & 63) * 4;
        const float4 v = *(const float4*)(W3 + (size_t)r * 256 + c4);
        float* d = &W3s[r * 257 + c4];
        d[0] = v.x; d[1] = v.y; d[2] = v.z; d[3] = v.w;
    }
    for (int bb = 0; bb < 8; ++bb) {
        const int b = blockIdx.x * 8 + bb;
        __syncthreads();
        vns[t] = h[((size_t)b * NODES_PER + 49) * 128 + t];
        sgs[t] = sgbuf[b * 128 + t];
        __syncthreads();
        float acc = b3[t];
        const float* wr = &W3s[t * 257];
        #pragma unroll 8
        for (int k = 0; k < 128; ++k) acc = fmaf(wr[k], vns[k], acc);
        #pragma unroll 8
        for (int k = 0; k < 128; ++k) acc = fmaf(wr[128 + k], sgs[k], acc);
        sh[b * 128 + t] = acc;
    }
}

extern "C" void kernel_launch(void* const* d_in, const int* in_sizes, int n_in,
                              void* d_out, int out_size, void* d_ws, size_t ws_size,
                              hipStream_t stream) {
    const int*   x   = (const int*)d_in[0];
    const int*   ei  = (const int*)d_in[1];
    const float* emb = (const float*)d_in[3];
    const float* Wg  = (const float*)d_in[4];
    const float* Wih = (const float*)d_in[5];
    const float* Whh = (const float*)d_in[6];
    const float* bih = (const float*)d_in[7];
    const float* bhh = (const float*)d_in[8];
    const float* W1  = (const float*)d_in[9];
    const float* b1  = (const float*)d_in[10];
    const float* W2  = (const float*)d_in[11];
    const float* b2  = (const float*)d_in[12];
    const float* qw  = (const float*)d_in[13];
    const float* qb  = (const float*)d_in[14];
    const float* W3  = (const float*)d_in[15];
    const float* b3  = (const float*)d_in[16];
    float* out = (float*)d_out;

    // workspace layout (floats); ~118 MB
    float* ws   = (float*)d_ws;
    float* h    = ws;                  // 6,553,600
    float* m    = h   + 6553600;       // 6,553,600  (reused as t2 later)
    float* agg  = m   + 6553600;       // 6,553,600
    float* gi   = agg + 6553600;       // 4,915,200
    float* gh   = gi  + 4915200;       // 4,915,200
    float* Wgt  = gh  + 4915200;       // 16,384
    float* t1   = Wgt + 16384;         // 131,072
    float* b12  = t1  + 131072;        // 128
    float* sg   = b12 + 128;           // 131,072
    float* sh   = sg  + 131072;        // 131,072

    // CSR int buffers ALIAS gi/gh scratch (dead until the GRU phase;
    // esrc is consumed by agg_kernel which completes before the GRU GEMMs)
    int* ints   = (int*)gi;
    int* deg    = ints;                // 51,200
    int* offs   = deg + NNODES;        // 51,201
    int* cursor = offs + NNODES + 1;   // 51,200
    int* esrc   = cursor + NNODES;     // 409,600
    int* bsum   = esrc + NEDGES;       // 200

    hipMemsetAsync(deg, 0, NNODES * sizeof(int), stream);
    transpose128<<<64, 256, 0, stream>>>(Wg, Wgt);
    b12_kernel<<<1, 128, 0, stream>>>(b1, b2, b12);

    // h = emb[x-1]
    gather_kernel<<<6400, 256, 0, stream>>>(x, emb, h);
    // m = h @ W_gconv
    gemm_bt128<<<dim3(1, 400), 512, 0, stream>>>(m, h, Wgt, nullptr, NNODES, 128, 128);

    // CSR build + gather-sum (replaces atomic scatter)
    hist_kernel<<<1600, 256, 0, stream>>>(ei, deg);
    blocksum_kernel<<<200, 256, 0, stream>>>(deg, bsum);
    scan_bsum_kernel<<<1, 64, 0, stream>>>(bsum);
    scan_kernel<<<200, 256, 0, stream>>>(deg, bsum, offs, cursor);
    fill_kernel<<<1600, 256, 0, stream>>>(ei, cursor, esrc);
    agg_kernel<<<12800, 256, 0, stream>>>(offs, esrc, m, agg);

    // GRU over 4 node chunks of 12800
    for (int c = 0; c < 4; ++c) {
        const size_t off = (size_t)c * 12800 * 128;
        gemm_bt128<<<dim3(3, 100), 512, 0, stream>>>(gi, agg + off, Wih, bih, 12800, 384, 128);
        gemm_bt128<<<dim3(3, 100), 512, 0, stream>>>(gh, h + off,  Whh, bhh, 12800, 384, 128);
        gru_kernel<<<6400, 256, 0, stream>>>(gi, gh, h + off);
    }

    // t1[b] = v_n[b] @ W1^T + (b1+b2)
    gemm_bt128<<<dim3(1, 8), 512, 0, stream>>>(t1, h + 49 * 128, W1, b12, NB, 128, NODES_PER * 128);
    // t2 = h @ W2^T (into m, m is dead)
    gemm_bt128<<<dim3(1, 400), 512, 0, stream>>>(m, h, W2, nullptr, NNODES, 128, 128);
    attn_kernel<<<NB, 64, 0, stream>>>(h, t1, m, qw, qb, sg);
    sh_kernel<<<128, 128, 0, stream>>>(h, sg, W3, b3, sh);
    // out = s_h @ emb^T
    gemm_bt128<<<dim3(782, 8), 512, 0, stream>>>(out, sh, emb, nullptr, NB, NVOCAB, 128);
}

// Round 3
// 562.665 us; speedup vs baseline: 3.5386x; 2.1622x over previous
//
#include <hip/hip_runtime.h>
#include <math.h>

#define NNODES 51200
#define NEDGES 409600
#define NB 1024
#define NODES_PER 50
#define NVOCAB 100000

typedef __attribute__((ext_vector_type(8))) short bf16x8;
typedef __attribute__((ext_vector_type(4))) float f32x4;

__device__ __forceinline__ float sigf(float x) { return 1.0f / (1.0f + __expf(-x)); }

__device__ __forceinline__ ushort f2bf(float x) {   // RTNE f32 -> bf16
    union { float f; unsigned u; } v; v.f = x;
    const unsigned r = v.u + 0x7FFF + ((v.u >> 16) & 1);
    return (ushort)(r >> 16);
}

// ---------------------------------------------------------------------------
// bf16-MFMA GEMM: C[M,N] = A[M,K=128] @ B[N,K=128]^T (+bias[N]), f32 in/out.
// 256 thr = 4 waves in 2x2; tile 128x128; K=128 fully staged (one stage).
// LDS [128 rows][128 bf16] with XOR swizzle: short_col ^= (row&7)<<3
// -> balanced ds_read_b128 (8 lanes/bank-quad = minimum). Reg-staged
// f32->bf16 conversion, so swizzle applied on both write and read.
// M must be a multiple of 128 (all call sites); N ragged-guarded.
// ---------------------------------------------------------------------------
__global__ __launch_bounds__(256)
void gemm_mfma_bt(float* __restrict__ C, const float* __restrict__ A,
                  const float* __restrict__ B, const float* __restrict__ bias,
                  int M, int N, int strideA) {
    __shared__ short As[128 * 128];
    __shared__ short Bs[128 * 128];
    const int m0 = blockIdx.x * 128;   // m fast -> consecutive blocks share B tile
    const int n0 = blockIdx.y * 128;
    const int t  = threadIdx.x;

    // stage A (f32 -> bf16, swizzled)
    #pragma unroll
    for (int f = t; f < 2048; f += 256) {
        const int r = f >> 4, c8 = (f & 15) * 8;
        const float* src = A + (size_t)(m0 + r) * strideA + c8;
        const float4 v0 = *(const float4*)(src);
        const float4 v1 = *(const float4*)(src + 4);
        bf16x8 pk;
        pk[0] = (short)f2bf(v0.x); pk[1] = (short)f2bf(v0.y);
        pk[2] = (short)f2bf(v0.z); pk[3] = (short)f2bf(v0.w);
        pk[4] = (short)f2bf(v1.x); pk[5] = (short)f2bf(v1.y);
        pk[6] = (short)f2bf(v1.z); pk[7] = (short)f2bf(v1.w);
        *(bf16x8*)&As[r * 128 + (c8 ^ ((r & 7) << 3))] = pk;
    }
    // stage B (guard n < N, zero-fill)
    #pragma unroll
    for (int f = t; f < 2048; f += 256) {
        const int r = f >> 4, c8 = (f & 15) * 8;
        const int n = n0 + r;
        bf16x8 pk = {0, 0, 0, 0, 0, 0, 0, 0};
        if (n < N) {
            const float* src = B + (size_t)n * 128 + c8;
            const float4 v0 = *(const float4*)(src);
            const float4 v1 = *(const float4*)(src + 4);
            pk[0] = (short)f2bf(v0.x); pk[1] = (short)f2bf(v0.y);
            pk[2] = (short)f2bf(v0.z); pk[3] = (short)f2bf(v0.w);
            pk[4] = (short)f2bf(v1.x); pk[5] = (short)f2bf(v1.y);
            pk[6] = (short)f2bf(v1.z); pk[7] = (short)f2bf(v1.w);
        }
        *(bf16x8*)&Bs[r * 128 + (c8 ^ ((r & 7) << 3))] = pk;
    }
    __syncthreads();

    const int lane = t & 63, wid = t >> 6;
    const int wr = wid >> 1, wc = wid & 1;          // 2x2 waves, 64x64 each
    const int l15 = lane & 15, kg = (lane >> 4) * 8;

    f32x4 acc[4][4] = {};
    #pragma unroll
    for (int kc = 0; kc < 4; ++kc) {
        const int cs = kc * 32 + kg;                 // short col within K
        bf16x8 af[4], bfr[4];
        #pragma unroll
        for (int i = 0; i < 4; ++i) {
            const int ra = wr * 64 + i * 16 + l15;
            af[i] = *(const bf16x8*)&As[ra * 128 + (cs ^ ((ra & 7) << 3))];
            const int rb = wc * 64 + i * 16 + l15;
            bfr[i] = *(const bf16x8*)&Bs[rb * 128 + (cs ^ ((rb & 7) << 3))];
        }
        #pragma unroll
        for (int i = 0; i < 4; ++i)
            #pragma unroll
            for (int j = 0; j < 4; ++j)
                acc[i][j] = __builtin_amdgcn_mfma_f32_16x16x32_bf16(af[i], bfr[j], acc[i][j], 0, 0, 0);
    }

    // epilogue: C/D layout col=lane&15, row=(lane>>4)*4+reg
    const int cr0 = (lane >> 4) * 4;
    #pragma unroll
    for (int j = 0; j < 4; ++j) {
        const int col = n0 + wc * 64 + j * 16 + l15;
        if (col < N) {
            const float bv = bias ? bias[col] : 0.f;
            #pragma unroll
            for (int i = 0; i < 4; ++i) {
                const size_t rbase = (size_t)(m0 + wr * 64 + i * 16 + cr0) * N + col;
                #pragma unroll
                for (int q = 0; q < 4; ++q)
                    C[rbase + (size_t)q * N] = acc[i][j][q] + bv;
            }
        }
    }
}

// h[i][:] = emb[x[i]-1][:]
__global__ __launch_bounds__(256)
void gather_kernel(const int* __restrict__ x, const float* __restrict__ emb,
                   float* __restrict__ h) {
    const int tid = blockIdx.x * 256 + threadIdx.x;
    const int i = tid >> 5, c = (tid & 31) * 4;
    const int idx = x[i] - 1;
    *(float4*)(h + (size_t)i * 128 + c) = *(const float4*)(emb + (size_t)idx * 128 + c);
}

__global__ __launch_bounds__(256)
void transpose128(const float* __restrict__ W, float* __restrict__ Wt) {
    const int tid = blockIdx.x * 256 + threadIdx.x;
    const int k = tid >> 7, n = tid & 127;
    Wt[(size_t)n * 128 + k] = W[tid];
}

__global__ void b12_kernel(const float* __restrict__ b1, const float* __restrict__ b2,
                           float* __restrict__ b12) {
    const int t = threadIdx.x;
    b12[t] = b1[t] + b2[t];
}

// ---------------- CSR build: histogram -> scan -> fill ----------------
__global__ __launch_bounds__(256)
void hist_kernel(const int* __restrict__ ei, int* __restrict__ deg) {
    const int e = blockIdx.x * 256 + threadIdx.x;
    atomicAdd(&deg[ei[NEDGES + e]], 1);
}

__global__ __launch_bounds__(256)
void blocksum_kernel(const int* __restrict__ deg, int* __restrict__ bsum) {
    __shared__ int s[256];
    const int t = threadIdx.x;
    s[t] = deg[blockIdx.x * 256 + t];
    __syncthreads();
    for (int off = 128; off > 0; off >>= 1) {
        if (t < off) s[t] += s[t + off];
        __syncthreads();
    }
    if (t == 0) bsum[blockIdx.x] = s[0];
}

__global__ void scan_bsum_kernel(int* __restrict__ bsum) {   // exclusive, 200 elems
    if (threadIdx.x == 0) {
        int acc = 0;
        for (int i = 0; i < 200; ++i) { const int v = bsum[i]; bsum[i] = acc; acc += v; }
    }
}

__global__ __launch_bounds__(256)
void scan_kernel(const int* __restrict__ deg, const int* __restrict__ bsum,
                 int* __restrict__ offs, int* __restrict__ cursor) {
    __shared__ int s[256];
    const int t = threadIdx.x;
    const int i = blockIdx.x * 256 + t;
    const int v = deg[i];
    s[t] = v;
    __syncthreads();
    for (int off = 1; off < 256; off <<= 1) {
        const int add = (t >= off) ? s[t - off] : 0;
        __syncthreads();
        s[t] += add;
        __syncthreads();
    }
    const int excl = s[t] - v + bsum[blockIdx.x];
    offs[i] = excl;
    cursor[i] = excl;
    if (blockIdx.x == 199 && t == 255) offs[NNODES] = excl + v;
}

__global__ __launch_bounds__(256)
void fill_kernel(const int* __restrict__ ei, int* __restrict__ cursor,
                 int* __restrict__ esrc) {
    const int e = blockIdx.x * 256 + threadIdx.x;
    const int dst = ei[NEDGES + e];
    const int pos = atomicAdd(&cursor[dst], 1);
    esrc[pos] = ei[e];
}

// agg[i] = sum over in-edges of m[src]; one wave per node
__global__ __launch_bounds__(256)
void agg_kernel(const int* __restrict__ offs, const int* __restrict__ esrc,
                const float* __restrict__ m, float* __restrict__ agg) {
    const int node = blockIdx.x * 4 + (threadIdx.x >> 6);
    const int l = threadIdx.x & 63;
    const int s = offs[node], e = offs[node + 1];
    float2 acc = make_float2(0.f, 0.f);
    for (int j = s; j < e; ++j) {
        const int src = esrc[j];
        const float2 v = *(const float2*)(m + (size_t)src * 128 + l * 2);
        acc.x += v.x; acc.y += v.y;
    }
    *(float2*)(agg + (size_t)node * 128 + l * 2) = acc;
}

// GRU elementwise over one 12800-node chunk; h updated in place, then ReLU
__global__ __launch_bounds__(256)
void gru_kernel(const float* __restrict__ gi, const float* __restrict__ gh,
                float* __restrict__ h) {
    const int tid = blockIdx.x * 256 + threadIdx.x;
    const int i = tid >> 7, j = tid & 127;
    const size_t gb = (size_t)i * 384;
    const float ir = gi[gb + j], iz = gi[gb + 128 + j], in_ = gi[gb + 256 + j];
    const float hr = gh[gb + j], hz = gh[gb + 128 + j], hn  = gh[gb + 256 + j];
    const float hv = h[(size_t)i * 128 + j];
    const float r  = sigf(ir + hr);
    const float z  = sigf(iz + hz);
    const float ng = tanhf(in_ + r * hn);
    const float o  = (1.f - z) * ng + z * hv;
    h[(size_t)i * 128 + j] = fmaxf(o, 0.f);
}

// Per-session attention readout: one wave per session.
__global__ __launch_bounds__(64)
void attn_kernel(const float* __restrict__ h, const float* __restrict__ t1,
                 const float* __restrict__ t2, const float* __restrict__ qw,
                 const float* __restrict__ qbp, float* __restrict__ sg) {
    const int b = blockIdx.x, l = threadIdx.x;
    const float t1a = t1[b * 128 + l], t1b = t1[b * 128 + 64 + l];
    const float qa = qw[l], qb2 = qw[64 + l];
    const float qbias = qbp[0];
    const float* hb  = h  + (size_t)b * NODES_PER * 128;
    const float* t2b = t2 + (size_t)b * NODES_PER * 128;
    float sga = 0.f, sgb = 0.f;
    for (int i = 0; i < NODES_PER; ++i) {
        const float ha  = hb[i * 128 + l], hb2v = hb[i * 128 + 64 + l];
        const float aa  = sigf(t1a + t2b[i * 128 + l]);
        const float ab  = sigf(t1b + t2b[i * 128 + 64 + l]);
        float p = aa * qa + ab * qb2;
        #pragma unroll
        for (int off = 32; off > 0; off >>= 1) p += __shfl_down(p, off);
        const float alpha = __shfl(p, 0) + qbias;
        sga += alpha * ha; sgb += alpha * hb2v;
    }
    sg[b * 128 + l] = sga;
    sg[b * 128 + 64 + l] = sgb;
}

// s_h[b] = W3 @ [v_n[b]; s_g[b]] + b3
__global__ __launch_bounds__(128)
void sh_kernel(const float* __restrict__ h, const float* __restrict__ sgbuf,
               const float* __restrict__ W3, const float* __restrict__ b3,
               float* __restrict__ sh) {
    __shared__ float W3s[128 * 257];
    __shared__ float vns[128], sgs[128];
    const int t = threadIdx.x;
    for (int f = t; f < 8192; f += 128) {
        const int r = f >> 6, c4 = (f & 63) * 4;
        const float4 v = *(const float4*)(W3 + (size_t)r * 256 + c4);
        float* d = &W3s[r * 257 + c4];
        d[0] = v.x; d[1] = v.y; d[2] = v.z; d[3] = v.w;
    }
    for (int bb = 0; bb < 8; ++bb) {
        const int b = blockIdx.x * 8 + bb;
        __syncthreads();
        vns[t] = h[((size_t)b * NODES_PER + 49) * 128 + t];
        sgs[t] = sgbuf[b * 128 + t];
        __syncthreads();
        float acc = b3[t];
        const float* wr = &W3s[t * 257];
        #pragma unroll 8
        for (int k = 0; k < 128; ++k) acc = fmaf(wr[k], vns[k], acc);
        #pragma unroll 8
        for (int k = 0; k < 128; ++k) acc = fmaf(wr[128 + k], sgs[k], acc);
        sh[b * 128 + t] = acc;
    }
}

extern "C" void kernel_launch(void* const* d_in, const int* in_sizes, int n_in,
                              void* d_out, int out_size, void* d_ws, size_t ws_size,
                              hipStream_t stream) {
    const int*   x   = (const int*)d_in[0];
    const int*   ei  = (const int*)d_in[1];
    const float* emb = (const float*)d_in[3];
    const float* Wg  = (const float*)d_in[4];
    const float* Wih = (const float*)d_in[5];
    const float* Whh = (const float*)d_in[6];
    const float* bih = (const float*)d_in[7];
    const float* bhh = (const float*)d_in[8];
    const float* W1  = (const float*)d_in[9];
    const float* b1  = (const float*)d_in[10];
    const float* W2  = (const float*)d_in[11];
    const float* b2  = (const float*)d_in[12];
    const float* qw  = (const float*)d_in[13];
    const float* qb  = (const float*)d_in[14];
    const float* W3  = (const float*)d_in[15];
    const float* b3  = (const float*)d_in[16];
    float* out = (float*)d_out;

    // workspace layout (floats); ~118 MB
    float* ws   = (float*)d_ws;
    float* h    = ws;                  // 6,553,600
    float* m    = h   + 6553600;       // 6,553,600  (reused as t2 later)
    float* agg  = m   + 6553600;       // 6,553,600
    float* gi   = agg + 6553600;       // 4,915,200
    float* gh   = gi  + 4915200;       // 4,915,200
    float* Wgt  = gh  + 4915200;       // 16,384
    float* t1   = Wgt + 16384;         // 131,072
    float* b12  = t1  + 131072;        // 128
    float* sg   = b12 + 128;           // 131,072
    float* sh   = sg  + 131072;        // 131,072

    // CSR int buffers alias gi/gh scratch (dead until GRU phase)
    int* ints   = (int*)gi;
    int* deg    = ints;
    int* offs   = deg + NNODES;
    int* cursor = offs + NNODES + 1;
    int* esrc   = cursor + NNODES;
    int* bsum   = esrc + NEDGES;

    hipMemsetAsync(deg, 0, NNODES * sizeof(int), stream);
    transpose128<<<64, 256, 0, stream>>>(Wg, Wgt);
    b12_kernel<<<1, 128, 0, stream>>>(b1, b2, b12);

    // h = emb[x-1]
    gather_kernel<<<6400, 256, 0, stream>>>(x, emb, h);
    // m = h @ W_gconv
    gemm_mfma_bt<<<dim3(400, 1), 256, 0, stream>>>(m, h, Wgt, nullptr, NNODES, 128, 128);

    // CSR build + gather-sum
    hist_kernel<<<1600, 256, 0, stream>>>(ei, deg);
    blocksum_kernel<<<200, 256, 0, stream>>>(deg, bsum);
    scan_bsum_kernel<<<1, 64, 0, stream>>>(bsum);
    scan_kernel<<<200, 256, 0, stream>>>(deg, bsum, offs, cursor);
    fill_kernel<<<1600, 256, 0, stream>>>(ei, cursor, esrc);
    agg_kernel<<<12800, 256, 0, stream>>>(offs, esrc, m, agg);

    // GRU over 4 node chunks of 12800
    for (int c = 0; c < 4; ++c) {
        const size_t off = (size_t)c * 12800 * 128;
        gemm_mfma_bt<<<dim3(100, 3), 256, 0, stream>>>(gi, agg + off, Wih, bih, 12800, 384, 128);
        gemm_mfma_bt<<<dim3(100, 3), 256, 0, stream>>>(gh, h + off,  Whh, bhh, 12800, 384, 128);
        gru_kernel<<<6400, 256, 0, stream>>>(gi, gh, h + off);
    }

    // t1[b] = v_n[b] @ W1^T + (b1+b2)
    gemm_mfma_bt<<<dim3(8, 1), 256, 0, stream>>>(t1, h + 49 * 128, W1, b12, NB, 128, NODES_PER * 128);
    // t2 = h @ W2^T (into m, m is dead)
    gemm_mfma_bt<<<dim3(400, 1), 256, 0, stream>>>(m, h, W2, nullptr, NNODES, 128, 128);
    attn_kernel<<<NB, 64, 0, stream>>>(h, t1, m, qw, qb, sg);
    sh_kernel<<<128, 128, 0, stream>>>(h, sg, W3, b3, sh);
    // out = s_h @ emb^T
    gemm_mfma_bt<<<dim3(8, 782), 256, 0, stream>>>(out, sh, emb, nullptr, NB, NVOCAB, 128);
}

// Round 5
// 528.545 us; speedup vs baseline: 3.7671x; 1.0646x over previous
//
#include <hip/hip_runtime.h>
#include <math.h>

#define NNODES 51200
#define NEDGES 409600
#define NB 1024
#define NODES_PER 50
#define NVOCAB 100000
#define CHUNK 25600

typedef __attribute__((ext_vector_type(8))) short bf16x8;
typedef __attribute__((ext_vector_type(4))) float f32x4;

__device__ __forceinline__ float sigf(float x) { return 1.0f / (1.0f + __expf(-x)); }

__device__ __forceinline__ ushort f2bf(float x) {   // RTNE f32 -> bf16
    union { float f; unsigned u; } v; v.f = x;
    const unsigned r = v.u + 0x7FFF + ((v.u >> 16) & 1);
    return (ushort)(r >> 16);
}
__device__ __forceinline__ float bf2f(ushort u) {
    union { float f; unsigned u; } v; v.u = ((unsigned)u) << 16; return v.f;
}
__device__ __forceinline__ bf16x8 cvt8(const float* __restrict__ src) {
    const float4 v0 = *(const float4*)src, v1 = *(const float4*)(src + 4);
    bf16x8 p;
    p[0] = (short)f2bf(v0.x); p[1] = (short)f2bf(v0.y);
    p[2] = (short)f2bf(v0.z); p[3] = (short)f2bf(v0.w);
    p[4] = (short)f2bf(v1.x); p[5] = (short)f2bf(v1.y);
    p[6] = (short)f2bf(v1.z); p[7] = (short)f2bf(v1.w);
    return p;
}

// ---------------------------------------------------------------------------
// bf16-MFMA GEMM, tile 128x128, 256 thr (4 waves 2x2), K=128 one stage.
// LDS XOR swizzle (short_col ^= (row&7)<<3). Epilogue repacks acc via LDS
// (aliased over As/Bs after a barrier) for fully coalesced global stores.
// OUT_MODE: 0 = f32 out (+opt bias, nontemporal), 1 = bf16 out.
// B_TRANSP: stage B[n][k] from W[k][n] (for W_gconv).
// ---------------------------------------------------------------------------
template<int OUT_MODE, bool B_TRANSP>
__global__ __launch_bounds__(256)
void gemm_tile(void* __restrict__ Cout, const float* __restrict__ A,
               const float* __restrict__ B, const float* __restrict__ bias,
               int M, int N, int strideA) {
    __shared__ float4 smemv[4224];                 // 67,584 B
    ushort* As = (ushort*)smemv;                   // [128*128]
    ushort* Bs = As + 128 * 128;
    const int m0 = blockIdx.x * 128;
    const int n0 = blockIdx.y * 128;
    const int t  = threadIdx.x;

    #pragma unroll
    for (int f = t; f < 2048; f += 256) {
        const int r = f >> 4, c8 = (f & 15) * 8;
        const bf16x8 pk = cvt8(A + (size_t)(m0 + r) * strideA + c8);
        *(bf16x8*)&As[r * 128 + (c8 ^ ((r & 7) << 3))] = pk;
    }
    #pragma unroll
    for (int f = t; f < 2048; f += 256) {
        const int r = f >> 4, c8 = (f & 15) * 8;
        const int n = n0 + r;
        bf16x8 pk = {0, 0, 0, 0, 0, 0, 0, 0};
        if (n < N) {
            if (B_TRANSP) {
                #pragma unroll
                for (int d = 0; d < 8; ++d)
                    pk[d] = (short)f2bf(B[(size_t)(c8 + d) * 128 + n]);
            } else {
                pk = cvt8(B + (size_t)n * 128 + c8);
            }
        }
        *(bf16x8*)&Bs[r * 128 + (c8 ^ ((r & 7) << 3))] = pk;
    }
    __syncthreads();

    const int lane = t & 63, wid = t >> 6;
    const int wr = wid >> 1, wc = wid & 1;
    const int l15 = lane & 15, kg = (lane >> 4) * 8;

    f32x4 acc[4][4] = {};
    #pragma unroll
    for (int kc = 0; kc < 4; ++kc) {
        const int cs = kc * 32 + kg;
        bf16x8 af[4], bfr[4];
        #pragma unroll
        for (int i = 0; i < 4; ++i) {
            const int ra = wr * 64 + i * 16 + l15;
            af[i] = *(const bf16x8*)&As[ra * 128 + (cs ^ ((ra & 7) << 3))];
            const int rb = wc * 64 + i * 16 + l15;
            bfr[i] = *(const bf16x8*)&Bs[rb * 128 + (cs ^ ((rb & 7) << 3))];
        }
        #pragma unroll
        for (int i = 0; i < 4; ++i)
            #pragma unroll
            for (int j = 0; j < 4; ++j)
                acc[i][j] = __builtin_amdgcn_mfma_f32_16x16x32_bf16(af[i], bfr[j], acc[i][j], 0, 0, 0);
    }

    __syncthreads();                               // done reading As/Bs; reuse LDS
    const int cr0 = (lane >> 4) * 4;

    if (OUT_MODE == 1) {
        ushort* Cs = (ushort*)smemv;               // [128][128] bf16
        #pragma unroll
        for (int i = 0; i < 4; ++i)
            #pragma unroll
            for (int j = 0; j < 4; ++j)
                #pragma unroll
                for (int q = 0; q < 4; ++q)
                    Cs[(wr * 64 + i * 16 + cr0 + q) * 128 + (wc * 64 + j * 16 + l15)] =
                        f2bf(acc[i][j][q]);
        __syncthreads();
        ushort* Cb = (ushort*)Cout;
        #pragma unroll
        for (int f = t; f < 2048; f += 256) {
            const int r = f >> 4, c8 = (f & 15) * 8;
            *(bf16x8*)(Cb + (size_t)(m0 + r) * 128 + c8) = *(bf16x8*)&Cs[r * 128 + c8];
        }
    } else {
        float* Cs = (float*)smemv;                 // [128][132] f32 (row stride 132 => 16B-aligned rows)
        #pragma unroll
        for (int i = 0; i < 4; ++i)
            #pragma unroll
            for (int j = 0; j < 4; ++j)
                #pragma unroll
                for (int q = 0; q < 4; ++q)
                    Cs[(wr * 64 + i * 16 + cr0 + q) * 132 + (wc * 64 + j * 16 + l15)] =
                        acc[i][j][q];
        __syncthreads();
        float* C = (float*)Cout;
        #pragma unroll
        for (int f = t; f < 2048; f += 256) {
            const int r = f >> 4, c8 = (f & 15) * 8;
            const int col = n0 + c8;
            if (col < N) {
                f32x4 v0 = *(f32x4*)&Cs[r * 132 + c8];
                f32x4 v1 = *(f32x4*)&Cs[r * 132 + c8 + 4];
                if (bias) {
                    v0 += *(const f32x4*)&bias[col];
                    v1 += *(const f32x4*)&bias[col + 4];
                }
                f32x4* dst = (f32x4*)(C + (size_t)(m0 + r) * N + col);
                __builtin_nontemporal_store(v0, dst);
                if (col + 4 < N) __builtin_nontemporal_store(v1, dst + 1);
            }
        }
    }
}

// ---------------------------------------------------------------------------
// 512-thr 128x384 GEMM against W[384][128] (f32), 8 waves x (16 rows x 384).
// MODE 0 (GI): A = bf16 agg chunk; writes gi[rloc][0..384) f32 + bias.
// MODE 1 (GRU): A = f32 h chunk (gh = h@Whh^T + bhh in-register); epilogue
//               reads gi, applies full GRU gate math + ReLU, updates h.
// LDS = 32 KB (A) + 96 KB (W) = 128 KB.
// ---------------------------------------------------------------------------
template<int MODE>
__global__ __launch_bounds__(512)
void gemm384(const void* __restrict__ Aptr, const float* __restrict__ W,
             const float* __restrict__ bias, float* __restrict__ gi,
             float* __restrict__ h) {
    __shared__ ushort As[128 * 128];
    __shared__ ushort Bs[384 * 128];
    const int mloc = blockIdx.x * 128;
    const int t = threadIdx.x;

    #pragma unroll
    for (int f = t; f < 2048; f += 512) {
        const int r = f >> 4, c8 = (f & 15) * 8;
        bf16x8 pk;
        if (MODE == 0)
            pk = *(const bf16x8*)((const ushort*)Aptr + (size_t)(mloc + r) * 128 + c8);
        else
            pk = cvt8((const float*)Aptr + (size_t)(mloc + r) * 128 + c8);
        *(bf16x8*)&As[r * 128 + (c8 ^ ((r & 7) << 3))] = pk;
    }
    #pragma unroll
    for (int f = t; f < 6144; f += 512) {
        const int r = f >> 4, c8 = (f & 15) * 8;
        const bf16x8 pk = cvt8(W + (size_t)r * 128 + c8);
        *(bf16x8*)&Bs[r * 128 + (c8 ^ ((r & 7) << 3))] = pk;
    }
    __syncthreads();

    const int lane = t & 63, wid = t >> 6;
    const int l15 = lane & 15, kg = (lane >> 4) * 8;

    f32x4 acc[24] = {};
    #pragma unroll
    for (int kc = 0; kc < 4; ++kc) {
        const int cs = kc * 32 + kg;
        const int ra = wid * 16 + l15;
        const bf16x8 af = *(const bf16x8*)&As[ra * 128 + (cs ^ ((ra & 7) << 3))];
        #pragma unroll
        for (int j = 0; j < 24; ++j) {
            const int rb = j * 16 + l15;
            const bf16x8 bfr = *(const bf16x8*)&Bs[rb * 128 + (cs ^ ((rb & 7) << 3))];
            acc[j] = __builtin_amdgcn_mfma_f32_16x16x32_bf16(af, bfr, acc[j], 0, 0, 0);
        }
    }

    const int rl0 = mloc + wid * 16 + (lane >> 4) * 4;   // chunk-local row base
    if (MODE == 0) {
        #pragma unroll
        for (int j = 0; j < 24; ++j) {
            const int col = j * 16 + l15;
            const float bv = bias[col];
            #pragma unroll
            for (int q = 0; q < 4; ++q)
                gi[(size_t)(rl0 + q) * 384 + col] = acc[j][q] + bv;
        }
    } else {
        #pragma unroll
        for (int j = 0; j < 8; ++j) {
            const int col = j * 16 + l15;
            const float bhr = bias[col], bhz = bias[128 + col], bhn = bias[256 + col];
            #pragma unroll
            for (int q = 0; q < 4; ++q) {
                const size_t gb = (size_t)(rl0 + q) * 384 + col;
                const float ir = gi[gb], iz = gi[gb + 128], in_ = gi[gb + 256];
                const float hr = acc[j][q] + bhr;
                const float hz = acc[j + 8][q] + bhz;
                const float hn = acc[j + 16][q] + bhn;
                const size_t hb = (size_t)(rl0 + q) * 128 + col;
                const float hv = h[hb];
                const float r_ = sigf(ir + hr);
                const float z  = sigf(iz + hz);
                const float ng = tanhf(in_ + r_ * hn);
                h[hb] = fmaxf((1.f - z) * ng + z * hv, 0.f);
            }
        }
    }
}

// h[i][:] = emb[x[i]-1][:]
__global__ __launch_bounds__(256)
void gather_kernel(const int* __restrict__ x, const float* __restrict__ emb,
                   float* __restrict__ h) {
    const int tid = blockIdx.x * 256 + threadIdx.x;
    const int i = tid >> 5, c = (tid & 31) * 4;
    const int idx = x[i] - 1;
    *(float4*)(h + (size_t)i * 128 + c) = *(const float4*)(emb + (size_t)idx * 128 + c);
}

// ---------------- CSR build ----------------
__global__ __launch_bounds__(256)
void hist_kernel(const int* __restrict__ ei, int* __restrict__ deg) {
    const int e = blockIdx.x * 256 + threadIdx.x;
    atomicAdd(&deg[ei[NEDGES + e]], 1);
}

__global__ __launch_bounds__(256)
void blocksum_kernel(const int* __restrict__ deg, int* __restrict__ bsum) {
    __shared__ int s[256];
    const int t = threadIdx.x;
    s[t] = deg[blockIdx.x * 256 + t];
    __syncthreads();
    for (int off = 128; off > 0; off >>= 1) {
        if (t < off) s[t] += s[t + off];
        __syncthreads();
    }
    if (t == 0) bsum[blockIdx.x] = s[0];
}

__global__ void scan_bsum_kernel(int* __restrict__ bsum) {
    if (threadIdx.x == 0) {
        int acc = 0;
        for (int i = 0; i < 200; ++i) { const int v = bsum[i]; bsum[i] = acc; acc += v; }
    }
}

__global__ __launch_bounds__(256)
void scan_kernel(const int* __restrict__ deg, const int* __restrict__ bsum,
                 int* __restrict__ offs, int* __restrict__ cursor) {
    __shared__ int s[256];
    const int t = threadIdx.x;
    const int i = blockIdx.x * 256 + t;
    const int v = deg[i];
    s[t] = v;
    __syncthreads();
    for (int off = 1; off < 256; off <<= 1) {
        const int add = (t >= off) ? s[t - off] : 0;
        __syncthreads();
        s[t] += add;
        __syncthreads();
    }
    const int excl = s[t] - v + bsum[blockIdx.x];
    offs[i] = excl;
    cursor[i] = excl;
    if (blockIdx.x == 199 && t == 255) offs[NNODES] = excl + v;
}

__global__ __launch_bounds__(256)
void fill_kernel(const int* __restrict__ ei, int* __restrict__ cursor,
                 int* __restrict__ esrc) {
    const int e = blockIdx.x * 256 + threadIdx.x;
    const int dst = ei[NEDGES + e];
    const int pos = atomicAdd(&cursor[dst], 1);
    esrc[pos] = ei[e];
}

// agg[i] = sum over in-edges of m[src] (bf16 in, f32 acc, bf16 out)
__global__ __launch_bounds__(256)
void agg_kernel(const int* __restrict__ offs, const int* __restrict__ esrc,
                const ushort* __restrict__ mb, ushort* __restrict__ aggb) {
    const int node = blockIdx.x * 4 + (threadIdx.x >> 6);
    const int l = threadIdx.x & 63;
    const int s = offs[node], e = offs[node + 1];
    float ax = 0.f, ay = 0.f;
    for (int j = s; j < e; ++j) {
        const int src = esrc[j];
        const unsigned u = *(const unsigned*)(mb + (size_t)src * 128 + l * 2);
        ax += bf2f((ushort)(u & 0xffff));
        ay += bf2f((ushort)(u >> 16));
    }
    const unsigned o = (unsigned)f2bf(ax) | ((unsigned)f2bf(ay) << 16);
    *(unsigned*)(aggb + (size_t)node * 128 + l * 2) = o;
}

// Per-session attention readout; t2 in bf16, b2 added here.
__global__ __launch_bounds__(64)
void attn_kernel(const float* __restrict__ h, const float* __restrict__ t1,
                 const ushort* __restrict__ t2, const float* __restrict__ qw,
                 const float* __restrict__ qbp, const float* __restrict__ b2,
                 float* __restrict__ sg) {
    const int b = blockIdx.x, l = threadIdx.x;
    const float t1a = t1[b * 128 + l] + b2[l];
    const float t1b = t1[b * 128 + 64 + l] + b2[64 + l];
    const float qa = qw[l], qb2 = qw[64 + l];
    const float qbias = qbp[0];
    const float*  hb  = h  + (size_t)b * NODES_PER * 128;
    const ushort* t2b = t2 + (size_t)b * NODES_PER * 128;
    float sga = 0.f, sgb = 0.f;
    for (int i = 0; i < NODES_PER; ++i) {
        const float ha  = hb[i * 128 + l], hb2v = hb[i * 128 + 64 + l];
        const float aa  = sigf(t1a + bf2f(t2b[i * 128 + l]));
        const float ab  = sigf(t1b + bf2f(t2b[i * 128 + 64 + l]));
        float p = aa * qa + ab * qb2;
        #pragma unroll
        for (int off = 32; off > 0; off >>= 1) p += __shfl_down(p, off);
        const float alpha = __shfl(p, 0) + qbias;
        sga += alpha * ha; sgb += alpha * hb2v;
    }
    sg[b * 128 + l] = sga;
    sg[b * 128 + 64 + l] = sgb;
}

// s_h[b] = W3 @ [v_n[b]; s_g[b]] + b3
__global__ __launch_bounds__(128)
void sh_kernel(const float* __restrict__ h, const float* __restrict__ sgbuf,
               const float* __restrict__ W3, const float* __restrict__ b3,
               float* __restrict__ sh) {
    __shared__ float W3s[128 * 257];
    __shared__ float vns[128], sgs[128];
    const int t = threadIdx.x;
    for (int f = t; f < 8192; f += 128) {
        const int r = f >> 6, c4 = (f & 63) * 4;
        const float4 v = *(const float4*)(W3 + (size_t)r * 256 + c4);
        float* d = &W3s[r * 257 + c4];
        d[0] = v.x; d[1] = v.y; d[2] = v.z; d[3] = v.w;
    }
    for (int bb = 0; bb < 8; ++bb) {
        const int b = blockIdx.x * 8 + bb;
        __syncthreads();
        vns[t] = h[((size_t)b * NODES_PER + 49) * 128 + t];
        sgs[t] = sgbuf[b * 128 + t];
        __syncthreads();
        float acc = b3[t];
        const float* wr = &W3s[t * 257];
        #pragma unroll 8
        for (int k = 0; k < 128; ++k) acc = fmaf(wr[k], vns[k], acc);
        #pragma unroll 8
        for (int k = 0; k < 128; ++k) acc = fmaf(wr[128 + k], sgs[k], acc);
        sh[b * 128 + t] = acc;
    }
}

extern "C" void kernel_launch(void* const* d_in, const int* in_sizes, int n_in,
                              void* d_out, int out_size, void* d_ws, size_t ws_size,
                              hipStream_t stream) {
    const int*   x   = (const int*)d_in[0];
    const int*   ei  = (const int*)d_in[1];
    const float* emb = (const float*)d_in[3];
    const float* Wg  = (const float*)d_in[4];
    const float* Wih = (const float*)d_in[5];
    const float* Whh = (const float*)d_in[6];
    const float* bih = (const float*)d_in[7];
    const float* bhh = (const float*)d_in[8];
    const float* W1  = (const float*)d_in[9];
    const float* b1  = (const float*)d_in[10];
    const float* W2  = (const float*)d_in[11];
    const float* b2  = (const float*)d_in[12];
    const float* qw  = (const float*)d_in[13];
    const float* qb  = (const float*)d_in[14];
    const float* W3  = (const float*)d_in[15];
    const float* b3  = (const float*)d_in[16];
    float* out = (float*)d_out;

    // workspace layout (float offsets); total ~93.3 MB
    float*  ws   = (float*)d_ws;
    float*  h    = ws;                            // 6,553,600 f32
    ushort* mb   = (ushort*)(ws + 6553600);       // 6,553,600 bf16 (m, later t2)
    ushort* aggb = (ushort*)(ws + 9830400);       // 6,553,600 bf16
    float*  gi   = ws + 13107200;                 // 25600*384 f32 (chunk)
    float*  t1   = ws + 22937600;                 // 131,072
    float*  sg   = ws + 23068672;                 // 131,072
    float*  sh   = ws + 23199744;                 // 131,072

    // CSR ints alias gi (dead until first gi GEMM; agg completes before that)
    int* deg    = (int*)gi;
    int* offs   = deg + NNODES;
    int* cursor = offs + NNODES + 1;
    int* esrc   = cursor + NNODES;
    int* bsum   = esrc + NEDGES;

    hipMemsetAsync(deg, 0, NNODES * sizeof(int), stream);

    // h = emb[x-1]
    gather_kernel<<<6400, 256, 0, stream>>>(x, emb, h);
    // m = h @ W_gconv  (B staged transposed from Wg; bf16 out)
    gemm_tile<1, true><<<dim3(400, 1), 256, 0, stream>>>(mb, h, Wg, nullptr, NNODES, 128, 128);

    // CSR build + gather-sum
    hist_kernel<<<1600, 256, 0, stream>>>(ei, deg);
    blocksum_kernel<<<200, 256, 0, stream>>>(deg, bsum);
    scan_bsum_kernel<<<1, 64, 0, stream>>>(bsum);
    scan_kernel<<<200, 256, 0, stream>>>(deg, bsum, offs, cursor);
    fill_kernel<<<1600, 256, 0, stream>>>(ei, cursor, esrc);
    agg_kernel<<<12800, 256, 0, stream>>>(offs, esrc, mb, aggb);

    // GRU: 2 chunks of 25600 rows; gi GEMM then fused gh+GRU
    for (int c = 0; c < 2; ++c) {
        const size_t roff = (size_t)c * CHUNK;
        gemm384<0><<<200, 512, 0, stream>>>(aggb + roff * 128, Wih, bih, gi, nullptr);
        gemm384<1><<<200, 512, 0, stream>>>(h + roff * 128, Whh, bhh, gi, h + roff * 128);
    }

    // t1[b] = v_n[b] @ W1^T + b1
    gemm_tile<0, false><<<dim3(8, 1), 256, 0, stream>>>(t1, h + 49 * 128, W1, b1, NB, 128, NODES_PER * 128);
    // t2 = h @ W2^T (bf16, into mb — m is dead)
    gemm_tile<1, false><<<dim3(400, 1), 256, 0, stream>>>(mb, h, W2, nullptr, NNODES, 128, 128);
    attn_kernel<<<NB, 64, 0, stream>>>(h, t1, mb, qw, qb, b2, sg);
    sh_kernel<<<128, 128, 0, stream>>>(h, sg, W3, b3, sh);
    // out = s_h @ emb^T
    gemm_tile<0, false><<<dim3(8, 782), 256, 0, stream>>>(out, sh, emb, nullptr, NB, NVOCAB, 128);
}

// Round 6
// 483.129 us; speedup vs baseline: 4.1212x; 1.0940x over previous
//
#include <hip/hip_runtime.h>
#include <math.h>

#define NNODES 51200
#define NEDGES 409600
#define NB 1024
#define NODES_PER 50
#define NVOCAB 100000
#define CHUNK 25600

typedef __attribute__((ext_vector_type(8))) short bf16x8;
typedef __attribute__((ext_vector_type(4))) float f32x4;

__device__ __forceinline__ float sigf(float x) { return 1.0f / (1.0f + __expf(-x)); }

__device__ __forceinline__ ushort f2bf(float x) {   // RTNE f32 -> bf16
    union { float f; unsigned u; } v; v.f = x;
    const unsigned r = v.u + 0x7FFF + ((v.u >> 16) & 1);
    return (ushort)(r >> 16);
}
__device__ __forceinline__ float bf2f(ushort u) {
    union { float f; unsigned u; } v; v.u = ((unsigned)u) << 16; return v.f;
}
__device__ __forceinline__ bf16x8 cvt8(const float* __restrict__ src) {
    const float4 v0 = *(const float4*)src, v1 = *(const float4*)(src + 4);
    bf16x8 p;
    p[0] = (short)f2bf(v0.x); p[1] = (short)f2bf(v0.y);
    p[2] = (short)f2bf(v0.z); p[3] = (short)f2bf(v0.w);
    p[4] = (short)f2bf(v1.x); p[5] = (short)f2bf(v1.y);
    p[6] = (short)f2bf(v1.z); p[7] = (short)f2bf(v1.w);
    return p;
}

// ---------------------------------------------------------------------------
// bf16-MFMA GEMM, tile 128x128, 256 thr (4 waves 2x2), K=128 one stage.
// LDS XOR swizzle (short_col ^= (row&7)<<3). Epilogue repacks acc via LDS
// for coalesced global stores (plain cached stores; nt caused 1.85x write amp).
// OUT_MODE: 0 = f32 out (+opt bias), 1 = bf16 out.
// B_TRANSP: stage B[n][k] from W[k][n] (for W_gconv).
// XSWZ: 1D grid, XCD-aware decode (vocab GEMM): the 8 m-tiles sharing a
//       B-tile run consecutively on ONE XCD -> B fetched once per XCD-L2.
// ---------------------------------------------------------------------------
template<int OUT_MODE, bool B_TRANSP, bool XSWZ>
__global__ __launch_bounds__(256)
void gemm_tile(void* __restrict__ Cout, const float* __restrict__ A,
               const float* __restrict__ B, const float* __restrict__ bias,
               int M, int N, int strideA) {
    __shared__ float4 smemv[4224];                 // 67,584 B
    ushort* As = (ushort*)smemv;                   // [128*128]
    ushort* Bs = As + 128 * 128;
    int m0, n0;
    if (XSWZ) {
        // id%8 = XCD (round-robin dispatch); within an XCD: m fast, n slow
        const int id = blockIdx.x;
        const int xcd = id & 7, loc = id >> 3;
        const int mt = loc & 7, nl = loc >> 3;     // 8 m-tiles, 98 n-tiles/XCD
        m0 = mt * 128;
        n0 = (xcd * 98 + nl) * 128;
    } else {
        m0 = blockIdx.x * 128;
        n0 = blockIdx.y * 128;
    }
    const int t  = threadIdx.x;

    #pragma unroll
    for (int f = t; f < 2048; f += 256) {
        const int r = f >> 4, c8 = (f & 15) * 8;
        const bf16x8 pk = cvt8(A + (size_t)(m0 + r) * strideA + c8);
        *(bf16x8*)&As[r * 128 + (c8 ^ ((r & 7) << 3))] = pk;
    }
    #pragma unroll
    for (int f = t; f < 2048; f += 256) {
        const int r = f >> 4, c8 = (f & 15) * 8;
        const int n = n0 + r;
        bf16x8 pk = {0, 0, 0, 0, 0, 0, 0, 0};
        if (n < N) {
            if (B_TRANSP) {
                #pragma unroll
                for (int d = 0; d < 8; ++d)
                    pk[d] = (short)f2bf(B[(size_t)(c8 + d) * 128 + n]);
            } else {
                pk = cvt8(B + (size_t)n * 128 + c8);
            }
        }
        *(bf16x8*)&Bs[r * 128 + (c8 ^ ((r & 7) << 3))] = pk;
    }
    __syncthreads();

    const int lane = t & 63, wid = t >> 6;
    const int wr = wid >> 1, wc = wid & 1;
    const int l15 = lane & 15, kg = (lane >> 4) * 8;

    f32x4 acc[4][4] = {};
    #pragma unroll
    for (int kc = 0; kc < 4; ++kc) {
        const int cs = kc * 32 + kg;
        bf16x8 af[4], bfr[4];
        #pragma unroll
        for (int i = 0; i < 4; ++i) {
            const int ra = wr * 64 + i * 16 + l15;
            af[i] = *(const bf16x8*)&As[ra * 128 + (cs ^ ((ra & 7) << 3))];
            const int rb = wc * 64 + i * 16 + l15;
            bfr[i] = *(const bf16x8*)&Bs[rb * 128 + (cs ^ ((rb & 7) << 3))];
        }
        #pragma unroll
        for (int i = 0; i < 4; ++i)
            #pragma unroll
            for (int j = 0; j < 4; ++j)
                acc[i][j] = __builtin_amdgcn_mfma_f32_16x16x32_bf16(af[i], bfr[j], acc[i][j], 0, 0, 0);
    }

    __syncthreads();                               // done reading As/Bs; reuse LDS
    const int cr0 = (lane >> 4) * 4;

    if (OUT_MODE == 1) {
        ushort* Cs = (ushort*)smemv;               // [128][128] bf16
        #pragma unroll
        for (int i = 0; i < 4; ++i)
            #pragma unroll
            for (int j = 0; j < 4; ++j)
                #pragma unroll
                for (int q = 0; q < 4; ++q)
                    Cs[(wr * 64 + i * 16 + cr0 + q) * 128 + (wc * 64 + j * 16 + l15)] =
                        f2bf(acc[i][j][q]);
        __syncthreads();
        ushort* Cb = (ushort*)Cout;
        #pragma unroll
        for (int f = t; f < 2048; f += 256) {
            const int r = f >> 4, c8 = (f & 15) * 8;
            *(bf16x8*)(Cb + (size_t)(m0 + r) * 128 + c8) = *(bf16x8*)&Cs[r * 128 + c8];
        }
    } else {
        float* Cs = (float*)smemv;                 // [128][132] f32
        #pragma unroll
        for (int i = 0; i < 4; ++i)
            #pragma unroll
            for (int j = 0; j < 4; ++j)
                #pragma unroll
                for (int q = 0; q < 4; ++q)
                    Cs[(wr * 64 + i * 16 + cr0 + q) * 132 + (wc * 64 + j * 16 + l15)] =
                        acc[i][j][q];
        __syncthreads();
        float* C = (float*)Cout;
        #pragma unroll
        for (int f = t; f < 2048; f += 256) {
            const int r = f >> 4, c8 = (f & 15) * 8;
            const int col = n0 + c8;
            if (col < N) {
                f32x4 v0 = *(f32x4*)&Cs[r * 132 + c8];
                f32x4 v1 = *(f32x4*)&Cs[r * 132 + c8 + 4];
                if (bias) {
                    v0 += *(const f32x4*)&bias[col];
                    v1 += *(const f32x4*)&bias[col + 4];
                }
                f32x4* dst = (f32x4*)(C + (size_t)(m0 + r) * N + col);
                *dst = v0;
                if (col + 4 < N) *(dst + 1) = v1;
            }
        }
    }
}

// ---------------------------------------------------------------------------
// 512-thr 128x384 GEMM against W[384][128] (f32), 8 waves x (16 rows x 384).
// MODE 0 (GI): A = bf16 agg chunk; writes gi f32 + bias.
// MODE 1 (GRU): A = f32 h chunk (gh in-register); epilogue reads gi, applies
//               GRU gates + ReLU, updates h in place.
// ---------------------------------------------------------------------------
template<int MODE>
__global__ __launch_bounds__(512)
void gemm384(const void* __restrict__ Aptr, const float* __restrict__ W,
             const float* __restrict__ bias, float* __restrict__ gi,
             float* __restrict__ h) {
    __shared__ ushort As[128 * 128];
    __shared__ ushort Bs[384 * 128];
    const int mloc = blockIdx.x * 128;
    const int t = threadIdx.x;

    #pragma unroll
    for (int f = t; f < 2048; f += 512) {
        const int r = f >> 4, c8 = (f & 15) * 8;
        bf16x8 pk;
        if (MODE == 0)
            pk = *(const bf16x8*)((const ushort*)Aptr + (size_t)(mloc + r) * 128 + c8);
        else
            pk = cvt8((const float*)Aptr + (size_t)(mloc + r) * 128 + c8);
        *(bf16x8*)&As[r * 128 + (c8 ^ ((r & 7) << 3))] = pk;
    }
    #pragma unroll
    for (int f = t; f < 6144; f += 512) {
        const int r = f >> 4, c8 = (f & 15) * 8;
        const bf16x8 pk = cvt8(W + (size_t)r * 128 + c8);
        *(bf16x8*)&Bs[r * 128 + (c8 ^ ((r & 7) << 3))] = pk;
    }
    __syncthreads();

    const int lane = t & 63, wid = t >> 6;
    const int l15 = lane & 15, kg = (lane >> 4) * 8;

    f32x4 acc[24] = {};
    #pragma unroll
    for (int kc = 0; kc < 4; ++kc) {
        const int cs = kc * 32 + kg;
        const int ra = wid * 16 + l15;
        const bf16x8 af = *(const bf16x8*)&As[ra * 128 + (cs ^ ((ra & 7) << 3))];
        #pragma unroll
        for (int j = 0; j < 24; ++j) {
            const int rb = j * 16 + l15;
            const bf16x8 bfr = *(const bf16x8*)&Bs[rb * 128 + (cs ^ ((rb & 7) << 3))];
            acc[j] = __builtin_amdgcn_mfma_f32_16x16x32_bf16(af, bfr, acc[j], 0, 0, 0);
        }
    }

    const int rl0 = mloc + wid * 16 + (lane >> 4) * 4;
    if (MODE == 0) {
        #pragma unroll
        for (int j = 0; j < 24; ++j) {
            const int col = j * 16 + l15;
            const float bv = bias[col];
            #pragma unroll
            for (int q = 0; q < 4; ++q)
                gi[(size_t)(rl0 + q) * 384 + col] = acc[j][q] + bv;
        }
    } else {
        #pragma unroll
        for (int j = 0; j < 8; ++j) {
            const int col = j * 16 + l15;
            const float bhr = bias[col], bhz = bias[128 + col], bhn = bias[256 + col];
            #pragma unroll
            for (int q = 0; q < 4; ++q) {
                const size_t gb = (size_t)(rl0 + q) * 384 + col;
                const float ir = gi[gb], iz = gi[gb + 128], in_ = gi[gb + 256];
                const float hr = acc[j][q] + bhr;
                const float hz = acc[j + 8][q] + bhz;
                const float hn = acc[j + 16][q] + bhn;
                const size_t hb = (size_t)(rl0 + q) * 128 + col;
                const float hv = h[hb];
                const float r_ = sigf(ir + hr);
                const float z  = sigf(iz + hz);
                const float ng = tanhf(in_ + r_ * hn);
                h[hb] = fmaxf((1.f - z) * ng + z * hv, 0.f);
            }
        }
    }
}

// h[i][:] = emb[x[i]-1][:]
__global__ __launch_bounds__(256)
void gather_kernel(const int* __restrict__ x, const float* __restrict__ emb,
                   float* __restrict__ h) {
    const int tid = blockIdx.x * 256 + threadIdx.x;
    const int i = tid >> 5, c = (tid & 31) * 4;
    const int idx = x[i] - 1;
    *(float4*)(h + (size_t)i * 128 + c) = *(const float4*)(emb + (size_t)idx * 128 + c);
}

// ---------------- CSR build ----------------
__global__ __launch_bounds__(256)
void hist_kernel(const int* __restrict__ ei, int* __restrict__ deg) {
    const int e = blockIdx.x * 256 + threadIdx.x;
    atomicAdd(&deg[ei[NEDGES + e]], 1);
}

__global__ __launch_bounds__(256)
void blocksum_kernel(const int* __restrict__ deg, int* __restrict__ bsum) {
    __shared__ int s[256];
    const int t = threadIdx.x;
    s[t] = deg[blockIdx.x * 256 + t];
    __syncthreads();
    for (int off = 128; off > 0; off >>= 1) {
        if (t < off) s[t] += s[t + off];
        __syncthreads();
    }
    if (t == 0) bsum[blockIdx.x] = s[0];
}

__global__ void scan_bsum_kernel(int* __restrict__ bsum) {
    if (threadIdx.x == 0) {
        int acc = 0;
        for (int i = 0; i < 200; ++i) { const int v = bsum[i]; bsum[i] = acc; acc += v; }
    }
}

__global__ __launch_bounds__(256)
void scan_kernel(const int* __restrict__ deg, const int* __restrict__ bsum,
                 int* __restrict__ offs, int* __restrict__ cursor) {
    __shared__ int s[256];
    const int t = threadIdx.x;
    const int i = blockIdx.x * 256 + t;
    const int v = deg[i];
    s[t] = v;
    __syncthreads();
    for (int off = 1; off < 256; off <<= 1) {
        const int add = (t >= off) ? s[t - off] : 0;
        __syncthreads();
        s[t] += add;
        __syncthreads();
    }
    const int excl = s[t] - v + bsum[blockIdx.x];
    offs[i] = excl;
    cursor[i] = excl;
    if (blockIdx.x == 199 && t == 255) offs[NNODES] = excl + v;
}

__global__ __launch_bounds__(256)
void fill_kernel(const int* __restrict__ ei, int* __restrict__ cursor,
                 int* __restrict__ esrc) {
    const int e = blockIdx.x * 256 + threadIdx.x;
    const int dst = ei[NEDGES + e];
    const int pos = atomicAdd(&cursor[dst], 1);
    esrc[pos] = ei[e];
}

// agg[i] = sum over in-edges of m[src] (bf16 in, f32 acc, bf16 out)
__global__ __launch_bounds__(256)
void agg_kernel(const int* __restrict__ offs, const int* __restrict__ esrc,
                const ushort* __restrict__ mb, ushort* __restrict__ aggb) {
    const int node = blockIdx.x * 4 + (threadIdx.x >> 6);
    const int l = threadIdx.x & 63;
    const int s = offs[node], e = offs[node + 1];
    float ax = 0.f, ay = 0.f;
    for (int j = s; j < e; ++j) {
        const int src = esrc[j];
        const unsigned u = *(const unsigned*)(mb + (size_t)src * 128 + l * 2);
        ax += bf2f((ushort)(u & 0xffff));
        ay += bf2f((ushort)(u >> 16));
    }
    const unsigned o = (unsigned)f2bf(ax) | ((unsigned)f2bf(ay) << 16);
    *(unsigned*)(aggb + (size_t)node * 128 + l * 2) = o;
}

// Per-session attention readout; t2 in bf16, b2 added here.
__global__ __launch_bounds__(64)
void attn_kernel(const float* __restrict__ h, const float* __restrict__ t1,
                 const ushort* __restrict__ t2, const float* __restrict__ qw,
                 const float* __restrict__ qbp, const float* __restrict__ b2,
                 float* __restrict__ sg) {
    const int b = blockIdx.x, l = threadIdx.x;
    const float t1a = t1[b * 128 + l] + b2[l];
    const float t1b = t1[b * 128 + 64 + l] + b2[64 + l];
    const float qa = qw[l], qb2 = qw[64 + l];
    const float qbias = qbp[0];
    const float*  hb  = h  + (size_t)b * NODES_PER * 128;
    const ushort* t2b = t2 + (size_t)b * NODES_PER * 128;
    float sga = 0.f, sgb = 0.f;
    for (int i = 0; i < NODES_PER; ++i) {
        const float ha  = hb[i * 128 + l], hb2v = hb[i * 128 + 64 + l];
        const float aa  = sigf(t1a + bf2f(t2b[i * 128 + l]));
        const float ab  = sigf(t1b + bf2f(t2b[i * 128 + 64 + l]));
        float p = aa * qa + ab * qb2;
        #pragma unroll
        for (int off = 32; off > 0; off >>= 1) p += __shfl_down(p, off);
        const float alpha = __shfl(p, 0) + qbias;
        sga += alpha * ha; sgb += alpha * hb2v;
    }
    sg[b * 128 + l] = sga;
    sg[b * 128 + 64 + l] = sgb;
}

// s_h[b] = W3 @ [v_n[b]; s_g[b]] + b3
__global__ __launch_bounds__(128)
void sh_kernel(const float* __restrict__ h, const float* __restrict__ sgbuf,
               const float* __restrict__ W3, const float* __restrict__ b3,
               float* __restrict__ sh) {
    __shared__ float W3s[128 * 257];
    __shared__ float vns[128], sgs[128];
    const int t = threadIdx.x;
    for (int f = t; f < 8192; f += 128) {
        const int r = f >> 6, c4 = (f & 63) * 4;
        const float4 v = *(const float4*)(W3 + (size_t)r * 256 + c4);
        float* d = &W3s[r * 257 + c4];
        d[0] = v.x; d[1] = v.y; d[2] = v.z; d[3] = v.w;
    }
    for (int bb = 0; bb < 8; ++bb) {
        const int b = blockIdx.x * 8 + bb;
        __syncthreads();
        vns[t] = h[((size_t)b * NODES_PER + 49) * 128 + t];
        sgs[t] = sgbuf[b * 128 + t];
        __syncthreads();
        float acc = b3[t];
        const float* wr = &W3s[t * 257];
        #pragma unroll 8
        for (int k = 0; k < 128; ++k) acc = fmaf(wr[k], vns[k], acc);
        #pragma unroll 8
        for (int k = 0; k < 128; ++k) acc = fmaf(wr[128 + k], sgs[k], acc);
        sh[b * 128 + t] = acc;
    }
}

extern "C" void kernel_launch(void* const* d_in, const int* in_sizes, int n_in,
                              void* d_out, int out_size, void* d_ws, size_t ws_size,
                              hipStream_t stream) {
    const int*   x   = (const int*)d_in[0];
    const int*   ei  = (const int*)d_in[1];
    const float* emb = (const float*)d_in[3];
    const float* Wg  = (const float*)d_in[4];
    const float* Wih = (const float*)d_in[5];
    const float* Whh = (const float*)d_in[6];
    const float* bih = (const float*)d_in[7];
    const float* bhh = (const float*)d_in[8];
    const float* W1  = (const float*)d_in[9];
    const float* b1  = (const float*)d_in[10];
    const float* W2  = (const float*)d_in[11];
    const float* b2  = (const float*)d_in[12];
    const float* qw  = (const float*)d_in[13];
    const float* qb  = (const float*)d_in[14];
    const float* W3  = (const float*)d_in[15];
    const float* b3  = (const float*)d_in[16];
    float* out = (float*)d_out;

    // workspace layout (float offsets); total ~93.3 MB
    float*  ws   = (float*)d_ws;
    float*  h    = ws;                            // 6,553,600 f32
    ushort* mb   = (ushort*)(ws + 6553600);       // 6,553,600 bf16 (m, later t2)
    ushort* aggb = (ushort*)(ws + 9830400);       // 6,553,600 bf16
    float*  gi   = ws + 13107200;                 // 25600*384 f32 (chunk)
    float*  t1   = ws + 22937600;                 // 131,072
    float*  sg   = ws + 23068672;                 // 131,072
    float*  sh   = ws + 23199744;                 // 131,072

    // CSR ints alias gi (dead until first gi GEMM; agg completes before that)
    int* deg    = (int*)gi;
    int* offs   = deg + NNODES;
    int* cursor = offs + NNODES + 1;
    int* esrc   = cursor + NNODES;
    int* bsum   = esrc + NEDGES;

    hipMemsetAsync(deg, 0, NNODES * sizeof(int), stream);

    // h = emb[x-1]
    gather_kernel<<<6400, 256, 0, stream>>>(x, emb, h);
    // m = h @ W_gconv  (B staged transposed from Wg; bf16 out)
    gemm_tile<1, true, false><<<dim3(400, 1), 256, 0, stream>>>(mb, h, Wg, nullptr, NNODES, 128, 128);

    // CSR build + gather-sum
    hist_kernel<<<1600, 256, 0, stream>>>(ei, deg);
    blocksum_kernel<<<200, 256, 0, stream>>>(deg, bsum);
    scan_bsum_kernel<<<1, 64, 0, stream>>>(bsum);
    scan_kernel<<<200, 256, 0, stream>>>(deg, bsum, offs, cursor);
    fill_kernel<<<1600, 256, 0, stream>>>(ei, cursor, esrc);
    agg_kernel<<<12800, 256, 0, stream>>>(offs, esrc, mb, aggb);

    // GRU: 2 chunks of 25600 rows; gi GEMM then fused gh+GRU
    for (int c = 0; c < 2; ++c) {
        const size_t roff = (size_t)c * CHUNK;
        gemm384<0><<<200, 512, 0, stream>>>(aggb + roff * 128, Wih, bih, gi, nullptr);
        gemm384<1><<<200, 512, 0, stream>>>(h + roff * 128, Whh, bhh, gi, h + roff * 128);
    }

    // t1[b] = v_n[b] @ W1^T + b1
    gemm_tile<0, false, false><<<dim3(8, 1), 256, 0, stream>>>(t1, h + 49 * 128, W1, b1, NB, 128, NODES_PER * 128);
    // t2 = h @ W2^T (bf16, into mb — m is dead)
    gemm_tile<1, false, false><<<dim3(400, 1), 256, 0, stream>>>(mb, h, W2, nullptr, NNODES, 128, 128);
    attn_kernel<<<NB, 64, 0, stream>>>(h, t1, mb, qw, qb, b2, sg);
    sh_kernel<<<128, 128, 0, stream>>>(h, sg, W3, b3, sh);
    // out = s_h @ emb^T  (XCD-swizzled 1D grid: 8 m-tiles x 784 n-tiles)
    gemm_tile<0, false, true><<<6272, 256, 0, stream>>>(out, sh, emb, nullptr, NB, NVOCAB, 128);
}

// Round 7
// 472.255 us; speedup vs baseline: 4.2161x; 1.0230x over previous
//
#include <hip/hip_runtime.h>
#include <math.h>

#define NNODES 51200
#define NEDGES 409600
#define NB 1024
#define NODES_PER 50
#define NVOCAB 100000

typedef __attribute__((ext_vector_type(8))) short bf16x8;
typedef __attribute__((ext_vector_type(4))) float f32x4;

__device__ __forceinline__ float sigf(float x) { return 1.0f / (1.0f + __expf(-x)); }

__device__ __forceinline__ ushort f2bf(float x) {   // RTNE f32 -> bf16
    union { float f; unsigned u; } v; v.f = x;
    const unsigned r = v.u + 0x7FFF + ((v.u >> 16) & 1);
    return (ushort)(r >> 16);
}
__device__ __forceinline__ float bf2f(ushort u) {
    union { float f; unsigned u; } v; v.u = ((unsigned)u) << 16; return v.f;
}
__device__ __forceinline__ bf16x8 cvt8(const float* __restrict__ src) {
    const float4 v0 = *(const float4*)src, v1 = *(const float4*)(src + 4);
    bf16x8 p;
    p[0] = (short)f2bf(v0.x); p[1] = (short)f2bf(v0.y);
    p[2] = (short)f2bf(v0.z); p[3] = (short)f2bf(v0.w);
    p[4] = (short)f2bf(v1.x); p[5] = (short)f2bf(v1.y);
    p[6] = (short)f2bf(v1.z); p[7] = (short)f2bf(v1.w);
    return p;
}

// ---------------------------------------------------------------------------
// bf16-MFMA GEMM, tile 128x128, 256 thr (4 waves 2x2), K=128 one stage.
// LDS XOR swizzle (short_col ^= (row&7)<<3). Epilogue repacks acc via LDS
// for coalesced global stores. OUT_MODE: 0 = f32 out (+opt bias), 1 = bf16.
// B_TRANSP: stage B[n][k] from W[k][n]. XSWZ: XCD-aware 1D grid (vocab).
// ---------------------------------------------------------------------------
template<int OUT_MODE, bool B_TRANSP, bool XSWZ>
__global__ __launch_bounds__(256)
void gemm_tile(void* __restrict__ Cout, const float* __restrict__ A,
               const float* __restrict__ B, const float* __restrict__ bias,
               int M, int N, int strideA) {
    __shared__ float4 smemv[4224];                 // 67,584 B
    ushort* As = (ushort*)smemv;
    ushort* Bs = As + 128 * 128;
    int m0, n0;
    if (XSWZ) {
        const int id = blockIdx.x;
        const int xcd = id & 7, loc = id >> 3;
        const int mt = loc & 7, nl = loc >> 3;     // 8 m-tiles, 98 n-tiles/XCD
        m0 = mt * 128;
        n0 = (xcd * 98 + nl) * 128;
    } else {
        m0 = blockIdx.x * 128;
        n0 = blockIdx.y * 128;
    }
    const int t  = threadIdx.x;

    #pragma unroll
    for (int f = t; f < 2048; f += 256) {
        const int r = f >> 4, c8 = (f & 15) * 8;
        const bf16x8 pk = cvt8(A + (size_t)(m0 + r) * strideA + c8);
        *(bf16x8*)&As[r * 128 + (c8 ^ ((r & 7) << 3))] = pk;
    }
    #pragma unroll
    for (int f = t; f < 2048; f += 256) {
        const int r = f >> 4, c8 = (f & 15) * 8;
        const int n = n0 + r;
        bf16x8 pk = {0, 0, 0, 0, 0, 0, 0, 0};
        if (n < N) {
            if (B_TRANSP) {
                #pragma unroll
                for (int d = 0; d < 8; ++d)
                    pk[d] = (short)f2bf(B[(size_t)(c8 + d) * 128 + n]);
            } else {
                pk = cvt8(B + (size_t)n * 128 + c8);
            }
        }
        *(bf16x8*)&Bs[r * 128 + (c8 ^ ((r & 7) << 3))] = pk;
    }
    __syncthreads();

    const int lane = t & 63, wid = t >> 6;
    const int wr = wid >> 1, wc = wid & 1;
    const int l15 = lane & 15, kg = (lane >> 4) * 8;

    f32x4 acc[4][4] = {};
    #pragma unroll
    for (int kc = 0; kc < 4; ++kc) {
        const int cs = kc * 32 + kg;
        bf16x8 af[4], bfr[4];
        #pragma unroll
        for (int i = 0; i < 4; ++i) {
            const int ra = wr * 64 + i * 16 + l15;
            af[i] = *(const bf16x8*)&As[ra * 128 + (cs ^ ((ra & 7) << 3))];
            const int rb = wc * 64 + i * 16 + l15;
            bfr[i] = *(const bf16x8*)&Bs[rb * 128 + (cs ^ ((rb & 7) << 3))];
        }
        #pragma unroll
        for (int i = 0; i < 4; ++i)
            #pragma unroll
            for (int j = 0; j < 4; ++j)
                acc[i][j] = __builtin_amdgcn_mfma_f32_16x16x32_bf16(af[i], bfr[j], acc[i][j], 0, 0, 0);
    }

    __syncthreads();
    const int cr0 = (lane >> 4) * 4;

    if (OUT_MODE == 1) {
        ushort* Cs = (ushort*)smemv;
        #pragma unroll
        for (int i = 0; i < 4; ++i)
            #pragma unroll
            for (int j = 0; j < 4; ++j)
                #pragma unroll
                for (int q = 0; q < 4; ++q)
                    Cs[(wr * 64 + i * 16 + cr0 + q) * 128 + (wc * 64 + j * 16 + l15)] =
                        f2bf(acc[i][j][q]);
        __syncthreads();
        ushort* Cb = (ushort*)Cout;
        #pragma unroll
        for (int f = t; f < 2048; f += 256) {
            const int r = f >> 4, c8 = (f & 15) * 8;
            *(bf16x8*)(Cb + (size_t)(m0 + r) * 128 + c8) = *(bf16x8*)&Cs[r * 128 + c8];
        }
    } else {
        float* Cs = (float*)smemv;                 // [128][132]
        #pragma unroll
        for (int i = 0; i < 4; ++i)
            #pragma unroll
            for (int j = 0; j < 4; ++j)
                #pragma unroll
                for (int q = 0; q < 4; ++q)
                    Cs[(wr * 64 + i * 16 + cr0 + q) * 132 + (wc * 64 + j * 16 + l15)] =
                        acc[i][j][q];
        __syncthreads();
        float* C = (float*)Cout;
        #pragma unroll
        for (int f = t; f < 2048; f += 256) {
            const int r = f >> 4, c8 = (f & 15) * 8;
            const int col = n0 + c8;
            if (col < N) {
                f32x4 v0 = *(f32x4*)&Cs[r * 132 + c8];
                f32x4 v1 = *(f32x4*)&Cs[r * 132 + c8 + 4];
                if (bias) {
                    v0 += *(const f32x4*)&bias[col];
                    v1 += *(const f32x4*)&bias[col + 4];
                }
                f32x4* dst = (f32x4*)(C + (size_t)(m0 + r) * N + col);
                *dst = v0;
                if (col + 4 < N) *(dst + 1) = v1;
            }
        }
    }
}

// ---------------------------------------------------------------------------
// Fully fused GRU: one dispatch, 400 blocks x 512 thr, 128 rows/block.
// Phase 1: A=agg(bf16), B=Wih -> acc_gi[24] in regs.
// Phase 2 (same LDS): A=h(cvt), B=Whh -> acc_gh[24].
// Epilogue: full gate math + ReLU, h updated in place. gi never hits memory.
// ---------------------------------------------------------------------------
__global__ __launch_bounds__(512)
void gru_fused(const ushort* __restrict__ aggb, const float* __restrict__ Wih,
               const float* __restrict__ Whh, const float* __restrict__ bih,
               const float* __restrict__ bhh, float* __restrict__ h) {
    __shared__ ushort As[128 * 128];
    __shared__ ushort Bs[384 * 128];
    const int m0 = blockIdx.x * 128;
    const int t = threadIdx.x;
    const int lane = t & 63, wid = t >> 6;
    const int l15 = lane & 15, kg = (lane >> 4) * 8;

    // ---- phase 1: gi = agg @ Wih^T ----
    #pragma unroll
    for (int f = t; f < 2048; f += 512) {
        const int r = f >> 4, c8 = (f & 15) * 8;
        const bf16x8 pk = *(const bf16x8*)(aggb + (size_t)(m0 + r) * 128 + c8);
        *(bf16x8*)&As[r * 128 + (c8 ^ ((r & 7) << 3))] = pk;
    }
    #pragma unroll
    for (int f = t; f < 6144; f += 512) {
        const int r = f >> 4, c8 = (f & 15) * 8;
        *(bf16x8*)&Bs[r * 128 + (c8 ^ ((r & 7) << 3))] = cvt8(Wih + (size_t)r * 128 + c8);
    }
    __syncthreads();

    f32x4 gi[24] = {};
    #pragma unroll
    for (int kc = 0; kc < 4; ++kc) {
        const int cs = kc * 32 + kg;
        const int ra = wid * 16 + l15;
        const bf16x8 af = *(const bf16x8*)&As[ra * 128 + (cs ^ ((ra & 7) << 3))];
        #pragma unroll
        for (int j = 0; j < 24; ++j) {
            const int rb = j * 16 + l15;
            const bf16x8 bfr = *(const bf16x8*)&Bs[rb * 128 + (cs ^ ((rb & 7) << 3))];
            gi[j] = __builtin_amdgcn_mfma_f32_16x16x32_bf16(af, bfr, gi[j], 0, 0, 0);
        }
    }
    __syncthreads();                               // all reads of As/Bs done

    // ---- phase 2: gh = h @ Whh^T (same LDS buffers) ----
    #pragma unroll
    for (int f = t; f < 2048; f += 512) {
        const int r = f >> 4, c8 = (f & 15) * 8;
        *(bf16x8*)&As[r * 128 + (c8 ^ ((r & 7) << 3))] = cvt8(h + (size_t)(m0 + r) * 128 + c8);
    }
    #pragma unroll
    for (int f = t; f < 6144; f += 512) {
        const int r = f >> 4, c8 = (f & 15) * 8;
        *(bf16x8*)&Bs[r * 128 + (c8 ^ ((r & 7) << 3))] = cvt8(Whh + (size_t)r * 128 + c8);
    }
    __syncthreads();

    f32x4 gh[24] = {};
    #pragma unroll
    for (int kc = 0; kc < 4; ++kc) {
        const int cs = kc * 32 + kg;
        const int ra = wid * 16 + l15;
        const bf16x8 af = *(const bf16x8*)&As[ra * 128 + (cs ^ ((ra & 7) << 3))];
        #pragma unroll
        for (int j = 0; j < 24; ++j) {
            const int rb = j * 16 + l15;
            const bf16x8 bfr = *(const bf16x8*)&Bs[rb * 128 + (cs ^ ((rb & 7) << 3))];
            gh[j] = __builtin_amdgcn_mfma_f32_16x16x32_bf16(af, bfr, gh[j], 0, 0, 0);
        }
    }

    // ---- epilogue: gates + ReLU ----
    const int rl0 = m0 + wid * 16 + (lane >> 4) * 4;
    #pragma unroll
    for (int j = 0; j < 8; ++j) {
        const int col = j * 16 + l15;
        const float bir = bih[col], biz = bih[128 + col], bin = bih[256 + col];
        const float bhr = bhh[col], bhz = bhh[128 + col], bhn = bhh[256 + col];
        #pragma unroll
        for (int q = 0; q < 4; ++q) {
            const size_t hb = (size_t)(rl0 + q) * 128 + col;
            const float hv = h[hb];
            const float r_ = sigf(gi[j][q] + bir + gh[j][q] + bhr);
            const float z  = sigf(gi[j + 8][q] + biz + gh[j + 8][q] + bhz);
            const float ng = tanhf(gi[j + 16][q] + bin + r_ * (gh[j + 16][q] + bhn));
            h[hb] = fmaxf((1.f - z) * ng + z * hv, 0.f);
        }
    }
}

// h[i][:] = emb[x[i]-1][:]
__global__ __launch_bounds__(256)
void gather_kernel(const int* __restrict__ x, const float* __restrict__ emb,
                   float* __restrict__ h) {
    const int tid = blockIdx.x * 256 + threadIdx.x;
    const int i = tid >> 5, c = (tid & 31) * 4;
    const int idx = x[i] - 1;
    *(float4*)(h + (size_t)i * 128 + c) = *(const float4*)(emb + (size_t)idx * 128 + c);
}

// ---------------- CSR build ----------------
__global__ __launch_bounds__(256)
void hist_kernel(const int* __restrict__ ei, int* __restrict__ deg) {
    const int e = blockIdx.x * 256 + threadIdx.x;
    atomicAdd(&deg[ei[NEDGES + e]], 1);
}

// single-dispatch exclusive scan of deg[51200]: 1024 thr x 50 elems each
__global__ __launch_bounds__(1024)
void scan_all(const int* __restrict__ deg, int* __restrict__ offs,
              int* __restrict__ cursor) {
    __shared__ int ps[1024];
    const int t = threadIdx.x;
    const int base = t * 50;
    int loc[50];
    int s = 0;
    #pragma unroll
    for (int i = 0; i < 50; ++i) { loc[i] = deg[base + i]; s += loc[i]; }
    ps[t] = s;
    __syncthreads();
    for (int off = 1; off < 1024; off <<= 1) {     // inclusive Hillis-Steele
        const int add = (t >= off) ? ps[t - off] : 0;
        __syncthreads();
        ps[t] += add;
        __syncthreads();
    }
    int run = ps[t] - s;                           // exclusive prefix of chunk
    #pragma unroll
    for (int i = 0; i < 50; ++i) {
        offs[base + i] = run;
        cursor[base + i] = run;
        run += loc[i];
    }
    if (t == 1023) offs[NNODES] = run;
}

__global__ __launch_bounds__(256)
void fill_kernel(const int* __restrict__ ei, int* __restrict__ cursor,
                 int* __restrict__ esrc) {
    const int e = blockIdx.x * 256 + threadIdx.x;
    const int dst = ei[NEDGES + e];
    const int pos = atomicAdd(&cursor[dst], 1);
    esrc[pos] = ei[e];
}

// agg[i] = sum over in-edges of m[src] (bf16 in, f32 acc, bf16 out)
__global__ __launch_bounds__(256)
void agg_kernel(const int* __restrict__ offs, const int* __restrict__ esrc,
                const ushort* __restrict__ mb, ushort* __restrict__ aggb) {
    const int node = blockIdx.x * 4 + (threadIdx.x >> 6);
    const int l = threadIdx.x & 63;
    const int s = offs[node], e = offs[node + 1];
    float ax = 0.f, ay = 0.f;
    for (int j = s; j < e; ++j) {
        const int src = esrc[j];
        const unsigned u = *(const unsigned*)(mb + (size_t)src * 128 + l * 2);
        ax += bf2f((ushort)(u & 0xffff));
        ay += bf2f((ushort)(u >> 16));
    }
    const unsigned o = (unsigned)f2bf(ax) | ((unsigned)f2bf(ay) << 16);
    *(unsigned*)(aggb + (size_t)node * 128 + l * 2) = o;
}

// Per-session attention readout; computes t1 = W1@vn + b1 + b2 inline.
__global__ __launch_bounds__(64)
void attn_kernel(const float* __restrict__ h, const float* __restrict__ W1,
                 const float* __restrict__ b1, const ushort* __restrict__ t2,
                 const float* __restrict__ qw, const float* __restrict__ qbp,
                 const float* __restrict__ b2, float* __restrict__ sg) {
    __shared__ float vns[128];
    const int b = blockIdx.x, l = threadIdx.x;
    const float* vn = h + ((size_t)b * NODES_PER + 49) * 128;
    vns[l] = vn[l];
    vns[64 + l] = vn[64 + l];
    __syncthreads();
    float t1a = b1[l] + b2[l];
    float t1b = b1[64 + l] + b2[64 + l];
    const float* w1a = W1 + (size_t)l * 128;
    const float* w1b = W1 + (size_t)(64 + l) * 128;
    #pragma unroll 8
    for (int k = 0; k < 128; k += 4) {
        const float4 wa = *(const float4*)(w1a + k);
        const float4 wb = *(const float4*)(w1b + k);
        t1a += wa.x * vns[k] + wa.y * vns[k + 1] + wa.z * vns[k + 2] + wa.w * vns[k + 3];
        t1b += wb.x * vns[k] + wb.y * vns[k + 1] + wb.z * vns[k + 2] + wb.w * vns[k + 3];
    }
    const float qa = qw[l], qb2 = qw[64 + l];
    const float qbias = qbp[0];
    const float*  hb  = h  + (size_t)b * NODES_PER * 128;
    const ushort* t2b = t2 + (size_t)b * NODES_PER * 128;
    float sga = 0.f, sgb = 0.f;
    for (int i = 0; i < NODES_PER; ++i) {
        const float ha  = hb[i * 128 + l], hb2v = hb[i * 128 + 64 + l];
        const float aa  = sigf(t1a + bf2f(t2b[i * 128 + l]));
        const float ab  = sigf(t1b + bf2f(t2b[i * 128 + 64 + l]));
        float p = aa * qa + ab * qb2;
        #pragma unroll
        for (int off = 32; off > 0; off >>= 1) p += __shfl_down(p, off);
        const float alpha = __shfl(p, 0) + qbias;
        sga += alpha * ha; sgb += alpha * hb2v;
    }
    sg[b * 128 + l] = sga;
    sg[b * 128 + 64 + l] = sgb;
}

// s_h[b] = W3 @ [v_n[b]; s_g[b]] + b3
__global__ __launch_bounds__(128)
void sh_kernel(const float* __restrict__ h, const float* __restrict__ sgbuf,
               const float* __restrict__ W3, const float* __restrict__ b3,
               float* __restrict__ sh) {
    __shared__ float W3s[128 * 257];
    __shared__ float vns[128], sgs[128];
    const int t = threadIdx.x;
    for (int f = t; f < 8192; f += 128) {
        const int r = f >> 6, c4 = (f & 63) * 4;
        const float4 v = *(const float4*)(W3 + (size_t)r * 256 + c4);
        float* d = &W3s[r * 257 + c4];
        d[0] = v.x; d[1] = v.y; d[2] = v.z; d[3] = v.w;
    }
    for (int bb = 0; bb < 8; ++bb) {
        const int b = blockIdx.x * 8 + bb;
        __syncthreads();
        vns[t] = h[((size_t)b * NODES_PER + 49) * 128 + t];
        sgs[t] = sgbuf[b * 128 + t];
        __syncthreads();
        float acc = b3[t];
        const float* wr = &W3s[t * 257];
        #pragma unroll 8
        for (int k = 0; k < 128; ++k) acc = fmaf(wr[k], vns[k], acc);
        #pragma unroll 8
        for (int k = 0; k < 128; ++k) acc = fmaf(wr[128 + k], sgs[k], acc);
        sh[b * 128 + t] = acc;
    }
}

extern "C" void kernel_launch(void* const* d_in, const int* in_sizes, int n_in,
                              void* d_out, int out_size, void* d_ws, size_t ws_size,
                              hipStream_t stream) {
    const int*   x   = (const int*)d_in[0];
    const int*   ei  = (const int*)d_in[1];
    const float* emb = (const float*)d_in[3];
    const float* Wg  = (const float*)d_in[4];
    const float* Wih = (const float*)d_in[5];
    const float* Whh = (const float*)d_in[6];
    const float* bih = (const float*)d_in[7];
    const float* bhh = (const float*)d_in[8];
    const float* W1  = (const float*)d_in[9];
    const float* b1  = (const float*)d_in[10];
    const float* W2  = (const float*)d_in[11];
    const float* b2  = (const float*)d_in[12];
    const float* qw  = (const float*)d_in[13];
    const float* qb  = (const float*)d_in[14];
    const float* W3  = (const float*)d_in[15];
    const float* b3  = (const float*)d_in[16];
    float* out = (float*)d_out;

    // workspace layout (float offsets); ~56 MB
    float*  ws   = (float*)d_ws;
    float*  h    = ws;                            // 6,553,600 f32
    ushort* mb   = (ushort*)(ws + 6553600);       // 6,553,600 bf16 (m, later t2)
    ushort* aggb = (ushort*)(ws + 9830400);       // 6,553,600 bf16
    float*  sg   = ws + 13107200;                 // 131,072
    float*  sh   = ws + 13238272;                 // 131,072
    int*    deg    = (int*)(ws + 13369344);       // 51,200
    int*    offs   = deg + NNODES;                // 51,201
    int*    cursor = offs + NNODES + 1;           // 51,200
    int*    esrc   = cursor + NNODES;             // 409,600

    hipMemsetAsync(deg, 0, NNODES * sizeof(int), stream);

    // h = emb[x-1]
    gather_kernel<<<6400, 256, 0, stream>>>(x, emb, h);
    // m = h @ W_gconv  (B staged transposed from Wg; bf16 out)
    gemm_tile<1, true, false><<<dim3(400, 1), 256, 0, stream>>>(mb, h, Wg, nullptr, NNODES, 128, 128);

    // CSR build + gather-sum
    hist_kernel<<<1600, 256, 0, stream>>>(ei, deg);
    scan_all<<<1, 1024, 0, stream>>>(deg, offs, cursor);
    fill_kernel<<<1600, 256, 0, stream>>>(ei, cursor, esrc);
    agg_kernel<<<12800, 256, 0, stream>>>(offs, esrc, mb, aggb);

    // fused GRU (single dispatch; gi/gh stay in registers)
    gru_fused<<<400, 512, 0, stream>>>(aggb, Wih, Whh, bih, bhh, h);

    // t2 = h @ W2^T (bf16, into mb — m is dead)
    gemm_tile<1, false, false><<<dim3(400, 1), 256, 0, stream>>>(mb, h, W2, nullptr, NNODES, 128, 128);
    // attention readout (t1 computed inline)
    attn_kernel<<<NB, 64, 0, stream>>>(h, W1, b1, mb, qw, qb, b2, sg);
    sh_kernel<<<128, 128, 0, stream>>>(h, sg, W3, b3, sh);
    // out = s_h @ emb^T  (XCD-swizzled 1D grid: 8 m-tiles x 784 n-tiles)
    gemm_tile<0, false, true><<<6272, 256, 0, stream>>>(out, sh, emb, nullptr, NB, NVOCAB, 128);
}

// Round 8
// 461.379 us; speedup vs baseline: 4.3155x; 1.0236x over previous
//
#include <hip/hip_runtime.h>
#include <math.h>

#define NNODES 51200
#define NEDGES 409600
#define NB 1024
#define NODES_PER 50
#define NVOCAB 100000

typedef __attribute__((ext_vector_type(8))) short bf16x8;
typedef __attribute__((ext_vector_type(4))) float f32x4;

__device__ __forceinline__ float sigf(float x) { return 1.0f / (1.0f + __expf(-x)); }

__device__ __forceinline__ ushort f2bf(float x) {   // RTNE f32 -> bf16
    union { float f; unsigned u; } v; v.f = x;
    const unsigned r = v.u + 0x7FFF + ((v.u >> 16) & 1);
    return (ushort)(r >> 16);
}
__device__ __forceinline__ float bf2f(ushort u) {
    union { float f; unsigned u; } v; v.u = ((unsigned)u) << 16; return v.f;
}
__device__ __forceinline__ bf16x8 cvt8(const float* __restrict__ src) {
    const float4 v0 = *(const float4*)src, v1 = *(const float4*)(src + 4);
    bf16x8 p;
    p[0] = (short)f2bf(v0.x); p[1] = (short)f2bf(v0.y);
    p[2] = (short)f2bf(v0.z); p[3] = (short)f2bf(v0.w);
    p[4] = (short)f2bf(v1.x); p[5] = (short)f2bf(v1.y);
    p[6] = (short)f2bf(v1.z); p[7] = (short)f2bf(v1.w);
    return p;
}

// ---------------------------------------------------------------------------
// Small bf16-out GEMM (used only for Wcomb = Wih @ Wg^T, 3 blocks).
// C[m][n] = sum_k A[m][k]*B[n][k]; C row stride = 128 (N=128 only).
// ---------------------------------------------------------------------------
__global__ __launch_bounds__(256)
void gemm_bf16(ushort* __restrict__ Cout, const float* __restrict__ A,
               const float* __restrict__ B) {
    __shared__ float4 smemv[4096];
    ushort* As = (ushort*)smemv;
    ushort* Bs = As + 128 * 128;
    const int m0 = blockIdx.x * 128;
    const int t  = threadIdx.x;

    #pragma unroll
    for (int f = t; f < 2048; f += 256) {
        const int r = f >> 4, c8 = (f & 15) * 8;
        *(bf16x8*)&As[r * 128 + (c8 ^ ((r & 7) << 3))] = cvt8(A + (size_t)(m0 + r) * 128 + c8);
        *(bf16x8*)&Bs[r * 128 + (c8 ^ ((r & 7) << 3))] = cvt8(B + (size_t)r * 128 + c8);
    }
    __syncthreads();

    const int lane = t & 63, wid = t >> 6;
    const int wr = wid >> 1, wc = wid & 1;
    const int l15 = lane & 15, kg = (lane >> 4) * 8;

    f32x4 acc[4][4] = {};
    #pragma unroll
    for (int kc = 0; kc < 4; ++kc) {
        const int cs = kc * 32 + kg;
        bf16x8 af[4], bfr[4];
        #pragma unroll
        for (int i = 0; i < 4; ++i) {
            const int ra = wr * 64 + i * 16 + l15;
            af[i] = *(const bf16x8*)&As[ra * 128 + (cs ^ ((ra & 7) << 3))];
            const int rb = wc * 64 + i * 16 + l15;
            bfr[i] = *(const bf16x8*)&Bs[rb * 128 + (cs ^ ((rb & 7) << 3))];
        }
        #pragma unroll
        for (int i = 0; i < 4; ++i)
            #pragma unroll
            for (int j = 0; j < 4; ++j)
                acc[i][j] = __builtin_amdgcn_mfma_f32_16x16x32_bf16(af[i], bfr[j], acc[i][j], 0, 0, 0);
    }
    const int cr0 = (lane >> 4) * 4;
    #pragma unroll
    for (int j = 0; j < 4; ++j) {
        const int col = wc * 64 + j * 16 + l15;
        #pragma unroll
        for (int i = 0; i < 4; ++i) {
            const int row = m0 + wr * 64 + i * 16 + cr0;
            #pragma unroll
            for (int q = 0; q < 4; ++q)
                Cout[(size_t)(row + q) * 128 + col] = f2bf(acc[i][j][q]);
        }
    }
}

// ---------------------------------------------------------------------------
// Vocab GEMM: out[1024][100000] = sh @ emb^T. A tile staged once per block,
// loop over 4 n-tiles (B restaged each iter). Direct acc->global stores
// (64B segments, L2 assembles lines). LDS 64 KB -> 2 blocks/CU.
// Grid 1600 = 8 mt x 200 grp; id%8 = XCD: grp = xcd*25 + (id>>3>>3), so each
// XCD owns a contiguous n-range and the 8 m-tiles of a group are adjacent.
// ---------------------------------------------------------------------------
__global__ __launch_bounds__(256)
void gemm_vocab(float* __restrict__ C, const float* __restrict__ A,
                const float* __restrict__ B) {
    __shared__ ushort As[128 * 128];
    __shared__ ushort Bs[128 * 128];
    const int id = blockIdx.x;
    const int xcd = id & 7, loc = id >> 3;
    const int mt = loc & 7, gin = loc >> 3;        // gin 0..24
    const int grp = xcd * 25 + gin;                // 0..199
    const int m0 = mt * 128;
    const int t = threadIdx.x;
    const int lane = t & 63, wid = t >> 6;
    const int wr = wid >> 1, wc = wid & 1;
    const int l15 = lane & 15, kg = (lane >> 4) * 8;
    const int cr0 = (lane >> 4) * 4;

    #pragma unroll
    for (int f = t; f < 2048; f += 256) {
        const int r = f >> 4, c8 = (f & 15) * 8;
        *(bf16x8*)&As[r * 128 + (c8 ^ ((r & 7) << 3))] = cvt8(A + (size_t)(m0 + r) * 128 + c8);
    }

    for (int it = 0; it < 4; ++it) {
        const int n0 = (grp * 4 + it) * 128;
        if (n0 >= NVOCAB) break;                   // block-uniform
        #pragma unroll
        for (int f = t; f < 2048; f += 256) {
            const int r = f >> 4, c8 = (f & 15) * 8;
            const int n = n0 + r;
            bf16x8 pk = {0, 0, 0, 0, 0, 0, 0, 0};
            if (n < NVOCAB) pk = cvt8(B + (size_t)n * 128 + c8);
            *(bf16x8*)&Bs[r * 128 + (c8 ^ ((r & 7) << 3))] = pk;
        }
        __syncthreads();

        f32x4 acc[4][4] = {};
        #pragma unroll
        for (int kc = 0; kc < 4; ++kc) {
            const int cs = kc * 32 + kg;
            bf16x8 af[4], bfr[4];
            #pragma unroll
            for (int i = 0; i < 4; ++i) {
                const int ra = wr * 64 + i * 16 + l15;
                af[i] = *(const bf16x8*)&As[ra * 128 + (cs ^ ((ra & 7) << 3))];
                const int rb = wc * 64 + i * 16 + l15;
                bfr[i] = *(const bf16x8*)&Bs[rb * 128 + (cs ^ ((rb & 7) << 3))];
            }
            #pragma unroll
            for (int i = 0; i < 4; ++i)
                #pragma unroll
                for (int j = 0; j < 4; ++j)
                    acc[i][j] = __builtin_amdgcn_mfma_f32_16x16x32_bf16(af[i], bfr[j], acc[i][j], 0, 0, 0);
        }

        #pragma unroll
        for (int j = 0; j < 4; ++j) {
            const int col = n0 + wc * 64 + j * 16 + l15;
            if (col < NVOCAB) {
                #pragma unroll
                for (int i = 0; i < 4; ++i) {
                    const size_t rbase = (size_t)(m0 + wr * 64 + i * 16 + cr0) * NVOCAB + col;
                    #pragma unroll
                    for (int q = 0; q < 4; ++q)
                        C[rbase + (size_t)q * NVOCAB] = acc[i][j][q];
                }
            }
        }
        __syncthreads();                           // Bs reads done before restage
    }
}

// ---------------------------------------------------------------------------
// Fully fused GRU: 400 blocks x 512 thr, 128 rows each.
// Phase 1: gi = S @ Wcomb^T (A=aggS bf16, B=Wcomb bf16 [384][128]).
// Phase 2: gh = h @ Whh^T (same LDS). Epilogue: gates + ReLU in place.
// ---------------------------------------------------------------------------
__global__ __launch_bounds__(512)
void gru_fused(const ushort* __restrict__ aggb, const ushort* __restrict__ Wc,
               const float* __restrict__ Whh, const float* __restrict__ bih,
               const float* __restrict__ bhh, float* __restrict__ h) {
    __shared__ ushort As[128 * 128];
    __shared__ ushort Bs[384 * 128];
    const int m0 = blockIdx.x * 128;
    const int t = threadIdx.x;
    const int lane = t & 63, wid = t >> 6;
    const int l15 = lane & 15, kg = (lane >> 4) * 8;

    // ---- phase 1: gi = S @ Wcomb^T ----
    #pragma unroll
    for (int f = t; f < 2048; f += 512) {
        const int r = f >> 4, c8 = (f & 15) * 8;
        const bf16x8 pk = *(const bf16x8*)(aggb + (size_t)(m0 + r) * 128 + c8);
        *(bf16x8*)&As[r * 128 + (c8 ^ ((r & 7) << 3))] = pk;
    }
    #pragma unroll
    for (int f = t; f < 6144; f += 512) {
        const int r = f >> 4, c8 = (f & 15) * 8;
        const bf16x8 pk = *(const bf16x8*)(Wc + (size_t)r * 128 + c8);
        *(bf16x8*)&Bs[r * 128 + (c8 ^ ((r & 7) << 3))] = pk;
    }
    __syncthreads();

    f32x4 gi[24] = {};
    #pragma unroll
    for (int kc = 0; kc < 4; ++kc) {
        const int cs = kc * 32 + kg;
        const int ra = wid * 16 + l15;
        const bf16x8 af = *(const bf16x8*)&As[ra * 128 + (cs ^ ((ra & 7) << 3))];
        #pragma unroll
        for (int j = 0; j < 24; ++j) {
            const int rb = j * 16 + l15;
            const bf16x8 bfr = *(const bf16x8*)&Bs[rb * 128 + (cs ^ ((rb & 7) << 3))];
            gi[j] = __builtin_amdgcn_mfma_f32_16x16x32_bf16(af, bfr, gi[j], 0, 0, 0);
        }
    }
    __syncthreads();

    // ---- phase 2: gh = h @ Whh^T ----
    #pragma unroll
    for (int f = t; f < 2048; f += 512) {
        const int r = f >> 4, c8 = (f & 15) * 8;
        *(bf16x8*)&As[r * 128 + (c8 ^ ((r & 7) << 3))] = cvt8(h + (size_t)(m0 + r) * 128 + c8);
    }
    #pragma unroll
    for (int f = t; f < 6144; f += 512) {
        const int r = f >> 4, c8 = (f & 15) * 8;
        *(bf16x8*)&Bs[r * 128 + (c8 ^ ((r & 7) << 3))] = cvt8(Whh + (size_t)r * 128 + c8);
    }
    __syncthreads();

    f32x4 gh[24] = {};
    #pragma unroll
    for (int kc = 0; kc < 4; ++kc) {
        const int cs = kc * 32 + kg;
        const int ra = wid * 16 + l15;
        const bf16x8 af = *(const bf16x8*)&As[ra * 128 + (cs ^ ((ra & 7) << 3))];
        #pragma unroll
        for (int j = 0; j < 24; ++j) {
            const int rb = j * 16 + l15;
            const bf16x8 bfr = *(const bf16x8*)&Bs[rb * 128 + (cs ^ ((rb & 7) << 3))];
            gh[j] = __builtin_amdgcn_mfma_f32_16x16x32_bf16(af, bfr, gh[j], 0, 0, 0);
        }
    }

    const int rl0 = m0 + wid * 16 + (lane >> 4) * 4;
    #pragma unroll
    for (int j = 0; j < 8; ++j) {
        const int col = j * 16 + l15;
        const float bir = bih[col], biz = bih[128 + col], bin = bih[256 + col];
        const float bhr = bhh[col], bhz = bhh[128 + col], bhn = bhh[256 + col];
        #pragma unroll
        for (int q = 0; q < 4; ++q) {
            const size_t hb = (size_t)(rl0 + q) * 128 + col;
            const float hv = h[hb];
            const float r_ = sigf(gi[j][q] + bir + gh[j][q] + bhr);
            const float z  = sigf(gi[j + 8][q] + biz + gh[j + 8][q] + bhz);
            const float ng = tanhf(gi[j + 16][q] + bin + r_ * (gh[j + 16][q] + bhn));
            h[hb] = fmaxf((1.f - z) * ng + z * hv, 0.f);
        }
    }
}

// h = emb[x-1] (f32) and hb = bf16 copy
__global__ __launch_bounds__(256)
void gather_kernel(const int* __restrict__ x, const float* __restrict__ emb,
                   float* __restrict__ h, ushort* __restrict__ hb) {
    const int tid = blockIdx.x * 256 + threadIdx.x;
    const int i = tid >> 5, c = (tid & 31) * 4;
    const int idx = x[i] - 1;
    const float4 v = *(const float4*)(emb + (size_t)idx * 128 + c);
    *(float4*)(h + (size_t)i * 128 + c) = v;
    uint2 uu;
    uu.x = (unsigned)f2bf(v.x) | ((unsigned)f2bf(v.y) << 16);
    uu.y = (unsigned)f2bf(v.z) | ((unsigned)f2bf(v.w) << 16);
    *(uint2*)(hb + (size_t)i * 128 + c) = uu;
}

// ---------------- CSR build ----------------
__global__ __launch_bounds__(256)
void hist_kernel(const int* __restrict__ ei, int* __restrict__ deg) {
    const int e = blockIdx.x * 256 + threadIdx.x;
    atomicAdd(&deg[ei[NEDGES + e]], 1);
}

__global__ __launch_bounds__(1024)
void scan_all(const int* __restrict__ deg, int* __restrict__ offs,
              int* __restrict__ cursor) {
    __shared__ int ps[1024];
    const int t = threadIdx.x;
    const int base = t * 50;
    int loc[50];
    int s = 0;
    #pragma unroll
    for (int i = 0; i < 50; ++i) { loc[i] = deg[base + i]; s += loc[i]; }
    ps[t] = s;
    __syncthreads();
    for (int off = 1; off < 1024; off <<= 1) {
        const int add = (t >= off) ? ps[t - off] : 0;
        __syncthreads();
        ps[t] += add;
        __syncthreads();
    }
    int run = ps[t] - s;
    #pragma unroll
    for (int i = 0; i < 50; ++i) {
        offs[base + i] = run;
        cursor[base + i] = run;
        run += loc[i];
    }
    if (t == 1023) offs[NNODES] = run;
}

__global__ __launch_bounds__(256)
void fill_kernel(const int* __restrict__ ei, int* __restrict__ cursor,
                 int* __restrict__ esrc) {
    const int e = blockIdx.x * 256 + threadIdx.x;
    const int dst = ei[NEDGES + e];
    const int pos = atomicAdd(&cursor[dst], 1);
    esrc[pos] = ei[e];
}

// S[i] = sum over in-edges of h[src] (bf16 in, f32 acc, bf16 out)
__global__ __launch_bounds__(256)
void agg_kernel(const int* __restrict__ offs, const int* __restrict__ esrc,
                const ushort* __restrict__ hb, ushort* __restrict__ aggb) {
    const int node = blockIdx.x * 4 + (threadIdx.x >> 6);
    const int l = threadIdx.x & 63;
    const int s = offs[node], e = offs[node + 1];
    float ax = 0.f, ay = 0.f;
    for (int j = s; j < e; ++j) {
        const int src = esrc[j];
        const unsigned u = *(const unsigned*)(hb + (size_t)src * 128 + l * 2);
        ax += bf2f((ushort)(u & 0xffff));
        ay += bf2f((ushort)(u >> 16));
    }
    const unsigned o = (unsigned)f2bf(ax) | ((unsigned)f2bf(ay) << 16);
    *(unsigned*)(aggb + (size_t)node * 128 + l * 2) = o;
}

// ---------------------------------------------------------------------------
// Fused t2-GEMM + attention: 512 blocks x 256 thr, 2 sessions (100 rows) each.
// t2 = h_tile @ W2^T via MFMA (rows 100..127 of tile = spill, ignored);
// t2 kept transposed in LDS; alphas node-per-lane; sg dim-per-lane.
// ---------------------------------------------------------------------------
__global__ __launch_bounds__(256)
void attn_fused(const float* __restrict__ h, const float* __restrict__ W1,
                const float* __restrict__ b1, const float* __restrict__ W2,
                const float* __restrict__ qw, const float* __restrict__ qbp,
                const float* __restrict__ b2, float* __restrict__ sg) {
    __shared__ ushort As[128 * 128];     // h tile bf16 (swizzled)
    __shared__ ushort Bs[128 * 128];     // W2 bf16 (swizzled)
    __shared__ float t2T[128 * 132];     // t2 transposed [d][row]
    __shared__ float t1s[2][128];
    __shared__ float qws[128];
    __shared__ float apar[2][2][64];
    __shared__ float alph[2][64];
    const int m0 = blockIdx.x * 100;
    const int t = threadIdx.x;
    const int lane = t & 63, wid = t >> 6;
    const int wr = wid >> 1, wc = wid & 1;
    const int l15 = lane & 15, kg = (lane >> 4) * 8;
    const int cr0 = (lane >> 4) * 4;

    #pragma unroll
    for (int f = t; f < 2048; f += 256) {
        const int r = f >> 4, c8 = (f & 15) * 8;
        int gr = m0 + r; if (gr > NNODES - 1) gr = NNODES - 1;   // clamp tail
        *(bf16x8*)&As[r * 128 + (c8 ^ ((r & 7) << 3))] = cvt8(h + (size_t)gr * 128 + c8);
        *(bf16x8*)&Bs[r * 128 + (c8 ^ ((r & 7) << 3))] = cvt8(W2 + (size_t)r * 128 + c8);
    }
    if (t < 128) qws[t] = qw[t];
    __syncthreads();

    // t2 = h @ W2^T
    f32x4 acc[4][4] = {};
    #pragma unroll
    for (int kc = 0; kc < 4; ++kc) {
        const int cs = kc * 32 + kg;
        bf16x8 af[4], bfr[4];
        #pragma unroll
        for (int i = 0; i < 4; ++i) {
            const int ra = wr * 64 + i * 16 + l15;
            af[i] = *(const bf16x8*)&As[ra * 128 + (cs ^ ((ra & 7) << 3))];
            const int rb = wc * 64 + i * 16 + l15;
            bfr[i] = *(const bf16x8*)&Bs[rb * 128 + (cs ^ ((rb & 7) << 3))];
        }
        #pragma unroll
        for (int i = 0; i < 4; ++i)
            #pragma unroll
            for (int j = 0; j < 4; ++j)
                acc[i][j] = __builtin_amdgcn_mfma_f32_16x16x32_bf16(af[i], bfr[j], acc[i][j], 0, 0, 0);
    }
    #pragma unroll
    for (int j = 0; j < 4; ++j) {
        const int col = wc * 64 + j * 16 + l15;
        #pragma unroll
        for (int i = 0; i < 4; ++i) {
            const int row = wr * 64 + i * 16 + cr0;
            #pragma unroll
            for (int q = 0; q < 4; ++q)
                t2T[col * 132 + row + q] = acc[i][j][q];
        }
    }

    // t1[d] = W1[d]·vn + b1[d] + b2[d]; wave's session = wid>>1, half = wid&1
    const int sess = wid >> 1, half = wid & 1;
    const int d = half * 64 + lane;
    const int vrow = sess * 50 + 49;
    const int vsw = (vrow & 7) << 3;
    float t1v = b1[d] + b2[d];
    const float* w1r = W1 + (size_t)d * 128;
    #pragma unroll 8
    for (int k = 0; k < 128; k += 4) {
        const float4 w = *(const float4*)(w1r + k);
        t1v += w.x * bf2f(As[vrow * 128 + ((k + 0) ^ vsw)])
             + w.y * bf2f(As[vrow * 128 + ((k + 1) ^ vsw)])
             + w.z * bf2f(As[vrow * 128 + ((k + 2) ^ vsw)])
             + w.w * bf2f(As[vrow * 128 + ((k + 3) ^ vsw)]);
    }
    t1s[sess][d] = t1v;
    __syncthreads();

    // alphas: lane = node (l<50), sum over this half's 64 dims
    float p = 0.f;
    if (lane < 50) {
        const int row = sess * 50 + lane;
        const int d0 = half * 64;
        #pragma unroll 8
        for (int dd = d0; dd < d0 + 64; ++dd)
            p += qws[dd] * sigf(t1s[sess][dd] + t2T[dd * 132 + row]);
    }
    apar[sess][half][lane] = p;
    __syncthreads();
    if (half == 0 && lane < 50)
        alph[sess][lane] = apar[sess][0][lane] + apar[sess][1][lane] + qbp[0];
    __syncthreads();

    // sg[d] = sum_i alpha_i * h[i][d]
    float sacc = 0.f;
    #pragma unroll 10
    for (int i = 0; i < 50; ++i) {
        const int row = sess * 50 + i;
        sacc += alph[sess][i] * bf2f(As[row * 128 + (d ^ ((row & 7) << 3))]);
    }
    sg[(size_t)(blockIdx.x * 2 + sess) * 128 + d] = sacc;
}

// s_h[b] = W3 @ [v_n[b]; s_g[b]] + b3
__global__ __launch_bounds__(128)
void sh_kernel(const float* __restrict__ h, const float* __restrict__ sgbuf,
               const float* __restrict__ W3, const float* __restrict__ b3,
               float* __restrict__ sh) {
    __shared__ float W3s[128 * 257];
    __shared__ float vns[128], sgs[128];
    const int t = threadIdx.x;
    for (int f = t; f < 8192; f += 128) {
        const int r = f >> 6, c4 = (f & 63) * 4;
        const float4 v = *(const float4*)(W3 + (size_t)r * 256 + c4);
        float* dd = &W3s[r * 257 + c4];
        dd[0] = v.x; dd[1] = v.y; dd[2] = v.z; dd[3] = v.w;
    }
    for (int bb = 0; bb < 8; ++bb) {
        const int b = blockIdx.x * 8 + bb;
        __syncthreads();
        vns[t] = h[((size_t)b * NODES_PER + 49) * 128 + t];
        sgs[t] = sgbuf[b * 128 + t];
        __syncthreads();
        float acc = b3[t];
        const float* wr = &W3s[t * 257];
        #pragma unroll 8
        for (int k = 0; k < 128; ++k) acc = fmaf(wr[k], vns[k], acc);
        #pragma unroll 8
        for (int k = 0; k < 128; ++k) acc = fmaf(wr[128 + k], sgs[k], acc);
        sh[b * 128 + t] = acc;
    }
}

extern "C" void kernel_launch(void* const* d_in, const int* in_sizes, int n_in,
                              void* d_out, int out_size, void* d_ws, size_t ws_size,
                              hipStream_t stream) {
    const int*   x   = (const int*)d_in[0];
    const int*   ei  = (const int*)d_in[1];
    const float* emb = (const float*)d_in[3];
    const float* Wg  = (const float*)d_in[4];
    const float* Wih = (const float*)d_in[5];
    const float* Whh = (const float*)d_in[6];
    const float* bih = (const float*)d_in[7];
    const float* bhh = (const float*)d_in[8];
    const float* W1  = (const float*)d_in[9];
    const float* b1  = (const float*)d_in[10];
    const float* W2  = (const float*)d_in[11];
    const float* b2  = (const float*)d_in[12];
    const float* qw  = (const float*)d_in[13];
    const float* qb  = (const float*)d_in[14];
    const float* W3  = (const float*)d_in[15];
    const float* b3  = (const float*)d_in[16];
    float* out = (float*)d_out;

    // workspace layout (float offsets); ~57 MB
    float*  ws   = (float*)d_ws;
    float*  h    = ws;                            // 6,553,600 f32
    ushort* hb   = (ushort*)(ws + 6553600);       // 6,553,600 bf16
    ushort* aggb = (ushort*)(ws + 9830400);       // 6,553,600 bf16
    ushort* Wc   = (ushort*)(ws + 13107200);      // 49,152 bf16 (384x128)
    float*  sg   = ws + 13131776;                 // 131,072
    float*  sh   = ws + 13262848;                 // 131,072
    int*    deg    = (int*)(ws + 13393920);       // 51,200
    int*    offs   = deg + NNODES;                // 51,201
    int*    cursor = offs + NNODES + 1;           // 51,200
    int*    esrc   = cursor + NNODES;             // 409,600

    hipMemsetAsync(deg, 0, NNODES * sizeof(int), stream);

    // Wcomb = Wih @ Wg^T  (bf16, [384][128]) — gi = S @ Wcomb^T later
    gemm_bf16<<<3, 256, 0, stream>>>(Wc, Wih, Wg);
    // h = emb[x-1] (+bf16 copy)
    gather_kernel<<<6400, 256, 0, stream>>>(x, emb, h, hb);

    // CSR build + gather-sum S = sum h[src]
    hist_kernel<<<1600, 256, 0, stream>>>(ei, deg);
    scan_all<<<1, 1024, 0, stream>>>(deg, offs, cursor);
    fill_kernel<<<1600, 256, 0, stream>>>(ei, cursor, esrc);
    agg_kernel<<<12800, 256, 0, stream>>>(offs, esrc, hb, aggb);

    // fused GRU (gi/gh in registers)
    gru_fused<<<400, 512, 0, stream>>>(aggb, Wc, Whh, bih, bhh, h);

    // fused t2 + attention -> sg
    attn_fused<<<512, 256, 0, stream>>>(h, W1, b1, W2, qw, qb, b2, sg);
    sh_kernel<<<128, 128, 0, stream>>>(h, sg, W3, b3, sh);
    // out = s_h @ emb^T
    gemm_vocab<<<1600, 256, 0, stream>>>(out, sh, emb);
}

// Round 9
// 435.909 us; speedup vs baseline: 4.5676x; 1.0584x over previous
//
#include <hip/hip_runtime.h>
#include <math.h>

#define NNODES 51200
#define NEDGES 409600
#define NB 1024
#define NODES_PER 50
#define NVOCAB 100000

typedef __attribute__((ext_vector_type(8))) short bf16x8;
typedef __attribute__((ext_vector_type(4))) float f32x4;

__device__ __forceinline__ float sigf(float x) { return 1.0f / (1.0f + __expf(-x)); }

__device__ __forceinline__ ushort f2bf(float x) {   // RTNE f32 -> bf16
    union { float f; unsigned u; } v; v.f = x;
    const unsigned r = v.u + 0x7FFF + ((v.u >> 16) & 1);
    return (ushort)(r >> 16);
}
__device__ __forceinline__ float bf2f(ushort u) {
    union { float f; unsigned u; } v; v.u = ((unsigned)u) << 16; return v.f;
}
__device__ __forceinline__ bf16x8 cvt8(const float* __restrict__ src) {
    const float4 v0 = *(const float4*)src, v1 = *(const float4*)(src + 4);
    bf16x8 p;
    p[0] = (short)f2bf(v0.x); p[1] = (short)f2bf(v0.y);
    p[2] = (short)f2bf(v0.z); p[3] = (short)f2bf(v0.w);
    p[4] = (short)f2bf(v1.x); p[5] = (short)f2bf(v1.y);
    p[6] = (short)f2bf(v1.z); p[7] = (short)f2bf(v1.w);
    return p;
}

// ---------------------------------------------------------------------------
// Small bf16-out GEMM (Wcomb = Wih @ Wg^T, 3 blocks).
// ---------------------------------------------------------------------------
__global__ __launch_bounds__(256)
void gemm_bf16(ushort* __restrict__ Cout, const float* __restrict__ A,
               const float* __restrict__ B) {
    __shared__ float4 smemv[4096];
    ushort* As = (ushort*)smemv;
    ushort* Bs = As + 128 * 128;
    const int m0 = blockIdx.x * 128;
    const int t  = threadIdx.x;

    #pragma unroll
    for (int f = t; f < 2048; f += 256) {
        const int r = f >> 4, c8 = (f & 15) * 8;
        *(bf16x8*)&As[r * 128 + (c8 ^ ((r & 7) << 3))] = cvt8(A + (size_t)(m0 + r) * 128 + c8);
        *(bf16x8*)&Bs[r * 128 + (c8 ^ ((r & 7) << 3))] = cvt8(B + (size_t)r * 128 + c8);
    }
    __syncthreads();

    const int lane = t & 63, wid = t >> 6;
    const int wr = wid >> 1, wc = wid & 1;
    const int l15 = lane & 15, kg = (lane >> 4) * 8;

    f32x4 acc[4][4] = {};
    #pragma unroll
    for (int kc = 0; kc < 4; ++kc) {
        const int cs = kc * 32 + kg;
        bf16x8 af[4], bfr[4];
        #pragma unroll
        for (int i = 0; i < 4; ++i) {
            const int ra = wr * 64 + i * 16 + l15;
            af[i] = *(const bf16x8*)&As[ra * 128 + (cs ^ ((ra & 7) << 3))];
            const int rb = wc * 64 + i * 16 + l15;
            bfr[i] = *(const bf16x8*)&Bs[rb * 128 + (cs ^ ((rb & 7) << 3))];
        }
        #pragma unroll
        for (int i = 0; i < 4; ++i)
            #pragma unroll
            for (int j = 0; j < 4; ++j)
                acc[i][j] = __builtin_amdgcn_mfma_f32_16x16x32_bf16(af[i], bfr[j], acc[i][j], 0, 0, 0);
    }
    const int cr0 = (lane >> 4) * 4;
    #pragma unroll
    for (int j = 0; j < 4; ++j) {
        const int col = wc * 64 + j * 16 + l15;
        #pragma unroll
        for (int i = 0; i < 4; ++i) {
            const int row = m0 + wr * 64 + i * 16 + cr0;
            #pragma unroll
            for (int q = 0; q < 4; ++q)
                Cout[(size_t)(row + q) * 128 + col] = f2bf(acc[i][j][q]);
        }
    }
}

// ---------------------------------------------------------------------------
// Vocab GEMM: out[1024][100000] = sh @ emb^T. A staged ONCE per block;
// loop over 4 n-tiles. Epilogue repacks acc through Cs[64][128] f32
// (overlaying Bs, 2 row-halves) -> wave-contiguous 512B float4 stores.
// LDS 64 KB -> 2 blocks/CU. Grid 1600, id%8 = XCD: each XCD owns a
// contiguous n-range; the 8 m-tiles of a group are adjacent -> B fetched
// ~once per XCD L2.
// ---------------------------------------------------------------------------
__global__ __launch_bounds__(256)
void gemm_vocab(float* __restrict__ C, const float* __restrict__ A,
                const float* __restrict__ B) {
    __shared__ ushort As[128 * 128];
    __shared__ ushort Bs[128 * 128];
    float* Cs = (float*)Bs;                        // [64][128] f32 = 32 KB
    const int id = blockIdx.x;
    const int xcd = id & 7, loc = id >> 3;
    const int mt = loc & 7, gin = loc >> 3;        // gin 0..24
    const int grp = xcd * 25 + gin;                // 0..199
    const int m0 = mt * 128;
    const int t = threadIdx.x;
    const int lane = t & 63, wid = t >> 6;
    const int wr = wid >> 1, wc = wid & 1;
    const int l15 = lane & 15, kg = (lane >> 4) * 8;
    const int cr0 = (lane >> 4) * 4;

    #pragma unroll
    for (int f = t; f < 2048; f += 256) {
        const int r = f >> 4, c8 = (f & 15) * 8;
        *(bf16x8*)&As[r * 128 + (c8 ^ ((r & 7) << 3))] = cvt8(A + (size_t)(m0 + r) * 128 + c8);
    }

    for (int it = 0; it < 4; ++it) {
        const int n0 = (grp * 4 + it) * 128;
        if (n0 >= NVOCAB) break;                   // block-uniform
        __syncthreads();                           // prev repack reads done
        #pragma unroll
        for (int f = t; f < 2048; f += 256) {
            const int r = f >> 4, c8 = (f & 15) * 8;
            const int n = n0 + r;
            bf16x8 pk = {0, 0, 0, 0, 0, 0, 0, 0};
            if (n < NVOCAB) pk = cvt8(B + (size_t)n * 128 + c8);
            *(bf16x8*)&Bs[r * 128 + (c8 ^ ((r & 7) << 3))] = pk;
        }
        __syncthreads();

        f32x4 acc[4][4] = {};
        #pragma unroll
        for (int kc = 0; kc < 4; ++kc) {
            const int cs = kc * 32 + kg;
            bf16x8 af[4], bfr[4];
            #pragma unroll
            for (int i = 0; i < 4; ++i) {
                const int ra = wr * 64 + i * 16 + l15;
                af[i] = *(const bf16x8*)&As[ra * 128 + (cs ^ ((ra & 7) << 3))];
                const int rb = wc * 64 + i * 16 + l15;
                bfr[i] = *(const bf16x8*)&Bs[rb * 128 + (cs ^ ((rb & 7) << 3))];
            }
            #pragma unroll
            for (int i = 0; i < 4; ++i)
                #pragma unroll
                for (int j = 0; j < 4; ++j)
                    acc[i][j] = __builtin_amdgcn_mfma_f32_16x16x32_bf16(af[i], bfr[j], acc[i][j], 0, 0, 0);
        }
        __syncthreads();                           // MFMA reads of Bs done

        #pragma unroll
        for (int half = 0; half < 2; ++half) {
            if (wr == half) {
                #pragma unroll
                for (int j = 0; j < 4; ++j) {
                    const int col = wc * 64 + j * 16 + l15;
                    #pragma unroll
                    for (int i = 0; i < 4; ++i) {
                        const int rl = i * 16 + cr0;       // 0..63
                        #pragma unroll
                        for (int q = 0; q < 4; ++q)
                            Cs[(rl + q) * 128 + col] = acc[i][j][q];
                    }
                }
            }
            __syncthreads();
            #pragma unroll
            for (int f = t; f < 2048; f += 256) {
                const int r = f >> 5, c4 = (f & 31) * 4;
                if (n0 + c4 < NVOCAB) {
                    const f32x4 v = *(const f32x4*)&Cs[r * 128 + c4];
                    *(f32x4*)(C + (size_t)(m0 + half * 64 + r) * NVOCAB + n0 + c4) = v;
                }
            }
            __syncthreads();
        }
    }
}

// ---------------------------------------------------------------------------
// Fully fused GRU: 400 blocks x 512 thr, 128 rows each.
// Phase 1: gi = S @ Wcomb^T. Phase 2: gh = h @ Whh^T (same LDS).
// Epilogue: gates + ReLU in place.
// ---------------------------------------------------------------------------
__global__ __launch_bounds__(512)
void gru_fused(const ushort* __restrict__ aggb, const ushort* __restrict__ Wc,
               const float* __restrict__ Whh, const float* __restrict__ bih,
               const float* __restrict__ bhh, float* __restrict__ h) {
    __shared__ ushort As[128 * 128];
    __shared__ ushort Bs[384 * 128];
    const int m0 = blockIdx.x * 128;
    const int t = threadIdx.x;
    const int lane = t & 63, wid = t >> 6;
    const int l15 = lane & 15, kg = (lane >> 4) * 8;

    #pragma unroll
    for (int f = t; f < 2048; f += 512) {
        const int r = f >> 4, c8 = (f & 15) * 8;
        const bf16x8 pk = *(const bf16x8*)(aggb + (size_t)(m0 + r) * 128 + c8);
        *(bf16x8*)&As[r * 128 + (c8 ^ ((r & 7) << 3))] = pk;
    }
    #pragma unroll
    for (int f = t; f < 6144; f += 512) {
        const int r = f >> 4, c8 = (f & 15) * 8;
        const bf16x8 pk = *(const bf16x8*)(Wc + (size_t)r * 128 + c8);
        *(bf16x8*)&Bs[r * 128 + (c8 ^ ((r & 7) << 3))] = pk;
    }
    __syncthreads();

    f32x4 gi[24] = {};
    #pragma unroll
    for (int kc = 0; kc < 4; ++kc) {
        const int cs = kc * 32 + kg;
        const int ra = wid * 16 + l15;
        const bf16x8 af = *(const bf16x8*)&As[ra * 128 + (cs ^ ((ra & 7) << 3))];
        #pragma unroll
        for (int j = 0; j < 24; ++j) {
            const int rb = j * 16 + l15;
            const bf16x8 bfr = *(const bf16x8*)&Bs[rb * 128 + (cs ^ ((rb & 7) << 3))];
            gi[j] = __builtin_amdgcn_mfma_f32_16x16x32_bf16(af, bfr, gi[j], 0, 0, 0);
        }
    }
    __syncthreads();

    #pragma unroll
    for (int f = t; f < 2048; f += 512) {
        const int r = f >> 4, c8 = (f & 15) * 8;
        *(bf16x8*)&As[r * 128 + (c8 ^ ((r & 7) << 3))] = cvt8(h + (size_t)(m0 + r) * 128 + c8);
    }
    #pragma unroll
    for (int f = t; f < 6144; f += 512) {
        const int r = f >> 4, c8 = (f & 15) * 8;
        *(bf16x8*)&Bs[r * 128 + (c8 ^ ((r & 7) << 3))] = cvt8(Whh + (size_t)r * 128 + c8);
    }
    __syncthreads();

    f32x4 gh[24] = {};
    #pragma unroll
    for (int kc = 0; kc < 4; ++kc) {
        const int cs = kc * 32 + kg;
        const int ra = wid * 16 + l15;
        const bf16x8 af = *(const bf16x8*)&As[ra * 128 + (cs ^ ((ra & 7) << 3))];
        #pragma unroll
        for (int j = 0; j < 24; ++j) {
            const int rb = j * 16 + l15;
            const bf16x8 bfr = *(const bf16x8*)&Bs[rb * 128 + (cs ^ ((rb & 7) << 3))];
            gh[j] = __builtin_amdgcn_mfma_f32_16x16x32_bf16(af, bfr, gh[j], 0, 0, 0);
        }
    }

    const int rl0 = m0 + wid * 16 + (lane >> 4) * 4;
    #pragma unroll
    for (int j = 0; j < 8; ++j) {
        const int col = j * 16 + l15;
        const float bir = bih[col], biz = bih[128 + col], bin = bih[256 + col];
        const float bhr = bhh[col], bhz = bhh[128 + col], bhn = bhh[256 + col];
        #pragma unroll
        for (int q = 0; q < 4; ++q) {
            const size_t hb = (size_t)(rl0 + q) * 128 + col;
            const float hv = h[hb];
            const float r_ = sigf(gi[j][q] + bir + gh[j][q] + bhr);
            const float z  = sigf(gi[j + 8][q] + biz + gh[j + 8][q] + bhz);
            const float ng = tanhf(gi[j + 16][q] + bin + r_ * (gh[j + 16][q] + bhn));
            h[hb] = fmaxf((1.f - z) * ng + z * hv, 0.f);
        }
    }
}

// h = emb[x-1] (f32) and hb = bf16 copy
__global__ __launch_bounds__(256)
void gather_kernel(const int* __restrict__ x, const float* __restrict__ emb,
                   float* __restrict__ h, ushort* __restrict__ hb) {
    const int tid = blockIdx.x * 256 + threadIdx.x;
    const int i = tid >> 5, c = (tid & 31) * 4;
    const int idx = x[i] - 1;
    const float4 v = *(const float4*)(emb + (size_t)idx * 128 + c);
    *(float4*)(h + (size_t)i * 128 + c) = v;
    uint2 uu;
    uu.x = (unsigned)f2bf(v.x) | ((unsigned)f2bf(v.y) << 16);
    uu.y = (unsigned)f2bf(v.z) | ((unsigned)f2bf(v.w) << 16);
    *(uint2*)(hb + (size_t)i * 128 + c) = uu;
}

// ---------------- CSR build ----------------
__global__ __launch_bounds__(256)
void hist_kernel(const int* __restrict__ ei, int* __restrict__ deg) {
    const int e = blockIdx.x * 256 + threadIdx.x;
    atomicAdd(&deg[ei[NEDGES + e]], 1);
}

__global__ __launch_bounds__(1024)
void scan_all(const int* __restrict__ deg, int* __restrict__ offs,
              int* __restrict__ cursor) {
    __shared__ int ps[1024];
    const int t = threadIdx.x;
    const int base = t * 50;
    int loc[50];
    int s = 0;
    #pragma unroll
    for (int i = 0; i < 50; ++i) { loc[i] = deg[base + i]; s += loc[i]; }
    ps[t] = s;
    __syncthreads();
    for (int off = 1; off < 1024; off <<= 1) {
        const int add = (t >= off) ? ps[t - off] : 0;
        __syncthreads();
        ps[t] += add;
        __syncthreads();
    }
    int run = ps[t] - s;
    #pragma unroll
    for (int i = 0; i < 50; ++i) {
        offs[base + i] = run;
        cursor[base + i] = run;
        run += loc[i];
    }
    if (t == 1023) offs[NNODES] = run;
}

__global__ __launch_bounds__(256)
void fill_kernel(const int* __restrict__ ei, int* __restrict__ cursor,
                 int* __restrict__ esrc) {
    const int e = blockIdx.x * 256 + threadIdx.x;
    const int dst = ei[NEDGES + e];
    const int pos = atomicAdd(&cursor[dst], 1);
    esrc[pos] = ei[e];
}

// S[i] = sum over in-edges of h[src] (bf16 in, f32 acc, bf16 out)
__global__ __launch_bounds__(256)
void agg_kernel(const int* __restrict__ offs, const int* __restrict__ esrc,
                const ushort* __restrict__ hb, ushort* __restrict__ aggb) {
    const int node = blockIdx.x * 4 + (threadIdx.x >> 6);
    const int l = threadIdx.x & 63;
    const int s = offs[node], e = offs[node + 1];
    float ax = 0.f, ay = 0.f;
    for (int j = s; j < e; ++j) {
        const int src = esrc[j];
        const unsigned u = *(const unsigned*)(hb + (size_t)src * 128 + l * 2);
        ax += bf2f((ushort)(u & 0xffff));
        ay += bf2f((ushort)(u >> 16));
    }
    const unsigned o = (unsigned)f2bf(ax) | ((unsigned)f2bf(ay) << 16);
    *(unsigned*)(aggb + (size_t)node * 128 + l * 2) = o;
}

// ---------------------------------------------------------------------------
// Fused t2-GEMM + attention: 512 blocks x 256 thr, 2 sessions (100 rows).
// t2 (bf16, swizzled, transposed [d][row]) OVERLAYS Bs after the MFMA ->
// LDS ~67 KB -> 2 blocks/CU.
// ---------------------------------------------------------------------------
__global__ __launch_bounds__(256)
void attn_fused(const float* __restrict__ h, const float* __restrict__ W1,
                const float* __restrict__ b1, const float* __restrict__ W2,
                const float* __restrict__ qw, const float* __restrict__ qbp,
                const float* __restrict__ b2, float* __restrict__ sg) {
    __shared__ ushort As[128 * 128];     // h tile bf16 (swizzled)
    __shared__ ushort Bs[128 * 128];     // W2 bf16, then t2T bf16 [d][row]
    __shared__ float t1s[2][128];
    __shared__ float qws[128];
    __shared__ float apar[2][2][64];
    __shared__ float alph[2][64];
    const int m0 = blockIdx.x * 100;
    const int t = threadIdx.x;
    const int lane = t & 63, wid = t >> 6;
    const int wr = wid >> 1, wc = wid & 1;
    const int l15 = lane & 15, kg = (lane >> 4) * 8;
    const int cr0 = (lane >> 4) * 4;

    #pragma unroll
    for (int f = t; f < 2048; f += 256) {
        const int r = f >> 4, c8 = (f & 15) * 8;
        int gr = m0 + r; if (gr > NNODES - 1) gr = NNODES - 1;   // clamp tail
        *(bf16x8*)&As[r * 128 + (c8 ^ ((r & 7) << 3))] = cvt8(h + (size_t)gr * 128 + c8);
        *(bf16x8*)&Bs[r * 128 + (c8 ^ ((r & 7) << 3))] = cvt8(W2 + (size_t)r * 128 + c8);
    }
    if (t < 128) qws[t] = qw[t];
    __syncthreads();

    // t2 = h @ W2^T
    f32x4 acc[4][4] = {};
    #pragma unroll
    for (int kc = 0; kc < 4; ++kc) {
        const int cs = kc * 32 + kg;
        bf16x8 af[4], bfr[4];
        #pragma unroll
        for (int i = 0; i < 4; ++i) {
            const int ra = wr * 64 + i * 16 + l15;
            af[i] = *(const bf16x8*)&As[ra * 128 + (cs ^ ((ra & 7) << 3))];
            const int rb = wc * 64 + i * 16 + l15;
            bfr[i] = *(const bf16x8*)&Bs[rb * 128 + (cs ^ ((rb & 7) << 3))];
        }
        #pragma unroll
        for (int i = 0; i < 4; ++i)
            #pragma unroll
            for (int j = 0; j < 4; ++j)
                acc[i][j] = __builtin_amdgcn_mfma_f32_16x16x32_bf16(af[i], bfr[j], acc[i][j], 0, 0, 0);
    }
    __syncthreads();                               // MFMA reads of Bs done

    // t2T (bf16, swizzled) overlays Bs: addr = d*128 + (row ^ ((d&7)<<3))
    #pragma unroll
    for (int j = 0; j < 4; ++j) {
        const int col = wc * 64 + j * 16 + l15;
        const int csw = (col & 7) << 3;
        #pragma unroll
        for (int i = 0; i < 4; ++i) {
            const int row = wr * 64 + i * 16 + cr0;
            #pragma unroll
            for (int q = 0; q < 4; ++q)
                Bs[col * 128 + ((row + q) ^ csw)] = f2bf(acc[i][j][q]);
        }
    }

    // t1[d] = W1[d]·vn + b1[d] + b2[d] (reads As only; overlaps t2 writes)
    const int sess = wid >> 1, half = wid & 1;
    const int d = half * 64 + lane;
    const int vrow = sess * 50 + 49;
    const int vsw = (vrow & 7) << 3;
    float t1v = b1[d] + b2[d];
    const float* w1r = W1 + (size_t)d * 128;
    #pragma unroll 8
    for (int k = 0; k < 128; k += 4) {
        const float4 w = *(const float4*)(w1r + k);
        t1v += w.x * bf2f(As[vrow * 128 + ((k + 0) ^ vsw)])
             + w.y * bf2f(As[vrow * 128 + ((k + 1) ^ vsw)])
             + w.z * bf2f(As[vrow * 128 + ((k + 2) ^ vsw)])
             + w.w * bf2f(As[vrow * 128 + ((k + 3) ^ vsw)]);
    }
    t1s[sess][d] = t1v;
    __syncthreads();

    // alphas: lane = node (l<50), sum over this half's 64 dims
    float p = 0.f;
    if (lane < 50) {
        const int row = sess * 50 + lane;
        const int d0 = half * 64;
        #pragma unroll 8
        for (int dd = d0; dd < d0 + 64; ++dd)
            p += qws[dd] * sigf(t1s[sess][dd] + bf2f(Bs[dd * 128 + (row ^ ((dd & 7) << 3))]));
    }
    apar[sess][half][lane] = p;
    __syncthreads();
    if (half == 0 && lane < 50)
        alph[sess][lane] = apar[sess][0][lane] + apar[sess][1][lane] + qbp[0];
    __syncthreads();

    // sg[d] = sum_i alpha_i * h[i][d]
    float sacc = 0.f;
    #pragma unroll 10
    for (int i = 0; i < 50; ++i) {
        const int row = sess * 50 + i;
        sacc += alph[sess][i] * bf2f(As[row * 128 + (d ^ ((row & 7) << 3))]);
    }
    sg[(size_t)(blockIdx.x * 2 + sess) * 128 + d] = sacc;
}

// s_h[b] = W3 @ [v_n[b]; s_g[b]] + b3
__global__ __launch_bounds__(128)
void sh_kernel(const float* __restrict__ h, const float* __restrict__ sgbuf,
               const float* __restrict__ W3, const float* __restrict__ b3,
               float* __restrict__ sh) {
    __shared__ float W3s[128 * 257];
    __shared__ float vns[128], sgs[128];
    const int t = threadIdx.x;
    for (int f = t; f < 8192; f += 128) {
        const int r = f >> 6, c4 = (f & 63) * 4;
        const float4 v = *(const float4*)(W3 + (size_t)r * 256 + c4);
        float* dd = &W3s[r * 257 + c4];
        dd[0] = v.x; dd[1] = v.y; dd[2] = v.z; dd[3] = v.w;
    }
    for (int bb = 0; bb < 8; ++bb) {
        const int b = blockIdx.x * 8 + bb;
        __syncthreads();
        vns[t] = h[((size_t)b * NODES_PER + 49) * 128 + t];
        sgs[t] = sgbuf[b * 128 + t];
        __syncthreads();
        float acc = b3[t];
        const float* wr = &W3s[t * 257];
        #pragma unroll 8
        for (int k = 0; k < 128; ++k) acc = fmaf(wr[k], vns[k], acc);
        #pragma unroll 8
        for (int k = 0; k < 128; ++k) acc = fmaf(wr[128 + k], sgs[k], acc);
        sh[b * 128 + t] = acc;
    }
}

extern "C" void kernel_launch(void* const* d_in, const int* in_sizes, int n_in,
                              void* d_out, int out_size, void* d_ws, size_t ws_size,
                              hipStream_t stream) {
    const int*   x   = (const int*)d_in[0];
    const int*   ei  = (const int*)d_in[1];
    const float* emb = (const float*)d_in[3];
    const float* Wg  = (const float*)d_in[4];
    const float* Wih = (const float*)d_in[5];
    const float* Whh = (const float*)d_in[6];
    const float* bih = (const float*)d_in[7];
    const float* bhh = (const float*)d_in[8];
    const float* W1  = (const float*)d_in[9];
    const float* b1  = (const float*)d_in[10];
    const float* W2  = (const float*)d_in[11];
    const float* b2  = (const float*)d_in[12];
    const float* qw  = (const float*)d_in[13];
    const float* qb  = (const float*)d_in[14];
    const float* W3  = (const float*)d_in[15];
    const float* b3  = (const float*)d_in[16];
    float* out = (float*)d_out;

    // workspace layout (float offsets); ~57 MB
    float*  ws   = (float*)d_ws;
    float*  h    = ws;                            // 6,553,600 f32
    ushort* hb   = (ushort*)(ws + 6553600);       // 6,553,600 bf16
    ushort* aggb = (ushort*)(ws + 9830400);       // 6,553,600 bf16
    ushort* Wc   = (ushort*)(ws + 13107200);      // 49,152 bf16 (384x128)
    float*  sg   = ws + 13131776;                 // 131,072
    float*  sh   = ws + 13262848;                 // 131,072
    int*    deg    = (int*)(ws + 13393920);       // 51,200
    int*    offs   = deg + NNODES;                // 51,201
    int*    cursor = offs + NNODES + 1;           // 51,200
    int*    esrc   = cursor + NNODES;             // 409,600

    hipMemsetAsync(deg, 0, NNODES * sizeof(int), stream);

    // Wcomb = Wih @ Wg^T  (bf16, [384][128])
    gemm_bf16<<<3, 256, 0, stream>>>(Wc, Wih, Wg);
    // h = emb[x-1] (+bf16 copy)
    gather_kernel<<<6400, 256, 0, stream>>>(x, emb, h, hb);

    // CSR build + gather-sum S = sum h[src]
    hist_kernel<<<1600, 256, 0, stream>>>(ei, deg);
    scan_all<<<1, 1024, 0, stream>>>(deg, offs, cursor);
    fill_kernel<<<1600, 256, 0, stream>>>(ei, cursor, esrc);
    agg_kernel<<<12800, 256, 0, stream>>>(offs, esrc, hb, aggb);

    // fused GRU (gi/gh in registers)
    gru_fused<<<400, 512, 0, stream>>>(aggb, Wc, Whh, bih, bhh, h);

    // fused t2 + attention -> sg
    attn_fused<<<512, 256, 0, stream>>>(h, W1, b1, W2, qw, qb, b2, sg);
    sh_kernel<<<128, 128, 0, stream>>>(h, sg, W3, b3, sh);
    // out = s_h @ emb^T
    gemm_vocab<<<1600, 256, 0, stream>>>(out, sh, emb);
}

// Round 10
// 365.704 us; speedup vs baseline: 5.4445x; 1.1920x over previous
//
#include <hip/hip_runtime.h>
#include <math.h>

#define NNODES 51200
#define NEDGES 409600
#define NB 1024
#define NODES_PER 50
#define NVOCAB 100000
#define NVPAD 100096

typedef __attribute__((ext_vector_type(8))) short bf16x8;
typedef __attribute__((ext_vector_type(4))) float f32x4;

__device__ __forceinline__ float sigf(float x) { return 1.0f / (1.0f + __expf(-x)); }

__device__ __forceinline__ ushort f2bf(float x) {   // RTNE f32 -> bf16
    union { float f; unsigned u; } v; v.f = x;
    const unsigned r = v.u + 0x7FFF + ((v.u >> 16) & 1);
    return (ushort)(r >> 16);
}
__device__ __forceinline__ float bf2f(ushort u) {
    union { float f; unsigned u; } v; v.u = ((unsigned)u) << 16; return v.f;
}
__device__ __forceinline__ bf16x8 cvt8(const float* __restrict__ src) {
    const float4 v0 = *(const float4*)src, v1 = *(const float4*)(src + 4);
    bf16x8 p;
    p[0] = (short)f2bf(v0.x); p[1] = (short)f2bf(v0.y);
    p[2] = (short)f2bf(v0.z); p[3] = (short)f2bf(v0.w);
    p[4] = (short)f2bf(v1.x); p[5] = (short)f2bf(v1.y);
    p[6] = (short)f2bf(v1.z); p[7] = (short)f2bf(v1.w);
    return p;
}

// ---------------------------------------------------------------------------
// Small bf16-out GEMM (Wcomb = Wih @ Wg^T, 3 blocks).
// ---------------------------------------------------------------------------
__global__ __launch_bounds__(256)
void gemm_bf16(ushort* __restrict__ Cout, const float* __restrict__ A,
               const float* __restrict__ B) {
    __shared__ float4 smemv[4096];
    ushort* As = (ushort*)smemv;
    ushort* Bs = As + 128 * 128;
    const int m0 = blockIdx.x * 128;
    const int t  = threadIdx.x;

    #pragma unroll
    for (int f = t; f < 2048; f += 256) {
        const int r = f >> 4, c8 = (f & 15) * 8;
        *(bf16x8*)&As[r * 128 + (c8 ^ ((r & 7) << 3))] = cvt8(A + (size_t)(m0 + r) * 128 + c8);
        *(bf16x8*)&Bs[r * 128 + (c8 ^ ((r & 7) << 3))] = cvt8(B + (size_t)r * 128 + c8);
    }
    __syncthreads();

    const int lane = t & 63, wid = t >> 6;
    const int wr = wid >> 1, wc = wid & 1;
    const int l15 = lane & 15, kg = (lane >> 4) * 8;

    f32x4 acc[4][4] = {};
    #pragma unroll
    for (int kc = 0; kc < 4; ++kc) {
        const int cs = kc * 32 + kg;
        bf16x8 af[4], bfr[4];
        #pragma unroll
        for (int i = 0; i < 4; ++i) {
            const int ra = wr * 64 + i * 16 + l15;
            af[i] = *(const bf16x8*)&As[ra * 128 + (cs ^ ((ra & 7) << 3))];
            const int rb = wc * 64 + i * 16 + l15;
            bfr[i] = *(const bf16x8*)&Bs[rb * 128 + (cs ^ ((rb & 7) << 3))];
        }
        #pragma unroll
        for (int i = 0; i < 4; ++i)
            #pragma unroll
            for (int j = 0; j < 4; ++j)
                acc[i][j] = __builtin_amdgcn_mfma_f32_16x16x32_bf16(af[i], bfr[j], acc[i][j], 0, 0, 0);
    }
    const int cr0 = (lane >> 4) * 4;
    #pragma unroll
    for (int j = 0; j < 4; ++j) {
        const int col = wc * 64 + j * 16 + l15;
        #pragma unroll
        for (int i = 0; i < 4; ++i) {
            const int row = m0 + wr * 64 + i * 16 + cr0;
            #pragma unroll
            for (int q = 0; q < 4; ++q)
                Cout[(size_t)(row + q) * 128 + col] = f2bf(acc[i][j][q]);
        }
    }
}

// ---------------------------------------------------------------------------
// Mega prep kernel: [0,6400) gather h/hb; [6400,8000) hist; rest emb->bf16
// pre-swizzled copy (pad rows zero-filled). All three parts independent.
// ---------------------------------------------------------------------------
__global__ __launch_bounds__(256)
void prep_kernel(const int* __restrict__ x, const float* __restrict__ emb,
                 float* __restrict__ h, ushort* __restrict__ hb,
                 const int* __restrict__ ei, int* __restrict__ deg,
                 ushort* __restrict__ embswz) {
    const int bid = blockIdx.x;
    const int t = threadIdx.x;
    if (bid < 6400) {                              // h = emb[x-1] (+bf16 copy)
        const int tid = bid * 256 + t;
        const int i = tid >> 5, c = (tid & 31) * 4;
        const int idx = x[i] - 1;
        const float4 v = *(const float4*)(emb + (size_t)idx * 128 + c);
        *(float4*)(h + (size_t)i * 128 + c) = v;
        uint2 uu;
        uu.x = (unsigned)f2bf(v.x) | ((unsigned)f2bf(v.y) << 16);
        uu.y = (unsigned)f2bf(v.z) | ((unsigned)f2bf(v.w) << 16);
        *(uint2*)(hb + (size_t)i * 128 + c) = uu;
    } else if (bid < 8000) {                       // degree histogram
        const int e = (bid - 6400) * 256 + t;
        atomicAdd(&deg[ei[NEDGES + e]], 1);
    } else {                                       // embswz pre-swizzled bf16
        const int f = (bid - 8000) * 256 + t;      // < 100096*16
        const int row = f >> 4, c8 = (f & 15) * 8;
        bf16x8 pk = {0, 0, 0, 0, 0, 0, 0, 0};
        if (row < NVOCAB) pk = cvt8(emb + (size_t)row * 128 + c8);
        *(bf16x8*)&embswz[(size_t)row * 128 + (c8 ^ ((row & 7) << 3))] = pk;
    }
}

// ---------------------------------------------------------------------------
// Vocab GEMM: out = sh @ emb^T. A staged once; 4 n-tiles per block; B staged
// by pure linear 16B copies from pre-swizzled bf16 embswz (no cvt, half the
// bytes). Epilogue repacks acc via Cs (overlay Bs) -> 512B coalesced stores.
// LDS 64 KB -> 2 blocks/CU. XCD-aware 1D grid (1600): each XCD owns a
// contiguous n-range; 8 m-tiles of a group adjacent -> B fetched ~once/XCD.
// ---------------------------------------------------------------------------
__global__ __launch_bounds__(256)
void gemm_vocab(float* __restrict__ C, const float* __restrict__ A,
                const ushort* __restrict__ Bswz) {
    __shared__ ushort As[128 * 128];
    __shared__ ushort Bs[128 * 128];
    float* Cs = (float*)Bs;                        // [64][128] f32 overlay
    const int id = blockIdx.x;
    const int xcd = id & 7, loc = id >> 3;
    const int mt = loc & 7, gin = loc >> 3;        // gin 0..24
    const int grp = xcd * 25 + gin;                // 0..199
    const int m0 = mt * 128;
    const int t = threadIdx.x;
    const int lane = t & 63, wid = t >> 6;
    const int wr = wid >> 1, wc = wid & 1;
    const int l15 = lane & 15, kg = (lane >> 4) * 8;
    const int cr0 = (lane >> 4) * 4;

    #pragma unroll
    for (int f = t; f < 2048; f += 256) {
        const int r = f >> 4, c8 = (f & 15) * 8;
        *(bf16x8*)&As[r * 128 + (c8 ^ ((r & 7) << 3))] = cvt8(A + (size_t)(m0 + r) * 128 + c8);
    }

    for (int it = 0; it < 4; ++it) {
        const int n0 = (grp * 4 + it) * 128;
        if (n0 >= NVOCAB) break;                   // block-uniform
        __syncthreads();                           // prev repack reads done
        const ushort* srcb = Bswz + (size_t)n0 * 128;
        #pragma unroll
        for (int f = t; f < 2048; f += 256)        // linear 32KB copy
            *(bf16x8*)&Bs[f * 8] = *(const bf16x8*)(srcb + f * 8);
        __syncthreads();

        f32x4 acc[4][4] = {};
        #pragma unroll
        for (int kc = 0; kc < 4; ++kc) {
            const int cs = kc * 32 + kg;
            bf16x8 af[4], bfr[4];
            #pragma unroll
            for (int i = 0; i < 4; ++i) {
                const int ra = wr * 64 + i * 16 + l15;
                af[i] = *(const bf16x8*)&As[ra * 128 + (cs ^ ((ra & 7) << 3))];
                const int rb = wc * 64 + i * 16 + l15;
                bfr[i] = *(const bf16x8*)&Bs[rb * 128 + (cs ^ ((rb & 7) << 3))];
            }
            #pragma unroll
            for (int i = 0; i < 4; ++i)
                #pragma unroll
                for (int j = 0; j < 4; ++j)
                    acc[i][j] = __builtin_amdgcn_mfma_f32_16x16x32_bf16(af[i], bfr[j], acc[i][j], 0, 0, 0);
        }
        __syncthreads();                           // MFMA reads of Bs done

        #pragma unroll
        for (int half = 0; half < 2; ++half) {
            if (wr == half) {
                #pragma unroll
                for (int j = 0; j < 4; ++j) {
                    const int col = wc * 64 + j * 16 + l15;
                    #pragma unroll
                    for (int i = 0; i < 4; ++i) {
                        const int rl = i * 16 + cr0;
                        #pragma unroll
                        for (int q = 0; q < 4; ++q)
                            Cs[(rl + q) * 128 + col] = acc[i][j][q];
                    }
                }
            }
            __syncthreads();
            #pragma unroll
            for (int f = t; f < 2048; f += 256) {
                const int r = f >> 5, c4 = (f & 31) * 4;
                if (n0 + c4 < NVOCAB) {
                    const f32x4 v = *(const f32x4*)&Cs[r * 128 + c4];
                    *(f32x4*)(C + (size_t)(m0 + half * 64 + r) * NVOCAB + n0 + c4) = v;
                }
            }
            __syncthreads();
        }
    }
}

// ---------------------------------------------------------------------------
// Fully fused GRU: 400 blocks x 512 thr, 128 rows each.
// ---------------------------------------------------------------------------
__global__ __launch_bounds__(512)
void gru_fused(const ushort* __restrict__ aggb, const ushort* __restrict__ Wc,
               const float* __restrict__ Whh, const float* __restrict__ bih,
               const float* __restrict__ bhh, float* __restrict__ h) {
    __shared__ ushort As[128 * 128];
    __shared__ ushort Bs[384 * 128];
    const int m0 = blockIdx.x * 128;
    const int t = threadIdx.x;
    const int lane = t & 63, wid = t >> 6;
    const int l15 = lane & 15, kg = (lane >> 4) * 8;

    #pragma unroll
    for (int f = t; f < 2048; f += 512) {
        const int r = f >> 4, c8 = (f & 15) * 8;
        const bf16x8 pk = *(const bf16x8*)(aggb + (size_t)(m0 + r) * 128 + c8);
        *(bf16x8*)&As[r * 128 + (c8 ^ ((r & 7) << 3))] = pk;
    }
    #pragma unroll
    for (int f = t; f < 6144; f += 512) {
        const int r = f >> 4, c8 = (f & 15) * 8;
        const bf16x8 pk = *(const bf16x8*)(Wc + (size_t)r * 128 + c8);
        *(bf16x8*)&Bs[r * 128 + (c8 ^ ((r & 7) << 3))] = pk;
    }
    __syncthreads();

    f32x4 gi[24] = {};
    #pragma unroll
    for (int kc = 0; kc < 4; ++kc) {
        const int cs = kc * 32 + kg;
        const int ra = wid * 16 + l15;
        const bf16x8 af = *(const bf16x8*)&As[ra * 128 + (cs ^ ((ra & 7) << 3))];
        #pragma unroll
        for (int j = 0; j < 24; ++j) {
            const int rb = j * 16 + l15;
            const bf16x8 bfr = *(const bf16x8*)&Bs[rb * 128 + (cs ^ ((rb & 7) << 3))];
            gi[j] = __builtin_amdgcn_mfma_f32_16x16x32_bf16(af, bfr, gi[j], 0, 0, 0);
        }
    }
    __syncthreads();

    #pragma unroll
    for (int f = t; f < 2048; f += 512) {
        const int r = f >> 4, c8 = (f & 15) * 8;
        *(bf16x8*)&As[r * 128 + (c8 ^ ((r & 7) << 3))] = cvt8(h + (size_t)(m0 + r) * 128 + c8);
    }
    #pragma unroll
    for (int f = t; f < 6144; f += 512) {
        const int r = f >> 4, c8 = (f & 15) * 8;
        *(bf16x8*)&Bs[r * 128 + (c8 ^ ((r & 7) << 3))] = cvt8(Whh + (size_t)r * 128 + c8);
    }
    __syncthreads();

    f32x4 gh[24] = {};
    #pragma unroll
    for (int kc = 0; kc < 4; ++kc) {
        const int cs = kc * 32 + kg;
        const int ra = wid * 16 + l15;
        const bf16x8 af = *(const bf16x8*)&As[ra * 128 + (cs ^ ((ra & 7) << 3))];
        #pragma unroll
        for (int j = 0; j < 24; ++j) {
            const int rb = j * 16 + l15;
            const bf16x8 bfr = *(const bf16x8*)&Bs[rb * 128 + (cs ^ ((rb & 7) << 3))];
            gh[j] = __builtin_amdgcn_mfma_f32_16x16x32_bf16(af, bfr, gh[j], 0, 0, 0);
        }
    }

    const int rl0 = m0 + wid * 16 + (lane >> 4) * 4;
    #pragma unroll
    for (int j = 0; j < 8; ++j) {
        const int col = j * 16 + l15;
        const float bir = bih[col], biz = bih[128 + col], bin = bih[256 + col];
        const float bhr = bhh[col], bhz = bhh[128 + col], bhn = bhh[256 + col];
        #pragma unroll
        for (int q = 0; q < 4; ++q) {
            const size_t hb = (size_t)(rl0 + q) * 128 + col;
            const float hv = h[hb];
            const float r_ = sigf(gi[j][q] + bir + gh[j][q] + bhr);
            const float z  = sigf(gi[j + 8][q] + biz + gh[j + 8][q] + bhz);
            const float ng = tanhf(gi[j + 16][q] + bin + r_ * (gh[j + 16][q] + bhn));
            h[hb] = fmaxf((1.f - z) * ng + z * hv, 0.f);
        }
    }
}

// ---------------- CSR build ----------------
__global__ __launch_bounds__(1024)
void scan_all(const int* __restrict__ deg, int* __restrict__ offs,
              int* __restrict__ cursor) {
    __shared__ int ps[1024];
    const int t = threadIdx.x;
    const int base = t * 50;
    int loc[50];
    int s = 0;
    #pragma unroll
    for (int i = 0; i < 50; ++i) { loc[i] = deg[base + i]; s += loc[i]; }
    ps[t] = s;
    __syncthreads();
    for (int off = 1; off < 1024; off <<= 1) {
        const int add = (t >= off) ? ps[t - off] : 0;
        __syncthreads();
        ps[t] += add;
        __syncthreads();
    }
    int run = ps[t] - s;
    #pragma unroll
    for (int i = 0; i < 50; ++i) {
        offs[base + i] = run;
        cursor[base + i] = run;
        run += loc[i];
    }
    if (t == 1023) offs[NNODES] = run;
}

__global__ __launch_bounds__(256)
void fill_kernel(const int* __restrict__ ei, int* __restrict__ cursor,
                 int* __restrict__ esrc) {
    const int e = blockIdx.x * 256 + threadIdx.x;
    const int dst = ei[NEDGES + e];
    const int pos = atomicAdd(&cursor[dst], 1);
    esrc[pos] = ei[e];
}

// S[i] = sum over in-edges of h[src] (bf16 in, f32 acc, bf16 out)
__global__ __launch_bounds__(256)
void agg_kernel(const int* __restrict__ offs, const int* __restrict__ esrc,
                const ushort* __restrict__ hb, ushort* __restrict__ aggb) {
    const int node = blockIdx.x * 4 + (threadIdx.x >> 6);
    const int l = threadIdx.x & 63;
    const int s = offs[node], e = offs[node + 1];
    float ax = 0.f, ay = 0.f;
    for (int j = s; j < e; ++j) {
        const int src = esrc[j];
        const unsigned u = *(const unsigned*)(hb + (size_t)src * 128 + l * 2);
        ax += bf2f((ushort)(u & 0xffff));
        ay += bf2f((ushort)(u >> 16));
    }
    const unsigned o = (unsigned)f2bf(ax) | ((unsigned)f2bf(ay) << 16);
    *(unsigned*)(aggb + (size_t)node * 128 + l * 2) = o;
}

// ---------------------------------------------------------------------------
// Fused t2-GEMM + attention + sh: 512 blocks x 256 thr, 2 sessions each.
// sg never leaves LDS; sh computed in-block (W3 rows from L2).
// ---------------------------------------------------------------------------
__global__ __launch_bounds__(256)
void attn_sh(const float* __restrict__ h, const float* __restrict__ W1,
             const float* __restrict__ b1, const float* __restrict__ W2,
             const float* __restrict__ qw, const float* __restrict__ qbp,
             const float* __restrict__ b2, const float* __restrict__ W3,
             const float* __restrict__ b3, float* __restrict__ sh) {
    __shared__ ushort As[128 * 128];     // h tile bf16 (swizzled)
    __shared__ ushort Bs[128 * 128];     // W2 bf16, then t2T bf16 [d][row]
    __shared__ float t1s[2][128];
    __shared__ float qws[128];
    __shared__ float apar[2][2][64];
    __shared__ float alph[2][64];
    __shared__ float sgs[2][128];
    const int m0 = blockIdx.x * 100;
    const int t = threadIdx.x;
    const int lane = t & 63, wid = t >> 6;
    const int wr = wid >> 1, wc = wid & 1;
    const int l15 = lane & 15, kg = (lane >> 4) * 8;
    const int cr0 = (lane >> 4) * 4;

    #pragma unroll
    for (int f = t; f < 2048; f += 256) {
        const int r = f >> 4, c8 = (f & 15) * 8;
        int gr = m0 + r; if (gr > NNODES - 1) gr = NNODES - 1;   // clamp tail
        *(bf16x8*)&As[r * 128 + (c8 ^ ((r & 7) << 3))] = cvt8(h + (size_t)gr * 128 + c8);
        *(bf16x8*)&Bs[r * 128 + (c8 ^ ((r & 7) << 3))] = cvt8(W2 + (size_t)r * 128 + c8);
    }
    if (t < 128) qws[t] = qw[t];
    __syncthreads();

    // t2 = h @ W2^T
    f32x4 acc[4][4] = {};
    #pragma unroll
    for (int kc = 0; kc < 4; ++kc) {
        const int cs = kc * 32 + kg;
        bf16x8 af[4], bfr[4];
        #pragma unroll
        for (int i = 0; i < 4; ++i) {
            const int ra = wr * 64 + i * 16 + l15;
            af[i] = *(const bf16x8*)&As[ra * 128 + (cs ^ ((ra & 7) << 3))];
            const int rb = wc * 64 + i * 16 + l15;
            bfr[i] = *(const bf16x8*)&Bs[rb * 128 + (cs ^ ((rb & 7) << 3))];
        }
        #pragma unroll
        for (int i = 0; i < 4; ++i)
            #pragma unroll
            for (int j = 0; j < 4; ++j)
                acc[i][j] = __builtin_amdgcn_mfma_f32_16x16x32_bf16(af[i], bfr[j], acc[i][j], 0, 0, 0);
    }
    __syncthreads();                               // MFMA reads of Bs done

    // t2T (bf16, swizzled) overlays Bs: addr = d*128 + (row ^ ((d&7)<<3))
    #pragma unroll
    for (int j = 0; j < 4; ++j) {
        const int col = wc * 64 + j * 16 + l15;
        const int csw = (col & 7) << 3;
        #pragma unroll
        for (int i = 0; i < 4; ++i) {
            const int row = wr * 64 + i * 16 + cr0;
            #pragma unroll
            for (int q = 0; q < 4; ++q)
                Bs[col * 128 + ((row + q) ^ csw)] = f2bf(acc[i][j][q]);
        }
    }

    // t1[d] = W1[d]·vn + b1[d] + b2[d]
    const int sess = wid >> 1, half = wid & 1;
    const int d = half * 64 + lane;
    const int vrow = sess * 50 + 49;
    const int vsw = (vrow & 7) << 3;
    float t1v = b1[d] + b2[d];
    const float* w1r = W1 + (size_t)d * 128;
    #pragma unroll 8
    for (int k = 0; k < 128; k += 4) {
        const float4 w = *(const float4*)(w1r + k);
        t1v += w.x * bf2f(As[vrow * 128 + ((k + 0) ^ vsw)])
             + w.y * bf2f(As[vrow * 128 + ((k + 1) ^ vsw)])
             + w.z * bf2f(As[vrow * 128 + ((k + 2) ^ vsw)])
             + w.w * bf2f(As[vrow * 128 + ((k + 3) ^ vsw)]);
    }
    t1s[sess][d] = t1v;
    __syncthreads();

    // alphas: lane = node (l<50), sum over this half's 64 dims
    float p = 0.f;
    if (lane < 50) {
        const int row = sess * 50 + lane;
        const int d0 = half * 64;
        #pragma unroll 8
        for (int dd = d0; dd < d0 + 64; ++dd)
            p += qws[dd] * sigf(t1s[sess][dd] + bf2f(Bs[dd * 128 + (row ^ ((dd & 7) << 3))]));
    }
    apar[sess][half][lane] = p;
    __syncthreads();
    if (half == 0 && lane < 50)
        alph[sess][lane] = apar[sess][0][lane] + apar[sess][1][lane] + qbp[0];
    __syncthreads();

    // sg[d] = sum_i alpha_i * h[i][d]  (kept in LDS)
    float sacc = 0.f;
    #pragma unroll 10
    for (int i = 0; i < 50; ++i) {
        const int row = sess * 50 + i;
        sacc += alph[sess][i] * bf2f(As[row * 128 + (d ^ ((row & 7) << 3))]);
    }
    sgs[sess][d] = sacc;
    __syncthreads();

    // sh[d] = W3[d] · [vn; sg] + b3[d]
    float shacc = b3[d];
    const float* w3r = W3 + (size_t)d * 256;
    #pragma unroll 8
    for (int k = 0; k < 128; k += 4) {
        const float4 w = *(const float4*)(w3r + k);
        shacc += w.x * bf2f(As[vrow * 128 + ((k + 0) ^ vsw)])
               + w.y * bf2f(As[vrow * 128 + ((k + 1) ^ vsw)])
               + w.z * bf2f(As[vrow * 128 + ((k + 2) ^ vsw)])
               + w.w * bf2f(As[vrow * 128 + ((k + 3) ^ vsw)]);
    }
    #pragma unroll 8
    for (int k = 0; k < 128; k += 4) {
        const float4 w = *(const float4*)(w3r + 128 + k);
        shacc += w.x * sgs[sess][k] + w.y * sgs[sess][k + 1]
               + w.z * sgs[sess][k + 2] + w.w * sgs[sess][k + 3];
    }
    sh[(size_t)(blockIdx.x * 2 + sess) * 128 + d] = shacc;
}

extern "C" void kernel_launch(void* const* d_in, const int* in_sizes, int n_in,
                              void* d_out, int out_size, void* d_ws, size_t ws_size,
                              hipStream_t stream) {
    const int*   x   = (const int*)d_in[0];
    const int*   ei  = (const int*)d_in[1];
    const float* emb = (const float*)d_in[3];
    const float* Wg  = (const float*)d_in[4];
    const float* Wih = (const float*)d_in[5];
    const float* Whh = (const float*)d_in[6];
    const float* bih = (const float*)d_in[7];
    const float* bhh = (const float*)d_in[8];
    const float* W1  = (const float*)d_in[9];
    const float* b1  = (const float*)d_in[10];
    const float* W2  = (const float*)d_in[11];
    const float* b2  = (const float*)d_in[12];
    const float* qw  = (const float*)d_in[13];
    const float* qb  = (const float*)d_in[14];
    const float* W3  = (const float*)d_in[15];
    const float* b3  = (const float*)d_in[16];
    float* out = (float*)d_out;

    // workspace layout (float offsets); ~81 MB
    float*  ws     = (float*)d_ws;
    float*  h      = ws;                           // 6,553,600 f32
    ushort* hb     = (ushort*)(ws + 6553600);      // 6,553,600 bf16
    ushort* aggb   = (ushort*)(ws + 9830400);      // 6,553,600 bf16
    ushort* Wc     = (ushort*)(ws + 13107200);     // 49,152 bf16
    float*  sh     = ws + 13131776;                // 131,072 f32
    ushort* embswz = (ushort*)(ws + 13262848);     // 100096*128 bf16 = 12,812,288
    int*    deg    = (int*)(ws + 19668992);        // 51,200
    int*    offs   = deg + NNODES;                 // 51,201
    int*    cursor = offs + NNODES + 1;            // 51,200
    int*    esrc   = cursor + NNODES;              // 409,600

    hipMemsetAsync(deg, 0, NNODES * sizeof(int), stream);

    // Wcomb = Wih @ Wg^T  (bf16 [384][128])
    gemm_bf16<<<3, 256, 0, stream>>>(Wc, Wih, Wg);
    // gather + hist + emb->bf16 pre-swizzle (independent parts)
    prep_kernel<<<8000 + NVPAD / 16, 256, 0, stream>>>(x, emb, h, hb, ei, deg, embswz);

    // CSR scan + fill + gather-sum
    scan_all<<<1, 1024, 0, stream>>>(deg, offs, cursor);
    fill_kernel<<<1600, 256, 0, stream>>>(ei, cursor, esrc);
    agg_kernel<<<12800, 256, 0, stream>>>(offs, esrc, hb, aggb);

    // fused GRU (gi/gh in registers)
    gru_fused<<<400, 512, 0, stream>>>(aggb, Wc, Whh, bih, bhh, h);

    // fused t2 + attention + sh
    attn_sh<<<512, 256, 0, stream>>>(h, W1, b1, W2, qw, qb, b2, W3, b3, sh);

    // out = s_h @ emb^T (bf16 pre-swizzled B)
    gemm_vocab<<<1600, 256, 0, stream>>>(out, sh, embswz);
}

// Round 11
// 317.424 us; speedup vs baseline: 6.2726x; 1.1521x over previous
//
#include <hip/hip_runtime.h>
#include <math.h>

#define NNODES 51200
#define NEDGES 409600
#define NB 1024
#define NODES_PER 50
#define NVOCAB 100000
#define NVPAD 100096
#define SLOTS 64

typedef __attribute__((ext_vector_type(8))) short bf16x8;
typedef __attribute__((ext_vector_type(4))) float f32x4;

__device__ __forceinline__ float sigf(float x) { return 1.0f / (1.0f + __expf(-x)); }

__device__ __forceinline__ ushort f2bf(float x) {   // RTNE f32 -> bf16
    union { float f; unsigned u; } v; v.f = x;
    const unsigned r = v.u + 0x7FFF + ((v.u >> 16) & 1);
    return (ushort)(r >> 16);
}
__device__ __forceinline__ float bf2f(ushort u) {
    union { float f; unsigned u; } v; v.u = ((unsigned)u) << 16; return v.f;
}
__device__ __forceinline__ bf16x8 cvt8(const float* __restrict__ src) {
    const float4 v0 = *(const float4*)src, v1 = *(const float4*)(src + 4);
    bf16x8 p;
    p[0] = (short)f2bf(v0.x); p[1] = (short)f2bf(v0.y);
    p[2] = (short)f2bf(v0.z); p[3] = (short)f2bf(v0.w);
    p[4] = (short)f2bf(v1.x); p[5] = (short)f2bf(v1.y);
    p[6] = (short)f2bf(v1.z); p[7] = (short)f2bf(v1.w);
    return p;
}

// ---------------------------------------------------------------------------
// Small bf16-out GEMM (Wcomb = Wih @ Wg^T, 3 blocks).
// ---------------------------------------------------------------------------
__global__ __launch_bounds__(256)
void gemm_bf16(ushort* __restrict__ Cout, const float* __restrict__ A,
               const float* __restrict__ B) {
    __shared__ float4 smemv[4096];
    ushort* As = (ushort*)smemv;
    ushort* Bs = As + 128 * 128;
    const int m0 = blockIdx.x * 128;
    const int t  = threadIdx.x;

    #pragma unroll
    for (int f = t; f < 2048; f += 256) {
        const int r = f >> 4, c8 = (f & 15) * 8;
        *(bf16x8*)&As[r * 128 + (c8 ^ ((r & 7) << 3))] = cvt8(A + (size_t)(m0 + r) * 128 + c8);
        *(bf16x8*)&Bs[r * 128 + (c8 ^ ((r & 7) << 3))] = cvt8(B + (size_t)r * 128 + c8);
    }
    __syncthreads();

    const int lane = t & 63, wid = t >> 6;
    const int wr = wid >> 1, wc = wid & 1;
    const int l15 = lane & 15, kg = (lane >> 4) * 8;

    f32x4 acc[4][4] = {};
    #pragma unroll
    for (int kc = 0; kc < 4; ++kc) {
        const int cs = kc * 32 + kg;
        bf16x8 af[4], bfr[4];
        #pragma unroll
        for (int i = 0; i < 4; ++i) {
            const int ra = wr * 64 + i * 16 + l15;
            af[i] = *(const bf16x8*)&As[ra * 128 + (cs ^ ((ra & 7) << 3))];
            const int rb = wc * 64 + i * 16 + l15;
            bfr[i] = *(const bf16x8*)&Bs[rb * 128 + (cs ^ ((rb & 7) << 3))];
        }
        #pragma unroll
        for (int i = 0; i < 4; ++i)
            #pragma unroll
            for (int j = 0; j < 4; ++j)
                acc[i][j] = __builtin_amdgcn_mfma_f32_16x16x32_bf16(af[i], bfr[j], acc[i][j], 0, 0, 0);
    }
    const int cr0 = (lane >> 4) * 4;
    #pragma unroll
    for (int j = 0; j < 4; ++j) {
        const int col = wc * 64 + j * 16 + l15;
        #pragma unroll
        for (int i = 0; i < 4; ++i) {
            const int row = m0 + wr * 64 + i * 16 + cr0;
            #pragma unroll
            for (int q = 0; q < 4; ++q)
                Cout[(size_t)(row + q) * 128 + col] = f2bf(acc[i][j][q]);
        }
    }
}

// ---------------------------------------------------------------------------
// Mega prep kernel:
//  [0,3200)       gather: hb[i] = bf16(emb[x[i]-1])
//  [3200,4800)    slot-CSR fill: esrc[dst*64+pos] = src
//  [4800,11056)   embswz: emb -> bf16, pre-swizzled, pad rows zeroed
// ---------------------------------------------------------------------------
__global__ __launch_bounds__(256)
void prep_kernel(const int* __restrict__ x, const float* __restrict__ emb,
                 ushort* __restrict__ hb, const int* __restrict__ ei,
                 int* __restrict__ cnt, int* __restrict__ esrc,
                 ushort* __restrict__ embswz) {
    const int bid = blockIdx.x;
    const int t = threadIdx.x;
    if (bid < 3200) {                              // gather
        const int tid = bid * 256 + t;
        const int i = tid >> 4, c8 = (tid & 15) * 8;
        const int idx = x[i] - 1;
        *(bf16x8*)(hb + (size_t)i * 128 + c8) = cvt8(emb + (size_t)idx * 128 + c8);
    } else if (bid < 4800) {                       // slot-CSR fill
        const int e = (bid - 3200) * 256 + t;
        const int dst = ei[NEDGES + e];
        const int pos = atomicAdd(&cnt[dst], 1);
        if (pos < SLOTS) esrc[(size_t)dst * SLOTS + pos] = ei[e];
    } else {                                       // embswz
        const int f = (bid - 4800) * 256 + t;      // < NVPAD*16
        const int row = f >> 4, c8 = (f & 15) * 8;
        bf16x8 pk = {0, 0, 0, 0, 0, 0, 0, 0};
        if (row < NVOCAB) pk = cvt8(emb + (size_t)row * 128 + c8);
        *(bf16x8*)&embswz[(size_t)row * 128 + (c8 ^ ((row & 7) << 3))] = pk;
    }
}

// S[i] = sum over in-edges of hb[src]; one wave per node
__global__ __launch_bounds__(256)
void agg_kernel(const int* __restrict__ cnt, const int* __restrict__ esrc,
                const ushort* __restrict__ hb, ushort* __restrict__ aggb) {
    const int node = blockIdx.x * 4 + (threadIdx.x >> 6);
    const int l = threadIdx.x & 63;
    int cn = cnt[node]; if (cn > SLOTS) cn = SLOTS;
    const int* es = esrc + (size_t)node * SLOTS;
    float ax = 0.f, ay = 0.f;
    for (int j = 0; j < cn; ++j) {
        const int src = es[j];
        const unsigned u = *(const unsigned*)(hb + (size_t)src * 128 + l * 2);
        ax += bf2f((ushort)(u & 0xffff));
        ay += bf2f((ushort)(u >> 16));
    }
    const unsigned o = (unsigned)f2bf(ax) | ((unsigned)f2bf(ay) << 16);
    *(unsigned*)(aggb + (size_t)node * 128 + l * 2) = o;
}

// ---------------------------------------------------------------------------
// Fully fused GRU on bf16 h: 400 blocks x 512 thr, 128 rows each.
// Phase 1: gi = S @ Wcomb^T. Phase 2: gh = hb @ Whh^T (As holds bf16 h).
// Epilogue: hv read from As (LDS, no global re-read); gates + ReLU written
// back into As; final linear bf16x8 copy As -> hb (fully coalesced).
// ---------------------------------------------------------------------------
__global__ __launch_bounds__(512)
void gru_fused(const ushort* __restrict__ aggb, const ushort* __restrict__ Wc,
               const float* __restrict__ Whh, const float* __restrict__ bih,
               const float* __restrict__ bhh, ushort* __restrict__ hb) {
    __shared__ ushort As[128 * 128];
    __shared__ ushort Bs[384 * 128];
    const int m0 = blockIdx.x * 128;
    const int t = threadIdx.x;
    const int lane = t & 63, wid = t >> 6;
    const int l15 = lane & 15, kg = (lane >> 4) * 8;

    // ---- phase 1: gi = S @ Wcomb^T ----
    #pragma unroll
    for (int f = t; f < 2048; f += 512) {
        const int r = f >> 4, c8 = (f & 15) * 8;
        const bf16x8 pk = *(const bf16x8*)(aggb + (size_t)(m0 + r) * 128 + c8);
        *(bf16x8*)&As[r * 128 + (c8 ^ ((r & 7) << 3))] = pk;
    }
    #pragma unroll
    for (int f = t; f < 6144; f += 512) {
        const int r = f >> 4, c8 = (f & 15) * 8;
        const bf16x8 pk = *(const bf16x8*)(Wc + (size_t)r * 128 + c8);
        *(bf16x8*)&Bs[r * 128 + (c8 ^ ((r & 7) << 3))] = pk;
    }
    __syncthreads();

    f32x4 gi[24] = {};
    #pragma unroll
    for (int kc = 0; kc < 4; ++kc) {
        const int cs = kc * 32 + kg;
        const int ra = wid * 16 + l15;
        const bf16x8 af = *(const bf16x8*)&As[ra * 128 + (cs ^ ((ra & 7) << 3))];
        #pragma unroll
        for (int j = 0; j < 24; ++j) {
            const int rb = j * 16 + l15;
            const bf16x8 bfr = *(const bf16x8*)&Bs[rb * 128 + (cs ^ ((rb & 7) << 3))];
            gi[j] = __builtin_amdgcn_mfma_f32_16x16x32_bf16(af, bfr, gi[j], 0, 0, 0);
        }
    }
    __syncthreads();

    // ---- phase 2: gh = h @ Whh^T (As = bf16 h, kept for epilogue) ----
    #pragma unroll
    for (int f = t; f < 2048; f += 512) {
        const int r = f >> 4, c8 = (f & 15) * 8;
        const bf16x8 pk = *(const bf16x8*)(hb + (size_t)(m0 + r) * 128 + c8);
        *(bf16x8*)&As[r * 128 + (c8 ^ ((r & 7) << 3))] = pk;
    }
    #pragma unroll
    for (int f = t; f < 6144; f += 512) {
        const int r = f >> 4, c8 = (f & 15) * 8;
        *(bf16x8*)&Bs[r * 128 + (c8 ^ ((r & 7) << 3))] = cvt8(Whh + (size_t)r * 128 + c8);
    }
    __syncthreads();

    f32x4 gh[24] = {};
    #pragma unroll
    for (int kc = 0; kc < 4; ++kc) {
        const int cs = kc * 32 + kg;
        const int ra = wid * 16 + l15;
        const bf16x8 af = *(const bf16x8*)&As[ra * 128 + (cs ^ ((ra & 7) << 3))];
        #pragma unroll
        for (int j = 0; j < 24; ++j) {
            const int rb = j * 16 + l15;
            const bf16x8 bfr = *(const bf16x8*)&Bs[rb * 128 + (cs ^ ((rb & 7) << 3))];
            gh[j] = __builtin_amdgcn_mfma_f32_16x16x32_bf16(af, bfr, gh[j], 0, 0, 0);
        }
    }

    // ---- epilogue: gates + ReLU; hv from As; result back into As ----
    // Each wave touches only As rows [wid*16, wid*16+16); each thread
    // reads/writes its own 32 slots -> no barrier needed before writes.
    const int lr0 = wid * 16 + (lane >> 4) * 4;
    #pragma unroll
    for (int j = 0; j < 8; ++j) {
        const int col = j * 16 + l15;
        const float bir = bih[col], biz = bih[128 + col], bin = bih[256 + col];
        const float bhr = bhh[col], bhz = bhh[128 + col], bhn = bhh[256 + col];
        #pragma unroll
        for (int q = 0; q < 4; ++q) {
            const int lr = lr0 + q;
            const int adr = lr * 128 + (col ^ ((lr & 7) << 3));
            const float hv = bf2f(As[adr]);
            const float r_ = sigf(gi[j][q] + bir + gh[j][q] + bhr);
            const float z  = sigf(gi[j + 8][q] + biz + gh[j + 8][q] + bhz);
            const float ng = tanhf(gi[j + 16][q] + bin + r_ * (gh[j + 16][q] + bhn));
            As[adr] = f2bf(fmaxf((1.f - z) * ng + z * hv, 0.f));
        }
    }
    __syncthreads();
    #pragma unroll
    for (int f = t; f < 2048; f += 512) {
        const int r = f >> 4, c8 = (f & 15) * 8;
        *(bf16x8*)(hb + (size_t)(m0 + r) * 128 + c8) =
            *(const bf16x8*)&As[r * 128 + (c8 ^ ((r & 7) << 3))];
    }
}

// ---------------------------------------------------------------------------
// Fused t2-GEMM + attention + sh: 512 blocks x 256 thr, 2 sessions each.
// ---------------------------------------------------------------------------
__global__ __launch_bounds__(256)
void attn_sh(const ushort* __restrict__ hb, const float* __restrict__ W1,
             const float* __restrict__ b1, const float* __restrict__ W2,
             const float* __restrict__ qw, const float* __restrict__ qbp,
             const float* __restrict__ b2, const float* __restrict__ W3,
             const float* __restrict__ b3, float* __restrict__ sh) {
    __shared__ ushort As[128 * 128];     // h tile bf16 (swizzled)
    __shared__ ushort Bs[128 * 128];     // W2 bf16, then t2T bf16 [d][row]
    __shared__ float t1s[2][128];
    __shared__ float qws[128];
    __shared__ float apar[2][2][64];
    __shared__ float alph[2][64];
    __shared__ float sgs[2][128];
    const int m0 = blockIdx.x * 100;
    const int t = threadIdx.x;
    const int lane = t & 63, wid = t >> 6;
    const int wr = wid >> 1, wc = wid & 1;
    const int l15 = lane & 15, kg = (lane >> 4) * 8;
    const int cr0 = (lane >> 4) * 4;

    #pragma unroll
    for (int f = t; f < 2048; f += 256) {
        const int r = f >> 4, c8 = (f & 15) * 8;
        int gr = m0 + r; if (gr > NNODES - 1) gr = NNODES - 1;   // clamp tail
        *(bf16x8*)&As[r * 128 + (c8 ^ ((r & 7) << 3))] =
            *(const bf16x8*)(hb + (size_t)gr * 128 + c8);
        *(bf16x8*)&Bs[r * 128 + (c8 ^ ((r & 7) << 3))] = cvt8(W2 + (size_t)r * 128 + c8);
    }
    if (t < 128) qws[t] = qw[t];
    __syncthreads();

    // t2 = h @ W2^T
    f32x4 acc[4][4] = {};
    #pragma unroll
    for (int kc = 0; kc < 4; ++kc) {
        const int cs = kc * 32 + kg;
        bf16x8 af[4], bfr[4];
        #pragma unroll
        for (int i = 0; i < 4; ++i) {
            const int ra = wr * 64 + i * 16 + l15;
            af[i] = *(const bf16x8*)&As[ra * 128 + (cs ^ ((ra & 7) << 3))];
            const int rb = wc * 64 + i * 16 + l15;
            bfr[i] = *(const bf16x8*)&Bs[rb * 128 + (cs ^ ((rb & 7) << 3))];
        }
        #pragma unroll
        for (int i = 0; i < 4; ++i)
            #pragma unroll
            for (int j = 0; j < 4; ++j)
                acc[i][j] = __builtin_amdgcn_mfma_f32_16x16x32_bf16(af[i], bfr[j], acc[i][j], 0, 0, 0);
    }
    __syncthreads();                               // MFMA reads of Bs done

    // t2T (bf16, swizzled) overlays Bs: addr = d*128 + (row ^ ((d&7)<<3))
    #pragma unroll
    for (int j = 0; j < 4; ++j) {
        const int col = wc * 64 + j * 16 + l15;
        const int csw = (col & 7) << 3;
        #pragma unroll
        for (int i = 0; i < 4; ++i) {
            const int row = wr * 64 + i * 16 + cr0;
            #pragma unroll
            for (int q = 0; q < 4; ++q)
                Bs[col * 128 + ((row + q) ^ csw)] = f2bf(acc[i][j][q]);
        }
    }

    // t1[d] = W1[d]·vn + b1[d] + b2[d]
    const int sess = wid >> 1, half = wid & 1;
    const int d = half * 64 + lane;
    const int vrow = sess * 50 + 49;
    const int vsw = (vrow & 7) << 3;
    float t1v = b1[d] + b2[d];
    const float* w1r = W1 + (size_t)d * 128;
    #pragma unroll 8
    for (int k = 0; k < 128; k += 4) {
        const float4 w = *(const float4*)(w1r + k);
        t1v += w.x * bf2f(As[vrow * 128 + ((k + 0) ^ vsw)])
             + w.y * bf2f(As[vrow * 128 + ((k + 1) ^ vsw)])
             + w.z * bf2f(As[vrow * 128 + ((k + 2) ^ vsw)])
             + w.w * bf2f(As[vrow * 128 + ((k + 3) ^ vsw)]);
    }
    t1s[sess][d] = t1v;
    __syncthreads();

    // alphas: lane = node (l<50), sum over this half's 64 dims
    float p = 0.f;
    if (lane < 50) {
        const int row = sess * 50 + lane;
        const int d0 = half * 64;
        #pragma unroll 8
        for (int dd = d0; dd < d0 + 64; ++dd)
            p += qws[dd] * sigf(t1s[sess][dd] + bf2f(Bs[dd * 128 + (row ^ ((dd & 7) << 3))]));
    }
    apar[sess][half][lane] = p;
    __syncthreads();
    if (half == 0 && lane < 50)
        alph[sess][lane] = apar[sess][0][lane] + apar[sess][1][lane] + qbp[0];
    __syncthreads();

    // sg[d] = sum_i alpha_i * h[i][d]  (kept in LDS)
    float sacc = 0.f;
    #pragma unroll 10
    for (int i = 0; i < 50; ++i) {
        const int row = sess * 50 + i;
        sacc += alph[sess][i] * bf2f(As[row * 128 + (d ^ ((row & 7) << 3))]);
    }
    sgs[sess][d] = sacc;
    __syncthreads();

    // sh[d] = W3[d] · [vn; sg] + b3[d]
    float shacc = b3[d];
    const float* w3r = W3 + (size_t)d * 256;
    #pragma unroll 8
    for (int k = 0; k < 128; k += 4) {
        const float4 w = *(const float4*)(w3r + k);
        shacc += w.x * bf2f(As[vrow * 128 + ((k + 0) ^ vsw)])
               + w.y * bf2f(As[vrow * 128 + ((k + 1) ^ vsw)])
               + w.z * bf2f(As[vrow * 128 + ((k + 2) ^ vsw)])
               + w.w * bf2f(As[vrow * 128 + ((k + 3) ^ vsw)]);
    }
    #pragma unroll 8
    for (int k = 0; k < 128; k += 4) {
        const float4 w = *(const float4*)(w3r + 128 + k);
        shacc += w.x * sgs[sess][k] + w.y * sgs[sess][k + 1]
               + w.z * sgs[sess][k + 2] + w.w * sgs[sess][k + 3];
    }
    sh[(size_t)(blockIdx.x * 2 + sess) * 128 + d] = shacc;
}

// ---------------------------------------------------------------------------
// Vocab GEMM: out = sh @ emb^T (pre-swizzled bf16 B). A staged once; 4
// n-tiles per block; epilogue repack via Cs (overlay Bs) -> 512B stores.
// ---------------------------------------------------------------------------
__global__ __launch_bounds__(256)
void gemm_vocab(float* __restrict__ C, const float* __restrict__ A,
                const ushort* __restrict__ Bswz) {
    __shared__ ushort As[128 * 128];
    __shared__ ushort Bs[128 * 128];
    float* Cs = (float*)Bs;                        // [64][128] f32 overlay
    const int id = blockIdx.x;
    const int xcd = id & 7, loc = id >> 3;
    const int mt = loc & 7, gin = loc >> 3;        // gin 0..24
    const int grp = xcd * 25 + gin;                // 0..199
    const int m0 = mt * 128;
    const int t = threadIdx.x;
    const int lane = t & 63, wid = t >> 6;
    const int wr = wid >> 1, wc = wid & 1;
    const int l15 = lane & 15, kg = (lane >> 4) * 8;
    const int cr0 = (lane >> 4) * 4;

    #pragma unroll
    for (int f = t; f < 2048; f += 256) {
        const int r = f >> 4, c8 = (f & 15) * 8;
        *(bf16x8*)&As[r * 128 + (c8 ^ ((r & 7) << 3))] = cvt8(A + (size_t)(m0 + r) * 128 + c8);
    }

    for (int it = 0; it < 4; ++it) {
        const int n0 = (grp * 4 + it) * 128;
        if (n0 >= NVOCAB) break;                   // block-uniform
        __syncthreads();                           // prev repack reads done
        const ushort* srcb = Bswz + (size_t)n0 * 128;
        #pragma unroll
        for (int f = t; f < 2048; f += 256)        // linear 32KB copy
            *(bf16x8*)&Bs[f * 8] = *(const bf16x8*)(srcb + f * 8);
        __syncthreads();

        f32x4 acc[4][4] = {};
        #pragma unroll
        for (int kc = 0; kc < 4; ++kc) {
            const int cs = kc * 32 + kg;
            bf16x8 af[4], bfr[4];
            #pragma unroll
            for (int i = 0; i < 4; ++i) {
                const int ra = wr * 64 + i * 16 + l15;
                af[i] = *(const bf16x8*)&As[ra * 128 + (cs ^ ((ra & 7) << 3))];
                const int rb = wc * 64 + i * 16 + l15;
                bfr[i] = *(const bf16x8*)&Bs[rb * 128 + (cs ^ ((rb & 7) << 3))];
            }
            #pragma unroll
            for (int i = 0; i < 4; ++i)
                #pragma unroll
                for (int j = 0; j < 4; ++j)
                    acc[i][j] = __builtin_amdgcn_mfma_f32_16x16x32_bf16(af[i], bfr[j], acc[i][j], 0, 0, 0);
        }
        __syncthreads();                           // MFMA reads of Bs done

        #pragma unroll
        for (int half = 0; half < 2; ++half) {
            if (wr == half) {
                #pragma unroll
                for (int j = 0; j < 4; ++j) {
                    const int col = wc * 64 + j * 16 + l15;
                    #pragma unroll
                    for (int i = 0; i < 4; ++i) {
                        const int rl = i * 16 + cr0;
                        #pragma unroll
                        for (int q = 0; q < 4; ++q)
                            Cs[(rl + q) * 128 + col] = acc[i][j][q];
                    }
                }
            }
            __syncthreads();
            #pragma unroll
            for (int f = t; f < 2048; f += 256) {
                const int r = f >> 5, c4 = (f & 31) * 4;
                if (n0 + c4 < NVOCAB) {
                    const f32x4 v = *(const f32x4*)&Cs[r * 128 + c4];
                    *(f32x4*)(C + (size_t)(m0 + half * 64 + r) * NVOCAB + n0 + c4) = v;
                }
            }
            __syncthreads();
        }
    }
}

extern "C" void kernel_launch(void* const* d_in, const int* in_sizes, int n_in,
                              void* d_out, int out_size, void* d_ws, size_t ws_size,
                              hipStream_t stream) {
    const int*   x   = (const int*)d_in[0];
    const int*   ei  = (const int*)d_in[1];
    const float* emb = (const float*)d_in[3];
    const float* Wg  = (const float*)d_in[4];
    const float* Wih = (const float*)d_in[5];
    const float* Whh = (const float*)d_in[6];
    const float* bih = (const float*)d_in[7];
    const float* bhh = (const float*)d_in[8];
    const float* W1  = (const float*)d_in[9];
    const float* b1  = (const float*)d_in[10];
    const float* W2  = (const float*)d_in[11];
    const float* b2  = (const float*)d_in[12];
    const float* qw  = (const float*)d_in[13];
    const float* qb  = (const float*)d_in[14];
    const float* W3  = (const float*)d_in[15];
    const float* b3  = (const float*)d_in[16];
    float* out = (float*)d_out;

    // workspace layout (float offsets); ~66 MB
    float*  ws     = (float*)d_ws;
    ushort* hb     = (ushort*)ws;                  // 6,553,600 bf16 (3,276,800 f)
    ushort* aggb   = (ushort*)(ws + 3276800);      // 6,553,600 bf16
    ushort* Wc     = (ushort*)(ws + 6553600);      // 49,152 bf16 (24,576 f)
    float*  sh     = ws + 6578176;                 // 131,072 f32
    ushort* embswz = (ushort*)(ws + 6709248);      // 12,812,288 bf16 (6,406,144 f)
    int*    cnt    = (int*)(ws + 13115392);        // 51,200
    int*    esrc   = cnt + NNODES;                 // 51200*64 = 3,276,800

    hipMemsetAsync(cnt, 0, NNODES * sizeof(int), stream);

    // Wcomb = Wih @ Wg^T  (bf16 [384][128])
    gemm_bf16<<<3, 256, 0, stream>>>(Wc, Wih, Wg);
    // gather + slot-CSR fill + emb->bf16 pre-swizzle (independent parts)
    prep_kernel<<<4800 + NVPAD / 16, 256, 0, stream>>>(x, emb, hb, ei, cnt, esrc, embswz);

    // gather-sum S = sum hb[src]
    agg_kernel<<<12800, 256, 0, stream>>>(cnt, esrc, hb, aggb);

    // fused GRU (gi/gh in registers; h bf16 in place)
    gru_fused<<<400, 512, 0, stream>>>(aggb, Wc, Whh, bih, bhh, hb);

    // fused t2 + attention + sh
    attn_sh<<<512, 256, 0, stream>>>(hb, W1, b1, W2, qw, qb, b2, W3, b3, sh);

    // out = s_h @ emb^T (bf16 pre-swizzled B)
    gemm_vocab<<<1600, 256, 0, stream>>>(out, sh, embswz);
}